// Round 1
// baseline (3460.774 us; speedup 1.0000x reference)
//
#include <hip/hip_runtime.h>

#define DEV __device__ __forceinline__

constexpr int NN = 50000;   // nodes
constexpr int NE = 400000;  // edges
constexpr int NG = 32;      // graphs
constexpr float EPSV = 1e-5f;

// ---------------------------------------------------------------------------
// lin_in: h = x @ W(11x64) + b   — trivial, one thread per output element
// ---------------------------------------------------------------------------
__global__ __launch_bounds__(256) void lin_in_kernel(
    const float* __restrict__ x, const float* __restrict__ W,
    const float* __restrict__ b, float* __restrict__ h)
{
  int gid = blockIdx.x * 256 + threadIdx.x;
  if (gid >= NN * 64) return;
  int n = gid >> 6, c = gid & 63;
  float acc = b[c];
#pragma unroll
  for (int k = 0; k < 11; ++k)
    acc = fmaf(x[n * 11 + k], W[k * 64 + c], acc);
  h[gid] = acc;
}

DEV void fma4(float acc[4], float a, const float4& bv) {
  acc[0] = fmaf(a, bv.x, acc[0]);
  acc[1] = fmaf(a, bv.y, acc[1]);
  acc[2] = fmaf(a, bv.z, acc[2]);
  acc[3] = fmaf(a, bv.w, acc[3]);
}

// ---------------------------------------------------------------------------
// Tiled GEMM with fused input-BN (mode 1) / edge gather (mode 0) /
// node concat (mode 2), bias add, and BN-stats accumulation epilogue.
// Tile: 64 rows x 64 cols, 256 threads, 4x4 accum per thread.
// MODE 0: A row e = [h[dst[e]](64) | h[src[e]](64) | edge_attr[e](4)], K=132
// MODE 1: A row r = relu(scale*prev[r]+shift), K=64  (in-place out OK)
// MODE 2: A row n = [h[n](64) | aggr[n](64)], K=128
// W (Kx64) is read from global (L1/L2-resident, ~33KB max).
// ---------------------------------------------------------------------------
template <int K, int MODE>
__global__ __launch_bounds__(256) void gemm_bn(
    const float* __restrict__ A0,
    const float* __restrict__ A1,
    const int* __restrict__ srcI,
    const int* __restrict__ dstI,
    const float* __restrict__ W,      // K x 64
    const float* __restrict__ bias,   // 64
    const float* __restrict__ inStats,// sum[64], sumsq[64] of producer
    const float* __restrict__ inG,
    const float* __restrict__ inBe,
    float invM_in,
    float* __restrict__ outp,         // M x 64
    float* __restrict__ outStats,     // sum[64], sumsq[64]
    int M)
{
  constexpr int LDA = K + 8;          // keep rows 16B-aligned, stagger banks
  __shared__ float A_s[64 * LDA];
  __shared__ float scale_s[64];
  __shared__ float shift_s[64];
  __shared__ float red_s[128];

  const int tid = threadIdx.x;
  const int rbase = blockIdx.x * 64;

  if (MODE == 1) {
    if (tid < 64) {
      float mean = inStats[tid] * invM_in;
      float var = inStats[64 + tid] * invM_in - mean * mean;
      float sc = inG[tid] * rsqrtf(var + EPSV);
      scale_s[tid] = sc;
      shift_s[tid] = inBe[tid] - mean * sc;
    }
    __syncthreads();
#pragma unroll
    for (int i = 0; i < 4; ++i) {
      int row = (tid >> 4) + i * 16;
      int c = (tid & 15) * 4;
      int r = rbase + row;
      float4 v = make_float4(0.f, 0.f, 0.f, 0.f);
      if (r < M) v = *(const float4*)&A0[(size_t)r * 64 + c];
      v.x = fmaxf(fmaf(scale_s[c + 0], v.x, shift_s[c + 0]), 0.f);
      v.y = fmaxf(fmaf(scale_s[c + 1], v.y, shift_s[c + 1]), 0.f);
      v.z = fmaxf(fmaf(scale_s[c + 2], v.z, shift_s[c + 2]), 0.f);
      v.w = fmaxf(fmaf(scale_s[c + 3], v.w, shift_s[c + 3]), 0.f);
      *(float4*)&A_s[row * LDA + c] = v;
    }
  } else if (MODE == 0) {
    int e_loc = tid >> 2;
    int quad = tid & 3;
    int e = rbase + e_loc;
    int si = srcI[e];
    int di = dstI[e];
#pragma unroll
    for (int q = 0; q < 4; ++q) {
      int c = quad * 16 + q * 4;
      *(float4*)&A_s[e_loc * LDA + c] = *(const float4*)&A0[(size_t)di * 64 + c];
      *(float4*)&A_s[e_loc * LDA + 64 + c] = *(const float4*)&A0[(size_t)si * 64 + c];
    }
    if (quad == 0)
      *(float4*)&A_s[e_loc * LDA + 128] = *(const float4*)&A1[(size_t)e * 4];
  } else {  // MODE 2
    int n_loc = tid >> 2;
    int quad = tid & 3;
    int n = rbase + n_loc;
    bool ok = n < M;
#pragma unroll
    for (int q = 0; q < 4; ++q) {
      int c = quad * 16 + q * 4;
      float4 va = make_float4(0.f, 0.f, 0.f, 0.f);
      float4 vb = make_float4(0.f, 0.f, 0.f, 0.f);
      if (ok) {
        va = *(const float4*)&A0[(size_t)n * 64 + c];
        vb = *(const float4*)&A1[(size_t)n * 64 + c];
      }
      *(float4*)&A_s[n_loc * LDA + c] = va;
      *(float4*)&A_s[n_loc * LDA + 64 + c] = vb;
    }
  }
  __syncthreads();

  const int col_g = tid & 15;
  const int row_g = tid >> 4;
  const int c0 = col_g * 4;
  const int r0 = row_g * 4;

  float acc[4][4];
#pragma unroll
  for (int i = 0; i < 4; ++i)
#pragma unroll
    for (int j = 0; j < 4; ++j) acc[i][j] = 0.f;

  for (int k = 0; k < K; k += 4) {
    float4 a0 = *(const float4*)&A_s[(r0 + 0) * LDA + k];
    float4 a1 = *(const float4*)&A_s[(r0 + 1) * LDA + k];
    float4 a2 = *(const float4*)&A_s[(r0 + 2) * LDA + k];
    float4 a3 = *(const float4*)&A_s[(r0 + 3) * LDA + k];
    float4 b0 = *(const float4*)&W[(k + 0) * 64 + c0];
    float4 b1 = *(const float4*)&W[(k + 1) * 64 + c0];
    float4 b2 = *(const float4*)&W[(k + 2) * 64 + c0];
    float4 b3 = *(const float4*)&W[(k + 3) * 64 + c0];
    fma4(acc[0], a0.x, b0); fma4(acc[0], a0.y, b1); fma4(acc[0], a0.z, b2); fma4(acc[0], a0.w, b3);
    fma4(acc[1], a1.x, b0); fma4(acc[1], a1.y, b1); fma4(acc[1], a1.z, b2); fma4(acc[1], a1.w, b3);
    fma4(acc[2], a2.x, b0); fma4(acc[2], a2.y, b1); fma4(acc[2], a2.z, b2); fma4(acc[2], a2.w, b3);
    fma4(acc[3], a3.x, b0); fma4(acc[3], a3.y, b1); fma4(acc[3], a3.z, b2); fma4(acc[3], a3.w, b3);
  }

  // epilogue: +bias, store, per-column sum / sumsq
  float4 bv = *(const float4*)&bias[c0];
  float s[4] = {0.f, 0.f, 0.f, 0.f};
  float s2[4] = {0.f, 0.f, 0.f, 0.f};
#pragma unroll
  for (int i = 0; i < 4; ++i) {
    int r = rbase + r0 + i;
    if (r < M) {
      float y0 = acc[i][0] + bv.x;
      float y1 = acc[i][1] + bv.y;
      float y2 = acc[i][2] + bv.z;
      float y3 = acc[i][3] + bv.w;
      float4 o;
      o.x = y0; o.y = y1; o.z = y2; o.w = y3;
      *(float4*)&outp[(size_t)r * 64 + c0] = o;
      s[0] += y0; s2[0] += y0 * y0;
      s[1] += y1; s2[1] += y1 * y1;
      s[2] += y2; s2[2] += y2 * y2;
      s[3] += y3; s2[3] += y3 * y3;
    }
  }
  // reduce the 4 row-groups within each wave (lanes differ by 16, 32)
#pragma unroll
  for (int j = 0; j < 4; ++j) {
    s[j] += __shfl_xor(s[j], 16, 64);
    s[j] += __shfl_xor(s[j], 32, 64);
    s2[j] += __shfl_xor(s2[j], 16, 64);
    s2[j] += __shfl_xor(s2[j], 32, 64);
  }
  if (tid < 128) red_s[tid] = 0.f;
  __syncthreads();
  if ((tid & 63) < 16) {
#pragma unroll
    for (int j = 0; j < 4; ++j) {
      atomicAdd(&red_s[c0 + j], s[j]);
      atomicAdd(&red_s[64 + c0 + j], s2[j]);
    }
  }
  __syncthreads();
  if (tid < 128) atomicAdd(&outStats[tid], red_s[tid]);
}

// ---------------------------------------------------------------------------
// scatter: aggr[dst[e]] += relu(bn2(t2[e]))   (folded BN finalize)
// ---------------------------------------------------------------------------
__global__ __launch_bounds__(256) void scatter_kernel(
    const float* __restrict__ t2, const int* __restrict__ dstI,
    const float* __restrict__ stats, const float* __restrict__ g,
    const float* __restrict__ be, float invM, float* __restrict__ aggr)
{
  int gid = blockIdx.x * 256 + threadIdx.x;
  if (gid >= NE * 16) return;
  int e = gid >> 4;
  int c = (gid & 15) * 4;
  float4 v = *(const float4*)&t2[(size_t)e * 64 + c];
  int di = dstI[e];
  const float* vp = (const float*)&v;
#pragma unroll
  for (int j = 0; j < 4; ++j) {
    float mean = stats[c + j] * invM;
    float var = stats[64 + c + j] * invM - mean * mean;
    float sc = g[c + j] * rsqrtf(var + EPSV);
    float sh = be[c + j] - mean * sc;
    float val = fmaxf(fmaf(sc, vp[j], sh), 0.f);
    atomicAdd(&aggr[(size_t)di * 64 + c + j], val);
  }
}

// ---------------------------------------------------------------------------
// residual: h += relu(bn4(u2))   (folded BN finalize)
// ---------------------------------------------------------------------------
__global__ __launch_bounds__(256) void residual_kernel(
    const float* __restrict__ u2, const float* __restrict__ stats,
    const float* __restrict__ g, const float* __restrict__ be,
    float invM, float* __restrict__ h)
{
  int gid = blockIdx.x * 256 + threadIdx.x;
  if (gid >= NN * 16) return;
  int c = (gid & 15) * 4;
  float4 v = *(const float4*)&u2[(size_t)gid * 4];
  float4 hv = *(const float4*)&h[(size_t)gid * 4];
  float* vp = (float*)&v;
  float* hp = (float*)&hv;
#pragma unroll
  for (int j = 0; j < 4; ++j) {
    float mean = stats[c + j] * invM;
    float var = stats[64 + c + j] * invM - mean * mean;
    float sc = g[c + j] * rsqrtf(var + EPSV);
    float sh = be[c + j] - mean * sc;
    hp[j] += fmaxf(fmaf(sc, vp[j], sh), 0.f);
  }
  *(float4*)&h[(size_t)gid * 4] = hv;
}

// ---------------------------------------------------------------------------
// pool + prediction head: batch is SORTED -> binary-search graph ranges.
// One block per graph; mean over nodes, dot with pred_W, +pred_b.
// ---------------------------------------------------------------------------
DEV int lower_bound_i(const int* __restrict__ a, int n, int v) {
  int lo = 0, hi = n;
  while (lo < hi) {
    int m = (lo + hi) >> 1;
    if (a[m] < v) lo = m + 1; else hi = m;
  }
  return lo;
}

__global__ __launch_bounds__(256) void pool_pred_kernel(
    const float* __restrict__ h, const int* __restrict__ batch,
    const float* __restrict__ predW, const float* __restrict__ predB,
    float* __restrict__ out)
{
  __shared__ int s_lo, s_hi;
  __shared__ float red[4][64];
  int g = blockIdx.x;
  int tid = threadIdx.x;
  if (tid == 0) {
    s_lo = lower_bound_i(batch, NN, g);
    s_hi = lower_bound_i(batch, NN, g + 1);
  }
  __syncthreads();
  int lo = s_lo, hi = s_hi;
  int c = tid & 63, sl = tid >> 6;
  float acc = 0.f;
  for (int n = lo + sl; n < hi; n += 4) acc += h[(size_t)n * 64 + c];
  red[sl][c] = acc;
  __syncthreads();
  if (tid < 64) {
    float v = red[0][tid] + red[1][tid] + red[2][tid] + red[3][tid];
    float cnt = (float)(hi - lo);
    cnt = fmaxf(cnt, 1.0f);
    float p = (v / cnt) * predW[tid];
#pragma unroll
    for (int off = 32; off > 0; off >>= 1) p += __shfl_down(p, off, 64);
    if (tid == 0) out[g] = p + predB[0];
  }
}

// ---------------------------------------------------------------------------
extern "C" void kernel_launch(void* const* d_in, const int* in_sizes, int n_in,
                              void* d_out, int out_size, void* d_ws, size_t ws_size,
                              hipStream_t stream)
{
  (void)in_sizes; (void)n_in; (void)out_size; (void)ws_size;

  const float* x        = (const float*)d_in[0];
  const float* edge_attr= (const float*)d_in[1];
  const int*   eidx     = (const int*)d_in[2];
  const int*   batch    = (const int*)d_in[3];
  const float* linW     = (const float*)d_in[4];
  const float* linB     = (const float*)d_in[5];
  const float* msgW1    = (const float*)d_in[6];
  const float* msgB1    = (const float*)d_in[7];
  const float* msgG1    = (const float*)d_in[8];
  const float* msgBe1   = (const float*)d_in[9];
  const float* msgW2    = (const float*)d_in[10];
  const float* msgB2    = (const float*)d_in[11];
  const float* msgG2    = (const float*)d_in[12];
  const float* msgBe2   = (const float*)d_in[13];
  const float* updW1    = (const float*)d_in[14];
  const float* updB1    = (const float*)d_in[15];
  const float* updG1    = (const float*)d_in[16];
  const float* updBe1   = (const float*)d_in[17];
  const float* updW2    = (const float*)d_in[18];
  const float* updB2    = (const float*)d_in[19];
  const float* updG2    = (const float*)d_in[20];
  const float* updBe2   = (const float*)d_in[21];
  const float* predW    = (const float*)d_in[22];
  const float* predB    = (const float*)d_in[23];

  const int* srcI = eidx;        // edge_index[0] = source
  const int* dstI = eidx + NE;   // edge_index[1] = target

  float* ws   = (float*)d_ws;
  float* h    = ws;                           // NN*64
  float* t1   = h + (size_t)NN * 64;          // NE*64 (t2 written in-place)
  float* aggr = t1 + (size_t)NE * 64;         // NN*64
  float* u1   = aggr + (size_t)NN * 64;       // NN*64 (u2 in-place)
  float* stats= u1 + (size_t)NN * 64;         // 16 * 128

  hipMemsetAsync(stats, 0, 16 * 128 * sizeof(float), stream);

  lin_in_kernel<<<(NN * 64 + 255) / 256, 256, 0, stream>>>(x, linW, linB, h);

  const float invE = 1.0f / (float)NE;
  const float invN = 1.0f / (float)NN;
  const int edgeBlocks = NE / 64;             // 6250
  const int nodeBlocks = (NN + 63) / 64;      // 782

  for (int l = 0; l < 4; ++l) {
    float* st0 = stats + (l * 4 + 0) * 128;
    float* st1 = stats + (l * 4 + 1) * 128;
    float* st2 = stats + (l * 4 + 2) * 128;
    float* st3 = stats + (l * 4 + 3) * 128;

    // t1 = m_in @ msgW1 + b1 ; stats(st0)
    gemm_bn<132, 0><<<edgeBlocks, 256, 0, stream>>>(
        h, edge_attr, srcI, dstI,
        msgW1 + (size_t)l * 132 * 64, msgB1 + l * 64,
        nullptr, nullptr, nullptr, 0.f,
        t1, st0, NE);

    // t1 = relu(bn(t1)) @ msgW2 + b2 (in-place) ; stats(st1)
    gemm_bn<64, 1><<<edgeBlocks, 256, 0, stream>>>(
        t1, nullptr, nullptr, nullptr,
        msgW2 + (size_t)l * 64 * 64, msgB2 + l * 64,
        st0, msgG1 + l * 64, msgBe1 + l * 64, invE,
        t1, st1, NE);

    hipMemsetAsync(aggr, 0, (size_t)NN * 64 * sizeof(float), stream);

    // aggr[dst] += relu(bn(t1))
    scatter_kernel<<<(NE * 16 + 255) / 256, 256, 0, stream>>>(
        t1, dstI, st1, msgG2 + l * 64, msgBe2 + l * 64, invE, aggr);

    // u1 = [h|aggr] @ updW1 + b1 ; stats(st2)
    gemm_bn<128, 2><<<nodeBlocks, 256, 0, stream>>>(
        h, aggr, nullptr, nullptr,
        updW1 + (size_t)l * 128 * 64, updB1 + l * 64,
        nullptr, nullptr, nullptr, 0.f,
        u1, st2, NN);

    // u1 = relu(bn(u1)) @ updW2 + b2 (in-place) ; stats(st3)
    gemm_bn<64, 1><<<nodeBlocks, 256, 0, stream>>>(
        u1, nullptr, nullptr, nullptr,
        updW2 + (size_t)l * 64 * 64, updB2 + l * 64,
        st2, updG1 + l * 64, updBe1 + l * 64, invN,
        u1, st3, NN);

    // h += relu(bn(u1))
    residual_kernel<<<(NN * 16 + 255) / 256, 256, 0, stream>>>(
        u1, st3, updG2 + l * 64, updBe2 + l * 64, invN, h);
  }

  pool_pred_kernel<<<NG, 256, 0, stream>>>(h, batch, predW, predB, (float*)d_out);
}

// Round 2
// 2396.403 us; speedup vs baseline: 1.4442x; 1.4442x over previous
//
#include <hip/hip_runtime.h>

#define DEV __device__ __forceinline__

constexpr int NN = 50000;   // nodes
constexpr int NE = 400000;  // edges
constexpr int NG = 32;      // graphs
constexpr float EPSV = 1e-5f;

// ---------------------------------------------------------------------------
// lin_in: h = x @ W(11x64) + b
// ---------------------------------------------------------------------------
__global__ __launch_bounds__(256) void lin_in_kernel(
    const float* __restrict__ x, const float* __restrict__ W,
    const float* __restrict__ b, float* __restrict__ h)
{
  int gid = blockIdx.x * 256 + threadIdx.x;
  if (gid >= NN * 64) return;
  int n = gid >> 6, c = gid & 63;
  float acc = b[c];
#pragma unroll
  for (int k = 0; k < 11; ++k)
    acc = fmaf(x[n * 11 + k], W[k * 64 + c], acc);
  h[gid] = acc;
}

DEV void fma4(float acc[4], float a, const float4& bv) {
  acc[0] = fmaf(a, bv.x, acc[0]);
  acc[1] = fmaf(a, bv.y, acc[1]);
  acc[2] = fmaf(a, bv.z, acc[2]);
  acc[3] = fmaf(a, bv.w, acc[3]);
}

// ---------------------------------------------------------------------------
// CSR build: histogram of dst -> exclusive scan -> edge-id fill
// ---------------------------------------------------------------------------
__global__ __launch_bounds__(256) void hist_kernel(
    const int* __restrict__ dstI, int* __restrict__ deg)
{
  int e = blockIdx.x * 256 + threadIdx.x;
  if (e < NE) atomicAdd(&deg[dstI[e]], 1);
}

__global__ __launch_bounds__(256) void scan_kernel(
    const int* __restrict__ deg, int* __restrict__ rowptr)
{
  // single block of 256 threads; each thread owns a contiguous chunk
  __shared__ int part[256];
  constexpr int CH = (NN + 255) / 256;  // 196
  int tid = threadIdx.x;
  int base = tid * CH;
  int sum = 0;
  for (int i = 0; i < CH; ++i) {
    int idx = base + i;
    if (idx < NN) sum += deg[idx];
  }
  part[tid] = sum;
  __syncthreads();
  for (int off = 1; off < 256; off <<= 1) {
    int v = 0;
    if (tid >= off) v = part[tid - off];
    __syncthreads();
    if (tid >= off) part[tid] += v;
    __syncthreads();
  }
  int run = (tid == 0) ? 0 : part[tid - 1];
  for (int i = 0; i < CH; ++i) {
    int idx = base + i;
    if (idx < NN) { rowptr[idx] = run; run += deg[idx]; }
  }
  if (tid == 255) rowptr[NN] = run;
}

__global__ __launch_bounds__(256) void fill_kernel(
    const int* __restrict__ dstI, const int* __restrict__ rowptr,
    int* __restrict__ cursor, int* __restrict__ eid)
{
  int e = blockIdx.x * 256 + threadIdx.x;
  if (e < NE) {
    int d = dstI[e];
    int pos = rowptr[d] + atomicAdd(&cursor[d], 1);
    eid[pos] = e;
  }
}

// ---------------------------------------------------------------------------
// Tiled GEMM with fused input-BN (mode 1) / edge gather (mode 0) /
// node concat (mode 2), bias add, and BN-stats accumulation epilogue.
// Tile: 64 rows x 64 cols, 256 threads, 4x4 accum per thread.
// ---------------------------------------------------------------------------
template <int K, int MODE>
__global__ __launch_bounds__(256) void gemm_bn(
    const float* __restrict__ A0,
    const float* __restrict__ A1,
    const int* __restrict__ srcI,
    const int* __restrict__ dstI,
    const float* __restrict__ W,      // K x 64
    const float* __restrict__ bias,   // 64
    const float* __restrict__ inStats,// sum[64], sumsq[64] of producer
    const float* __restrict__ inG,
    const float* __restrict__ inBe,
    float invM_in,
    float* __restrict__ outp,         // M x 64
    float* __restrict__ outStats,     // sum[64], sumsq[64]
    int M)
{
  constexpr int LDA = K + 8;          // rows 16B-aligned, stagger banks
  __shared__ float A_s[64 * LDA];
  __shared__ float scale_s[64];
  __shared__ float shift_s[64];
  __shared__ float red_s[128];

  const int tid = threadIdx.x;
  const int rbase = blockIdx.x * 64;

  if (MODE == 1) {
    if (tid < 64) {
      float mean = inStats[tid] * invM_in;
      float var = inStats[64 + tid] * invM_in - mean * mean;
      float sc = inG[tid] * rsqrtf(var + EPSV);
      scale_s[tid] = sc;
      shift_s[tid] = inBe[tid] - mean * sc;
    }
    __syncthreads();
#pragma unroll
    for (int i = 0; i < 4; ++i) {
      int row = (tid >> 4) + i * 16;
      int c = (tid & 15) * 4;
      int r = rbase + row;
      float4 v = make_float4(0.f, 0.f, 0.f, 0.f);
      if (r < M) v = *(const float4*)&A0[(size_t)r * 64 + c];
      v.x = fmaxf(fmaf(scale_s[c + 0], v.x, shift_s[c + 0]), 0.f);
      v.y = fmaxf(fmaf(scale_s[c + 1], v.y, shift_s[c + 1]), 0.f);
      v.z = fmaxf(fmaf(scale_s[c + 2], v.z, shift_s[c + 2]), 0.f);
      v.w = fmaxf(fmaf(scale_s[c + 3], v.w, shift_s[c + 3]), 0.f);
      *(float4*)&A_s[row * LDA + c] = v;
    }
  } else if (MODE == 0) {
    int e_loc = tid >> 2;
    int quad = tid & 3;
    int e = rbase + e_loc;
    int si = srcI[e];
    int di = dstI[e];
#pragma unroll
    for (int q = 0; q < 4; ++q) {
      int c = quad * 16 + q * 4;
      *(float4*)&A_s[e_loc * LDA + c] = *(const float4*)&A0[(size_t)di * 64 + c];
      *(float4*)&A_s[e_loc * LDA + 64 + c] = *(const float4*)&A0[(size_t)si * 64 + c];
    }
    if (quad == 0)
      *(float4*)&A_s[e_loc * LDA + 128] = *(const float4*)&A1[(size_t)e * 4];
  } else {  // MODE 2
    int n_loc = tid >> 2;
    int quad = tid & 3;
    int n = rbase + n_loc;
    bool ok = n < M;
#pragma unroll
    for (int q = 0; q < 4; ++q) {
      int c = quad * 16 + q * 4;
      float4 va = make_float4(0.f, 0.f, 0.f, 0.f);
      float4 vb = make_float4(0.f, 0.f, 0.f, 0.f);
      if (ok) {
        va = *(const float4*)&A0[(size_t)n * 64 + c];
        vb = *(const float4*)&A1[(size_t)n * 64 + c];
      }
      *(float4*)&A_s[n_loc * LDA + c] = va;
      *(float4*)&A_s[n_loc * LDA + 64 + c] = vb;
    }
  }
  __syncthreads();

  const int col_g = tid & 15;
  const int row_g = tid >> 4;
  const int c0 = col_g * 4;
  const int r0 = row_g * 4;

  float acc[4][4];
#pragma unroll
  for (int i = 0; i < 4; ++i)
#pragma unroll
    for (int j = 0; j < 4; ++j) acc[i][j] = 0.f;

  for (int k = 0; k < K; k += 4) {
    float4 a0 = *(const float4*)&A_s[(r0 + 0) * LDA + k];
    float4 a1 = *(const float4*)&A_s[(r0 + 1) * LDA + k];
    float4 a2 = *(const float4*)&A_s[(r0 + 2) * LDA + k];
    float4 a3 = *(const float4*)&A_s[(r0 + 3) * LDA + k];
    float4 b0 = *(const float4*)&W[(k + 0) * 64 + c0];
    float4 b1 = *(const float4*)&W[(k + 1) * 64 + c0];
    float4 b2 = *(const float4*)&W[(k + 2) * 64 + c0];
    float4 b3 = *(const float4*)&W[(k + 3) * 64 + c0];
    fma4(acc[0], a0.x, b0); fma4(acc[0], a0.y, b1); fma4(acc[0], a0.z, b2); fma4(acc[0], a0.w, b3);
    fma4(acc[1], a1.x, b0); fma4(acc[1], a1.y, b1); fma4(acc[1], a1.z, b2); fma4(acc[1], a1.w, b3);
    fma4(acc[2], a2.x, b0); fma4(acc[2], a2.y, b1); fma4(acc[2], a2.z, b2); fma4(acc[2], a2.w, b3);
    fma4(acc[3], a3.x, b0); fma4(acc[3], a3.y, b1); fma4(acc[3], a3.z, b2); fma4(acc[3], a3.w, b3);
  }

  // epilogue: +bias, store, per-column sum / sumsq
  float4 bv = *(const float4*)&bias[c0];
  float s[4] = {0.f, 0.f, 0.f, 0.f};
  float s2[4] = {0.f, 0.f, 0.f, 0.f};
#pragma unroll
  for (int i = 0; i < 4; ++i) {
    int r = rbase + r0 + i;
    if (r < M) {
      float y0 = acc[i][0] + bv.x;
      float y1 = acc[i][1] + bv.y;
      float y2 = acc[i][2] + bv.z;
      float y3 = acc[i][3] + bv.w;
      float4 o;
      o.x = y0; o.y = y1; o.z = y2; o.w = y3;
      *(float4*)&outp[(size_t)r * 64 + c0] = o;
      s[0] += y0; s2[0] += y0 * y0;
      s[1] += y1; s2[1] += y1 * y1;
      s[2] += y2; s2[2] += y2 * y2;
      s[3] += y3; s2[3] += y3 * y3;
    }
  }
#pragma unroll
  for (int j = 0; j < 4; ++j) {
    s[j] += __shfl_xor(s[j], 16, 64);
    s[j] += __shfl_xor(s[j], 32, 64);
    s2[j] += __shfl_xor(s2[j], 16, 64);
    s2[j] += __shfl_xor(s2[j], 32, 64);
  }
  if (tid < 128) red_s[tid] = 0.f;
  __syncthreads();
  if ((tid & 63) < 16) {
#pragma unroll
    for (int j = 0; j < 4; ++j) {
      atomicAdd(&red_s[c0 + j], s[j]);
      atomicAdd(&red_s[64 + c0 + j], s2[j]);
    }
  }
  __syncthreads();
  if (tid < 128) atomicAdd(&outStats[tid], red_s[tid]);
}

// ---------------------------------------------------------------------------
// aggregate: aggr[n] = sum over incoming edges e of relu(bn2(t1[e]))
// One wave per node, lane = channel. CSR gather — zero atomics.
// ---------------------------------------------------------------------------
__global__ __launch_bounds__(256) void aggregate_kernel(
    const float* __restrict__ t1, const int* __restrict__ rowptr,
    const int* __restrict__ eid, const float* __restrict__ stats,
    const float* __restrict__ g, const float* __restrict__ be,
    float invM, float* __restrict__ aggr)
{
  int node = (blockIdx.x * 256 + threadIdx.x) >> 6;
  int lane = threadIdx.x & 63;
  if (node >= NN) return;
  float mean = stats[lane] * invM;
  float var = stats[64 + lane] * invM - mean * mean;
  float sc = g[lane] * rsqrtf(var + EPSV);
  float sh = be[lane] - mean * sc;
  int lo = rowptr[node], hi = rowptr[node + 1];
  float acc = 0.f;
  for (int i = lo; i < hi; ++i) {
    int e = eid[i];
    acc += fmaxf(fmaf(sc, t1[(size_t)e * 64 + lane], sh), 0.f);
  }
  aggr[(size_t)node * 64 + lane] = acc;
}

// ---------------------------------------------------------------------------
// residual: h += relu(bn4(u2))
// ---------------------------------------------------------------------------
__global__ __launch_bounds__(256) void residual_kernel(
    const float* __restrict__ u2, const float* __restrict__ stats,
    const float* __restrict__ g, const float* __restrict__ be,
    float invM, float* __restrict__ h)
{
  int gid = blockIdx.x * 256 + threadIdx.x;
  if (gid >= NN * 16) return;
  int c = (gid & 15) * 4;
  float4 v = *(const float4*)&u2[(size_t)gid * 4];
  float4 hv = *(const float4*)&h[(size_t)gid * 4];
  float* vp = (float*)&v;
  float* hp = (float*)&hv;
#pragma unroll
  for (int j = 0; j < 4; ++j) {
    float mean = stats[c + j] * invM;
    float var = stats[64 + c + j] * invM - mean * mean;
    float sc = g[c + j] * rsqrtf(var + EPSV);
    float sh = be[c + j] - mean * sc;
    hp[j] += fmaxf(fmaf(sc, vp[j], sh), 0.f);
  }
  *(float4*)&h[(size_t)gid * 4] = hv;
}

// ---------------------------------------------------------------------------
// pool + prediction head (batch sorted -> binary-search ranges)
// ---------------------------------------------------------------------------
DEV int lower_bound_i(const int* __restrict__ a, int n, int v) {
  int lo = 0, hi = n;
  while (lo < hi) {
    int m = (lo + hi) >> 1;
    if (a[m] < v) lo = m + 1; else hi = m;
  }
  return lo;
}

__global__ __launch_bounds__(256) void pool_pred_kernel(
    const float* __restrict__ h, const int* __restrict__ batch,
    const float* __restrict__ predW, const float* __restrict__ predB,
    float* __restrict__ out)
{
  __shared__ int s_lo, s_hi;
  __shared__ float red[4][64];
  int g = blockIdx.x;
  int tid = threadIdx.x;
  if (tid == 0) {
    s_lo = lower_bound_i(batch, NN, g);
    s_hi = lower_bound_i(batch, NN, g + 1);
  }
  __syncthreads();
  int lo = s_lo, hi = s_hi;
  int c = tid & 63, sl = tid >> 6;
  float acc = 0.f;
  for (int n = lo + sl; n < hi; n += 4) acc += h[(size_t)n * 64 + c];
  red[sl][c] = acc;
  __syncthreads();
  if (tid < 64) {
    float v = red[0][tid] + red[1][tid] + red[2][tid] + red[3][tid];
    float cnt = (float)(hi - lo);
    cnt = fmaxf(cnt, 1.0f);
    float p = (v / cnt) * predW[tid];
#pragma unroll
    for (int off = 32; off > 0; off >>= 1) p += __shfl_down(p, off, 64);
    if (tid == 0) out[g] = p + predB[0];
  }
}

// ---------------------------------------------------------------------------
extern "C" void kernel_launch(void* const* d_in, const int* in_sizes, int n_in,
                              void* d_out, int out_size, void* d_ws, size_t ws_size,
                              hipStream_t stream)
{
  (void)in_sizes; (void)n_in; (void)out_size; (void)ws_size;

  const float* x        = (const float*)d_in[0];
  const float* edge_attr= (const float*)d_in[1];
  const int*   eidx     = (const int*)d_in[2];
  const int*   batch    = (const int*)d_in[3];
  const float* linW     = (const float*)d_in[4];
  const float* linB     = (const float*)d_in[5];
  const float* msgW1    = (const float*)d_in[6];
  const float* msgB1    = (const float*)d_in[7];
  const float* msgG1    = (const float*)d_in[8];
  const float* msgBe1   = (const float*)d_in[9];
  const float* msgW2    = (const float*)d_in[10];
  const float* msgB2    = (const float*)d_in[11];
  const float* msgG2    = (const float*)d_in[12];
  const float* msgBe2   = (const float*)d_in[13];
  const float* updW1    = (const float*)d_in[14];
  const float* updB1    = (const float*)d_in[15];
  const float* updG1    = (const float*)d_in[16];
  const float* updBe1   = (const float*)d_in[17];
  const float* updW2    = (const float*)d_in[18];
  const float* updB2    = (const float*)d_in[19];
  const float* updG2    = (const float*)d_in[20];
  const float* updBe2   = (const float*)d_in[21];
  const float* predW    = (const float*)d_in[22];
  const float* predB    = (const float*)d_in[23];

  const int* srcI = eidx;        // edge_index[0] = source
  const int* dstI = eidx + NE;   // edge_index[1] = target

  float* ws   = (float*)d_ws;
  float* h    = ws;                           // NN*64
  float* t1   = h + (size_t)NN * 64;          // NE*64 (t2 in-place)
  float* aggr = t1 + (size_t)NE * 64;         // NN*64
  float* u1   = aggr + (size_t)NN * 64;       // NN*64 (u2 in-place)
  float* stats= u1 + (size_t)NN * 64;         // 16 * 128
  int*   deg    = (int*)(stats + 16 * 128);   // NN
  int*   cursor = deg + NN;                   // NN
  int*   rowptr = cursor + NN;                // NN+1
  int*   eid    = rowptr + NN + 1;            // NE

  hipMemsetAsync(stats, 0, 16 * 128 * sizeof(float), stream);
  hipMemsetAsync(deg, 0, 2 * NN * sizeof(int), stream);  // deg + cursor

  // CSR of dst (built once; reused by all 4 layers)
  hist_kernel<<<(NE + 255) / 256, 256, 0, stream>>>(dstI, deg);
  scan_kernel<<<1, 256, 0, stream>>>(deg, rowptr);
  fill_kernel<<<(NE + 255) / 256, 256, 0, stream>>>(dstI, rowptr, cursor, eid);

  lin_in_kernel<<<(NN * 64 + 255) / 256, 256, 0, stream>>>(x, linW, linB, h);

  const float invE = 1.0f / (float)NE;
  const float invN = 1.0f / (float)NN;
  const int edgeBlocks = NE / 64;             // 6250
  const int nodeBlocks = (NN + 63) / 64;      // 782

  for (int l = 0; l < 4; ++l) {
    float* st0 = stats + (l * 4 + 0) * 128;
    float* st1 = stats + (l * 4 + 1) * 128;
    float* st2 = stats + (l * 4 + 2) * 128;
    float* st3 = stats + (l * 4 + 3) * 128;

    // t1 = m_in @ msgW1 + b1 ; stats(st0)
    gemm_bn<132, 0><<<edgeBlocks, 256, 0, stream>>>(
        h, edge_attr, srcI, dstI,
        msgW1 + (size_t)l * 132 * 64, msgB1 + l * 64,
        nullptr, nullptr, nullptr, 0.f,
        t1, st0, NE);

    // t1 = relu(bn(t1)) @ msgW2 + b2 (in-place) ; stats(st1)
    gemm_bn<64, 1><<<edgeBlocks, 256, 0, stream>>>(
        t1, nullptr, nullptr, nullptr,
        msgW2 + (size_t)l * 64 * 64, msgB2 + l * 64,
        st0, msgG1 + l * 64, msgBe1 + l * 64, invE,
        t1, st1, NE);

    // aggr[n] = sum_{e: dst[e]==n} relu(bn(t1[e]))   (CSR gather)
    aggregate_kernel<<<(NN * 64 + 255) / 256, 256, 0, stream>>>(
        t1, rowptr, eid, st1, msgG2 + l * 64, msgBe2 + l * 64, invE, aggr);

    // u1 = [h|aggr] @ updW1 + b1 ; stats(st2)
    gemm_bn<128, 2><<<nodeBlocks, 256, 0, stream>>>(
        h, aggr, nullptr, nullptr,
        updW1 + (size_t)l * 128 * 64, updB1 + l * 64,
        nullptr, nullptr, nullptr, 0.f,
        u1, st2, NN);

    // u1 = relu(bn(u1)) @ updW2 + b2 (in-place) ; stats(st3)
    gemm_bn<64, 1><<<nodeBlocks, 256, 0, stream>>>(
        u1, nullptr, nullptr, nullptr,
        updW2 + (size_t)l * 64 * 64, updB2 + l * 64,
        st2, updG1 + l * 64, updBe1 + l * 64, invN,
        u1, st3, NN);

    // h += relu(bn(u1))
    residual_kernel<<<(NN * 16 + 255) / 256, 256, 0, stream>>>(
        u1, st3, updG2 + l * 64, updBe2 + l * 64, invN, h);
  }

  pool_pred_kernel<<<NG, 256, 0, stream>>>(h, batch, predW, predB, (float*)d_out);
}

// Round 3
// 2033.895 us; speedup vs baseline: 1.7016x; 1.1782x over previous
//
#include <hip/hip_runtime.h>

#define DEV __device__ __forceinline__

constexpr int NN = 50000;   // nodes
constexpr int NE = 400000;  // edges
constexpr int NG = 32;      // graphs
constexpr float EPSV = 1e-5f;

// ---------------------------------------------------------------------------
// lin_in: h = x @ W(11x64) + b
// ---------------------------------------------------------------------------
__global__ __launch_bounds__(256) void lin_in_kernel(
    const float* __restrict__ x, const float* __restrict__ W,
    const float* __restrict__ b, float* __restrict__ h)
{
  int gid = blockIdx.x * 256 + threadIdx.x;
  if (gid >= NN * 64) return;
  int n = gid >> 6, c = gid & 63;
  float acc = b[c];
#pragma unroll
  for (int k = 0; k < 11; ++k)
    acc = fmaf(x[n * 11 + k], W[k * 64 + c], acc);
  h[gid] = acc;
}

DEV void fma4(float acc[4], float a, const float4& bv) {
  acc[0] = fmaf(a, bv.x, acc[0]);
  acc[1] = fmaf(a, bv.y, acc[1]);
  acc[2] = fmaf(a, bv.z, acc[2]);
  acc[3] = fmaf(a, bv.w, acc[3]);
}

// ---------------------------------------------------------------------------
// CSR build: histogram of dst -> exclusive scan -> edge-id fill
// ---------------------------------------------------------------------------
__global__ __launch_bounds__(256) void hist_kernel(
    const int* __restrict__ dstI, int* __restrict__ deg)
{
  int e = blockIdx.x * 256 + threadIdx.x;
  if (e < NE) atomicAdd(&deg[dstI[e]], 1);
}

__global__ __launch_bounds__(256) void scan_kernel(
    const int* __restrict__ deg, int* __restrict__ rowptr)
{
  __shared__ int part[256];
  constexpr int CH = (NN + 255) / 256;  // 196
  int tid = threadIdx.x;
  int base = tid * CH;
  int sum = 0;
  for (int i = 0; i < CH; ++i) {
    int idx = base + i;
    if (idx < NN) sum += deg[idx];
  }
  part[tid] = sum;
  __syncthreads();
  for (int off = 1; off < 256; off <<= 1) {
    int v = 0;
    if (tid >= off) v = part[tid - off];
    __syncthreads();
    if (tid >= off) part[tid] += v;
    __syncthreads();
  }
  int run = (tid == 0) ? 0 : part[tid - 1];
  for (int i = 0; i < CH; ++i) {
    int idx = base + i;
    if (idx < NN) { rowptr[idx] = run; run += deg[idx]; }
  }
  if (tid == 255) rowptr[NN] = run;
}

__global__ __launch_bounds__(256) void fill_kernel(
    const int* __restrict__ dstI, const int* __restrict__ rowptr,
    int* __restrict__ cursor, int* __restrict__ eid)
{
  int e = blockIdx.x * 256 + threadIdx.x;
  if (e < NE) {
    int d = dstI[e];
    int pos = rowptr[d] + atomicAdd(&cursor[d], 1);
    eid[pos] = e;
  }
}

// ---------------------------------------------------------------------------
// gemm_dual: Hd = h @ W[0:64], Hs = h @ W[64:128]  (W is the 132x64 msg_W1)
// 64-row tile, 256 threads, 4x4x2 acc. No bias, no stats (linear pieces).
// ---------------------------------------------------------------------------
__global__ __launch_bounds__(256) void gemm_dual(
    const float* __restrict__ h, const float* __restrict__ W,
    float* __restrict__ Hd, float* __restrict__ Hs)
{
  __shared__ float A_s[64 * 72];
  const int tid = threadIdx.x;
  const int rbase = blockIdx.x * 64;

  int n_loc = tid >> 2, quad = tid & 3;
  int n = rbase + n_loc;
  bool ok = n < NN;
#pragma unroll
  for (int q = 0; q < 4; ++q) {
    int c = quad * 16 + q * 4;
    float4 v = make_float4(0.f, 0.f, 0.f, 0.f);
    if (ok) v = *(const float4*)&h[(size_t)n * 64 + c];
    *(float4*)&A_s[n_loc * 72 + c] = v;
  }
  __syncthreads();

  const int c0 = (tid & 15) * 4;
  const int r0 = (tid >> 4) * 4;
  float ad[4][4], as_[4][4];
#pragma unroll
  for (int i = 0; i < 4; ++i)
#pragma unroll
    for (int j = 0; j < 4; ++j) { ad[i][j] = 0.f; as_[i][j] = 0.f; }

  for (int k = 0; k < 64; k += 2) {
    float4 bd0 = *(const float4*)&W[(k + 0) * 64 + c0];
    float4 bd1 = *(const float4*)&W[(k + 1) * 64 + c0];
    float4 bs0 = *(const float4*)&W[(64 + k + 0) * 64 + c0];
    float4 bs1 = *(const float4*)&W[(64 + k + 1) * 64 + c0];
#pragma unroll
    for (int i = 0; i < 4; ++i) {
      float a0 = A_s[(r0 + i) * 72 + k];
      float a1 = A_s[(r0 + i) * 72 + k + 1];
      fma4(ad[i], a0, bd0); fma4(ad[i], a1, bd1);
      fma4(as_[i], a0, bs0); fma4(as_[i], a1, bs1);
    }
  }
#pragma unroll
  for (int i = 0; i < 4; ++i) {
    int r = rbase + r0 + i;
    if (r < NN) {
      float4 od, os;
      od.x = ad[i][0]; od.y = ad[i][1]; od.z = ad[i][2]; od.w = ad[i][3];
      os.x = as_[i][0]; os.y = as_[i][1]; os.z = as_[i][2]; os.w = as_[i][3];
      *(float4*)&Hd[(size_t)r * 64 + c0] = od;
      *(float4*)&Hs[(size_t)r * 64 + c0] = os;
    }
  }
}

// ---------------------------------------------------------------------------
// edge_combine: t1[e] = Hd[dst[e]] + Hs[src[e]] + ea[e]@W_bot + b ; stats out
// 16 threads per edge (float4 per thread), grid-stride, W_bot in registers.
// ---------------------------------------------------------------------------
__global__ __launch_bounds__(256) void edge_combine(
    const float* __restrict__ Hd, const float* __restrict__ Hs,
    const float* __restrict__ ea, const int* __restrict__ srcI,
    const int* __restrict__ dstI, const float* __restrict__ Wb, // 4x64
    const float* __restrict__ bias, float* __restrict__ t1,
    float* __restrict__ outStats)
{
  __shared__ float red_s[128];
  const int tid = threadIdx.x;
  const int c0 = (tid & 15) * 4;
  const float4 bv = *(const float4*)&bias[c0];
  const float4 w0 = *(const float4*)&Wb[0 * 64 + c0];
  const float4 w1 = *(const float4*)&Wb[1 * 64 + c0];
  const float4 w2 = *(const float4*)&Wb[2 * 64 + c0];
  const float4 w3 = *(const float4*)&Wb[3 * 64 + c0];

  float s[4] = {0.f, 0.f, 0.f, 0.f};
  float s2[4] = {0.f, 0.f, 0.f, 0.f};

  int e0 = (blockIdx.x * 256 + tid) >> 4;
  int estep = (gridDim.x * 256) >> 4;
  for (int e = e0; e < NE; e += estep) {
    int si = srcI[e];
    int di = dstI[e];
    float4 av = *(const float4*)&ea[(size_t)e * 4];
    float4 hd = *(const float4*)&Hd[(size_t)di * 64 + c0];
    float4 hs = *(const float4*)&Hs[(size_t)si * 64 + c0];
    float4 y;
    y.x = hd.x + hs.x + bv.x + av.x * w0.x + av.y * w1.x + av.z * w2.x + av.w * w3.x;
    y.y = hd.y + hs.y + bv.y + av.x * w0.y + av.y * w1.y + av.z * w2.y + av.w * w3.y;
    y.z = hd.z + hs.z + bv.z + av.x * w0.z + av.y * w1.z + av.z * w2.z + av.w * w3.z;
    y.w = hd.w + hs.w + bv.w + av.x * w0.w + av.y * w1.w + av.z * w2.w + av.w * w3.w;
    *(float4*)&t1[(size_t)e * 64 + c0] = y;
    s[0] += y.x; s2[0] += y.x * y.x;
    s[1] += y.y; s2[1] += y.y * y.y;
    s[2] += y.z; s2[2] += y.z * y.z;
    s[3] += y.w; s2[3] += y.w * y.w;
  }
#pragma unroll
  for (int j = 0; j < 4; ++j) {
    s[j] += __shfl_xor(s[j], 16, 64);
    s[j] += __shfl_xor(s[j], 32, 64);
    s2[j] += __shfl_xor(s2[j], 16, 64);
    s2[j] += __shfl_xor(s2[j], 32, 64);
  }
  if (tid < 128) red_s[tid] = 0.f;
  __syncthreads();
  if ((tid & 63) < 16) {
#pragma unroll
    for (int j = 0; j < 4; ++j) {
      atomicAdd(&red_s[c0 + j], s[j]);
      atomicAdd(&red_s[64 + c0 + j], s2[j]);
    }
  }
  __syncthreads();
  if (tid < 128) atomicAdd(&outStats[tid], red_s[tid]);
}

// ---------------------------------------------------------------------------
// gemm64_bn: out = relu(bn(A)) @ W(64x64) + b, W staged in LDS, stats out.
// In-place (out == A) safe: block reads only its own rows before writing.
// ---------------------------------------------------------------------------
__global__ __launch_bounds__(256) void gemm64_bn(
    const float* __restrict__ A0,
    const float* __restrict__ W,      // 64 x 64
    const float* __restrict__ bias,
    const float* __restrict__ inStats,
    const float* __restrict__ inG,
    const float* __restrict__ inBe,
    float invM_in,
    float* __restrict__ outp,
    float* __restrict__ outStats,
    int M)
{
  __shared__ float A_s[64 * 72];
  __shared__ float W_s[64 * 64];
  __shared__ float scale_s[64];
  __shared__ float shift_s[64];
  __shared__ float red_s[128];

  const int tid = threadIdx.x;
  const int rbase = blockIdx.x * 64;

  if (tid < 64) {
    float mean = inStats[tid] * invM_in;
    float var = inStats[64 + tid] * invM_in - mean * mean;
    float sc = inG[tid] * rsqrtf(var + EPSV);
    scale_s[tid] = sc;
    shift_s[tid] = inBe[tid] - mean * sc;
  }
  // stage W: 4096 floats = 1024 float4, 4 per thread
#pragma unroll
  for (int i = 0; i < 4; ++i) {
    int idx = (i * 256 + tid) * 4;
    *(float4*)&W_s[idx] = *(const float4*)&W[idx];
  }
  __syncthreads();

#pragma unroll
  for (int i = 0; i < 4; ++i) {
    int row = (tid >> 4) + i * 16;
    int c = (tid & 15) * 4;
    int r = rbase + row;
    float4 v = make_float4(0.f, 0.f, 0.f, 0.f);
    if (r < M) v = *(const float4*)&A0[(size_t)r * 64 + c];
    v.x = fmaxf(fmaf(scale_s[c + 0], v.x, shift_s[c + 0]), 0.f);
    v.y = fmaxf(fmaf(scale_s[c + 1], v.y, shift_s[c + 1]), 0.f);
    v.z = fmaxf(fmaf(scale_s[c + 2], v.z, shift_s[c + 2]), 0.f);
    v.w = fmaxf(fmaf(scale_s[c + 3], v.w, shift_s[c + 3]), 0.f);
    *(float4*)&A_s[row * 72 + c] = v;
  }
  __syncthreads();

  const int c0 = (tid & 15) * 4;
  const int r0 = (tid >> 4) * 4;

  float acc[4][4];
#pragma unroll
  for (int i = 0; i < 4; ++i)
#pragma unroll
    for (int j = 0; j < 4; ++j) acc[i][j] = 0.f;

  for (int k = 0; k < 64; k += 4) {
    float4 a0 = *(const float4*)&A_s[(r0 + 0) * 72 + k];
    float4 a1 = *(const float4*)&A_s[(r0 + 1) * 72 + k];
    float4 a2 = *(const float4*)&A_s[(r0 + 2) * 72 + k];
    float4 a3 = *(const float4*)&A_s[(r0 + 3) * 72 + k];
    float4 b0 = *(const float4*)&W_s[(k + 0) * 64 + c0];
    float4 b1 = *(const float4*)&W_s[(k + 1) * 64 + c0];
    float4 b2 = *(const float4*)&W_s[(k + 2) * 64 + c0];
    float4 b3 = *(const float4*)&W_s[(k + 3) * 64 + c0];
    fma4(acc[0], a0.x, b0); fma4(acc[0], a0.y, b1); fma4(acc[0], a0.z, b2); fma4(acc[0], a0.w, b3);
    fma4(acc[1], a1.x, b0); fma4(acc[1], a1.y, b1); fma4(acc[1], a1.z, b2); fma4(acc[1], a1.w, b3);
    fma4(acc[2], a2.x, b0); fma4(acc[2], a2.y, b1); fma4(acc[2], a2.z, b2); fma4(acc[2], a2.w, b3);
    fma4(acc[3], a3.x, b0); fma4(acc[3], a3.y, b1); fma4(acc[3], a3.z, b2); fma4(acc[3], a3.w, b3);
  }

  float4 bv = *(const float4*)&bias[c0];
  float s[4] = {0.f, 0.f, 0.f, 0.f};
  float s2[4] = {0.f, 0.f, 0.f, 0.f};
#pragma unroll
  for (int i = 0; i < 4; ++i) {
    int r = rbase + r0 + i;
    if (r < M) {
      float y0 = acc[i][0] + bv.x;
      float y1 = acc[i][1] + bv.y;
      float y2 = acc[i][2] + bv.z;
      float y3 = acc[i][3] + bv.w;
      float4 o;
      o.x = y0; o.y = y1; o.z = y2; o.w = y3;
      *(float4*)&outp[(size_t)r * 64 + c0] = o;
      s[0] += y0; s2[0] += y0 * y0;
      s[1] += y1; s2[1] += y1 * y1;
      s[2] += y2; s2[2] += y2 * y2;
      s[3] += y3; s2[3] += y3 * y3;
    }
  }
#pragma unroll
  for (int j = 0; j < 4; ++j) {
    s[j] += __shfl_xor(s[j], 16, 64);
    s[j] += __shfl_xor(s[j], 32, 64);
    s2[j] += __shfl_xor(s2[j], 16, 64);
    s2[j] += __shfl_xor(s2[j], 32, 64);
  }
  if (tid < 128) red_s[tid] = 0.f;
  __syncthreads();
  if ((tid & 63) < 16) {
#pragma unroll
    for (int j = 0; j < 4; ++j) {
      atomicAdd(&red_s[c0 + j], s[j]);
      atomicAdd(&red_s[64 + c0 + j], s2[j]);
    }
  }
  __syncthreads();
  if (tid < 128) atomicAdd(&outStats[tid], red_s[tid]);
}

// ---------------------------------------------------------------------------
// gemm_concat_bn: u1 = [h|aggr] @ W(128x64) + b ; stats out. (W from global)
// ---------------------------------------------------------------------------
__global__ __launch_bounds__(256) void gemm_concat_bn(
    const float* __restrict__ A0,
    const float* __restrict__ A1,
    const float* __restrict__ W,      // 128 x 64
    const float* __restrict__ bias,
    float* __restrict__ outp,
    float* __restrict__ outStats,
    int M)
{
  constexpr int LDA = 136;
  __shared__ float A_s[64 * LDA];
  __shared__ float red_s[128];

  const int tid = threadIdx.x;
  const int rbase = blockIdx.x * 64;

  int n_loc = tid >> 2, quad = tid & 3;
  int n = rbase + n_loc;
  bool ok = n < M;
#pragma unroll
  for (int q = 0; q < 4; ++q) {
    int c = quad * 16 + q * 4;
    float4 va = make_float4(0.f, 0.f, 0.f, 0.f);
    float4 vb = make_float4(0.f, 0.f, 0.f, 0.f);
    if (ok) {
      va = *(const float4*)&A0[(size_t)n * 64 + c];
      vb = *(const float4*)&A1[(size_t)n * 64 + c];
    }
    *(float4*)&A_s[n_loc * LDA + c] = va;
    *(float4*)&A_s[n_loc * LDA + 64 + c] = vb;
  }
  __syncthreads();

  const int c0 = (tid & 15) * 4;
  const int r0 = (tid >> 4) * 4;

  float acc[4][4];
#pragma unroll
  for (int i = 0; i < 4; ++i)
#pragma unroll
    for (int j = 0; j < 4; ++j) acc[i][j] = 0.f;

  for (int k = 0; k < 128; k += 4) {
    float4 a0 = *(const float4*)&A_s[(r0 + 0) * LDA + k];
    float4 a1 = *(const float4*)&A_s[(r0 + 1) * LDA + k];
    float4 a2 = *(const float4*)&A_s[(r0 + 2) * LDA + k];
    float4 a3 = *(const float4*)&A_s[(r0 + 3) * LDA + k];
    float4 b0 = *(const float4*)&W[(k + 0) * 64 + c0];
    float4 b1 = *(const float4*)&W[(k + 1) * 64 + c0];
    float4 b2 = *(const float4*)&W[(k + 2) * 64 + c0];
    float4 b3 = *(const float4*)&W[(k + 3) * 64 + c0];
    fma4(acc[0], a0.x, b0); fma4(acc[0], a0.y, b1); fma4(acc[0], a0.z, b2); fma4(acc[0], a0.w, b3);
    fma4(acc[1], a1.x, b0); fma4(acc[1], a1.y, b1); fma4(acc[1], a1.z, b2); fma4(acc[1], a1.w, b3);
    fma4(acc[2], a2.x, b0); fma4(acc[2], a2.y, b1); fma4(acc[2], a2.z, b2); fma4(acc[2], a2.w, b3);
    fma4(acc[3], a3.x, b0); fma4(acc[3], a3.y, b1); fma4(acc[3], a3.z, b2); fma4(acc[3], a3.w, b3);
  }

  float4 bv = *(const float4*)&bias[c0];
  float s[4] = {0.f, 0.f, 0.f, 0.f};
  float s2[4] = {0.f, 0.f, 0.f, 0.f};
#pragma unroll
  for (int i = 0; i < 4; ++i) {
    int r = rbase + r0 + i;
    if (r < M) {
      float y0 = acc[i][0] + bv.x;
      float y1 = acc[i][1] + bv.y;
      float y2 = acc[i][2] + bv.z;
      float y3 = acc[i][3] + bv.w;
      float4 o;
      o.x = y0; o.y = y1; o.z = y2; o.w = y3;
      *(float4*)&outp[(size_t)r * 64 + c0] = o;
      s[0] += y0; s2[0] += y0 * y0;
      s[1] += y1; s2[1] += y1 * y1;
      s[2] += y2; s2[2] += y2 * y2;
      s[3] += y3; s2[3] += y3 * y3;
    }
  }
#pragma unroll
  for (int j = 0; j < 4; ++j) {
    s[j] += __shfl_xor(s[j], 16, 64);
    s[j] += __shfl_xor(s[j], 32, 64);
    s2[j] += __shfl_xor(s2[j], 16, 64);
    s2[j] += __shfl_xor(s2[j], 32, 64);
  }
  if (tid < 128) red_s[tid] = 0.f;
  __syncthreads();
  if ((tid & 63) < 16) {
#pragma unroll
    for (int j = 0; j < 4; ++j) {
      atomicAdd(&red_s[c0 + j], s[j]);
      atomicAdd(&red_s[64 + c0 + j], s2[j]);
    }
  }
  __syncthreads();
  if (tid < 128) atomicAdd(&outStats[tid], red_s[tid]);
}

// ---------------------------------------------------------------------------
// aggregate: aggr[n] = sum_{e in CSR(n)} relu(bn(t1[e]))
// ---------------------------------------------------------------------------
__global__ __launch_bounds__(256) void aggregate_kernel(
    const float* __restrict__ t1, const int* __restrict__ rowptr,
    const int* __restrict__ eid, const float* __restrict__ stats,
    const float* __restrict__ g, const float* __restrict__ be,
    float invM, float* __restrict__ aggr)
{
  int node = (blockIdx.x * 256 + threadIdx.x) >> 6;
  int lane = threadIdx.x & 63;
  if (node >= NN) return;
  float mean = stats[lane] * invM;
  float var = stats[64 + lane] * invM - mean * mean;
  float sc = g[lane] * rsqrtf(var + EPSV);
  float sh = be[lane] - mean * sc;
  int lo = rowptr[node], hi = rowptr[node + 1];
  float acc = 0.f;
  for (int i = lo; i < hi; ++i) {
    int e = eid[i];
    acc += fmaxf(fmaf(sc, t1[(size_t)e * 64 + lane], sh), 0.f);
  }
  aggr[(size_t)node * 64 + lane] = acc;
}

// ---------------------------------------------------------------------------
// residual: h += relu(bn(u2))
// ---------------------------------------------------------------------------
__global__ __launch_bounds__(256) void residual_kernel(
    const float* __restrict__ u2, const float* __restrict__ stats,
    const float* __restrict__ g, const float* __restrict__ be,
    float invM, float* __restrict__ h)
{
  int gid = blockIdx.x * 256 + threadIdx.x;
  if (gid >= NN * 16) return;
  int c = (gid & 15) * 4;
  float4 v = *(const float4*)&u2[(size_t)gid * 4];
  float4 hv = *(const float4*)&h[(size_t)gid * 4];
  float* vp = (float*)&v;
  float* hp = (float*)&hv;
#pragma unroll
  for (int j = 0; j < 4; ++j) {
    float mean = stats[c + j] * invM;
    float var = stats[64 + c + j] * invM - mean * mean;
    float sc = g[c + j] * rsqrtf(var + EPSV);
    float sh = be[c + j] - mean * sc;
    hp[j] += fmaxf(fmaf(sc, vp[j], sh), 0.f);
  }
  *(float4*)&h[(size_t)gid * 4] = hv;
}

// ---------------------------------------------------------------------------
// pool + prediction head (batch sorted -> binary-search ranges)
// ---------------------------------------------------------------------------
DEV int lower_bound_i(const int* __restrict__ a, int n, int v) {
  int lo = 0, hi = n;
  while (lo < hi) {
    int m = (lo + hi) >> 1;
    if (a[m] < v) lo = m + 1; else hi = m;
  }
  return lo;
}

__global__ __launch_bounds__(256) void pool_pred_kernel(
    const float* __restrict__ h, const int* __restrict__ batch,
    const float* __restrict__ predW, const float* __restrict__ predB,
    float* __restrict__ out)
{
  __shared__ int s_lo, s_hi;
  __shared__ float red[4][64];
  int g = blockIdx.x;
  int tid = threadIdx.x;
  if (tid == 0) {
    s_lo = lower_bound_i(batch, NN, g);
    s_hi = lower_bound_i(batch, NN, g + 1);
  }
  __syncthreads();
  int lo = s_lo, hi = s_hi;
  int c = tid & 63, sl = tid >> 6;
  float acc = 0.f;
  for (int n = lo + sl; n < hi; n += 4) acc += h[(size_t)n * 64 + c];
  red[sl][c] = acc;
  __syncthreads();
  if (tid < 64) {
    float v = red[0][tid] + red[1][tid] + red[2][tid] + red[3][tid];
    float cnt = (float)(hi - lo);
    cnt = fmaxf(cnt, 1.0f);
    float p = (v / cnt) * predW[tid];
#pragma unroll
    for (int off = 32; off > 0; off >>= 1) p += __shfl_down(p, off, 64);
    if (tid == 0) out[g] = p + predB[0];
  }
}

// ---------------------------------------------------------------------------
extern "C" void kernel_launch(void* const* d_in, const int* in_sizes, int n_in,
                              void* d_out, int out_size, void* d_ws, size_t ws_size,
                              hipStream_t stream)
{
  (void)in_sizes; (void)n_in; (void)out_size; (void)ws_size;

  const float* x        = (const float*)d_in[0];
  const float* edge_attr= (const float*)d_in[1];
  const int*   eidx     = (const int*)d_in[2];
  const int*   batch    = (const int*)d_in[3];
  const float* linW     = (const float*)d_in[4];
  const float* linB     = (const float*)d_in[5];
  const float* msgW1    = (const float*)d_in[6];
  const float* msgB1    = (const float*)d_in[7];
  const float* msgG1    = (const float*)d_in[8];
  const float* msgBe1   = (const float*)d_in[9];
  const float* msgW2    = (const float*)d_in[10];
  const float* msgB2    = (const float*)d_in[11];
  const float* msgG2    = (const float*)d_in[12];
  const float* msgBe2   = (const float*)d_in[13];
  const float* updW1    = (const float*)d_in[14];
  const float* updB1    = (const float*)d_in[15];
  const float* updG1    = (const float*)d_in[16];
  const float* updBe1   = (const float*)d_in[17];
  const float* updW2    = (const float*)d_in[18];
  const float* updB2    = (const float*)d_in[19];
  const float* updG2    = (const float*)d_in[20];
  const float* updBe2   = (const float*)d_in[21];
  const float* predW    = (const float*)d_in[22];
  const float* predB    = (const float*)d_in[23];

  const int* srcI = eidx;        // edge_index[0] = source
  const int* dstI = eidx + NE;   // edge_index[1] = target

  float* ws   = (float*)d_ws;
  float* h    = ws;                           // NN*64
  float* t1   = h + (size_t)NN * 64;          // NE*64 (t2 in-place)
  float* aggr = t1 + (size_t)NE * 64;         // NN*64 (aliases Hd)
  float* u1   = aggr + (size_t)NN * 64;       // NN*64 (aliases Hs; u2 in-place)
  float* stats= u1 + (size_t)NN * 64;         // 16 * 128
  int*   deg    = (int*)(stats + 16 * 128);   // NN
  int*   cursor = deg + NN;                   // NN
  int*   rowptr = cursor + NN;                // NN+1
  int*   eid    = rowptr + NN + 1;            // NE

  float* Hd = aggr;   // Hd dead before aggregate_kernel writes aggr
  float* Hs = u1;     // Hs dead before gemm_concat_bn writes u1

  hipMemsetAsync(stats, 0, 16 * 128 * sizeof(float), stream);
  hipMemsetAsync(deg, 0, 2 * NN * sizeof(int), stream);  // deg + cursor

  hist_kernel<<<(NE + 255) / 256, 256, 0, stream>>>(dstI, deg);
  scan_kernel<<<1, 256, 0, stream>>>(deg, rowptr);
  fill_kernel<<<(NE + 255) / 256, 256, 0, stream>>>(dstI, rowptr, cursor, eid);

  lin_in_kernel<<<(NN * 64 + 255) / 256, 256, 0, stream>>>(x, linW, linB, h);

  const float invE = 1.0f / (float)NE;
  const float invN = 1.0f / (float)NN;
  const int edgeBlocks = NE / 64;             // 6250
  const int nodeBlocks = (NN + 63) / 64;      // 782

  for (int l = 0; l < 4; ++l) {
    float* st0 = stats + (l * 4 + 0) * 128;
    float* st1 = stats + (l * 4 + 1) * 128;
    float* st2 = stats + (l * 4 + 2) * 128;
    float* st3 = stats + (l * 4 + 3) * 128;
    const float* W1 = msgW1 + (size_t)l * 132 * 64;

    // Hd = h @ W1[0:64], Hs = h @ W1[64:128]
    gemm_dual<<<nodeBlocks, 256, 0, stream>>>(h, W1, Hd, Hs);

    // t1[e] = Hd[dst] + Hs[src] + ea@W1[128:132] + b1 ; stats(st0)
    edge_combine<<<2048, 256, 0, stream>>>(
        Hd, Hs, edge_attr, srcI, dstI, W1 + 128 * 64, msgB1 + l * 64,
        t1, st0);

    // t1 = relu(bn(t1)) @ msgW2 + b2 (in-place) ; stats(st1)
    gemm64_bn<<<edgeBlocks, 256, 0, stream>>>(
        t1, msgW2 + (size_t)l * 64 * 64, msgB2 + l * 64,
        st0, msgG1 + l * 64, msgBe1 + l * 64, invE,
        t1, st1, NE);

    // aggr[n] = sum relu(bn(t1)) over incoming edges (CSR gather)
    aggregate_kernel<<<(NN * 64 + 255) / 256, 256, 0, stream>>>(
        t1, rowptr, eid, st1, msgG2 + l * 64, msgBe2 + l * 64, invE, aggr);

    // u1 = [h|aggr] @ updW1 + b1 ; stats(st2)
    gemm_concat_bn<<<nodeBlocks, 256, 0, stream>>>(
        h, aggr, updW1 + (size_t)l * 128 * 64, updB1 + l * 64,
        u1, st2, NN);

    // u1 = relu(bn(u1)) @ updW2 + b2 (in-place) ; stats(st3)
    gemm64_bn<<<nodeBlocks, 256, 0, stream>>>(
        u1, updW2 + (size_t)l * 64 * 64, updB2 + l * 64,
        st2, updG1 + l * 64, updBe1 + l * 64, invN,
        u1, st3, NN);

    // h += relu(bn(u1))
    residual_kernel<<<(NN * 16 + 255) / 256, 256, 0, stream>>>(
        u1, st3, updG2 + l * 64, updBe2 + l * 64, invN, h);
  }

  pool_pred_kernel<<<NG, 256, 0, stream>>>(h, batch, predW, predB, (float*)d_out);
}

// Round 4
// 1592.457 us; speedup vs baseline: 2.1732x; 1.2772x over previous
//
#include <hip/hip_runtime.h>

#define DEV __device__ __forceinline__

constexpr int NN = 50000;   // nodes
constexpr int NE = 400000;  // edges
constexpr int NG = 32;      // graphs
constexpr float EPSV = 1e-5f;

typedef __attribute__((ext_vector_type(8))) short s16x8;
typedef __attribute__((ext_vector_type(4))) float f32x4;

DEV unsigned short f2b(float f) {  // fp32 -> bf16 RNE (finite inputs)
  union { float f; unsigned u; } x; x.f = f;
  unsigned r = x.u + 0x7fffu + ((x.u >> 16) & 1u);
  return (unsigned short)(r >> 16);
}
DEV float b2f(unsigned short u) {
  union { unsigned u; float f; } x; x.u = ((unsigned)u) << 16; return x.f;
}

// ---------------------------------------------------------------------------
// lin_in: h = x @ W(11x64) + b
// ---------------------------------------------------------------------------
__global__ __launch_bounds__(256) void lin_in_kernel(
    const float* __restrict__ x, const float* __restrict__ W,
    const float* __restrict__ b, float* __restrict__ h)
{
  int gid = blockIdx.x * 256 + threadIdx.x;
  if (gid >= NN * 64) return;
  int n = gid >> 6, c = gid & 63;
  float acc = b[c];
#pragma unroll
  for (int k = 0; k < 11; ++k)
    acc = fmaf(x[n * 11 + k], W[k * 64 + c], acc);
  h[gid] = acc;
}

DEV void fma4(float acc[4], float a, const float4& bv) {
  acc[0] = fmaf(a, bv.x, acc[0]);
  acc[1] = fmaf(a, bv.y, acc[1]);
  acc[2] = fmaf(a, bv.z, acc[2]);
  acc[3] = fmaf(a, bv.w, acc[3]);
}

// ---------------------------------------------------------------------------
// CSR build: histogram of dst -> exclusive scan -> edge-id fill
// ---------------------------------------------------------------------------
__global__ __launch_bounds__(256) void hist_kernel(
    const int* __restrict__ dstI, int* __restrict__ deg)
{
  int e = blockIdx.x * 256 + threadIdx.x;
  if (e < NE) atomicAdd(&deg[dstI[e]], 1);
}

__global__ __launch_bounds__(256) void scan_kernel(
    const int* __restrict__ deg, int* __restrict__ rowptr)
{
  __shared__ int part[256];
  constexpr int CH = (NN + 255) / 256;  // 196
  int tid = threadIdx.x;
  int base = tid * CH;
  int sum = 0;
  for (int i = 0; i < CH; ++i) {
    int idx = base + i;
    if (idx < NN) sum += deg[idx];
  }
  part[tid] = sum;
  __syncthreads();
  for (int off = 1; off < 256; off <<= 1) {
    int v = 0;
    if (tid >= off) v = part[tid - off];
    __syncthreads();
    if (tid >= off) part[tid] += v;
    __syncthreads();
  }
  int run = (tid == 0) ? 0 : part[tid - 1];
  for (int i = 0; i < CH; ++i) {
    int idx = base + i;
    if (idx < NN) { rowptr[idx] = run; run += deg[idx]; }
  }
  if (tid == 255) rowptr[NN] = run;
}

__global__ __launch_bounds__(256) void fill_kernel(
    const int* __restrict__ dstI, const int* __restrict__ rowptr,
    int* __restrict__ cursor, int* __restrict__ eid)
{
  int e = blockIdx.x * 256 + threadIdx.x;
  if (e < NE) {
    int d = dstI[e];
    int pos = rowptr[d] + atomicAdd(&cursor[d], 1);
    eid[pos] = e;
  }
}

// ---------------------------------------------------------------------------
// gemm_dual: Hd = h @ W[0:64], Hs = h @ W[64:128] (bf16 outputs)
// ---------------------------------------------------------------------------
__global__ __launch_bounds__(256) void gemm_dual(
    const float* __restrict__ h, const float* __restrict__ W,
    unsigned short* __restrict__ Hd, unsigned short* __restrict__ Hs)
{
  __shared__ float A_s[64 * 72];
  const int tid = threadIdx.x;
  const int rbase = blockIdx.x * 64;

  int n_loc = tid >> 2, quad = tid & 3;
  int n = rbase + n_loc;
  bool ok = n < NN;
#pragma unroll
  for (int q = 0; q < 4; ++q) {
    int c = quad * 16 + q * 4;
    float4 v = make_float4(0.f, 0.f, 0.f, 0.f);
    if (ok) v = *(const float4*)&h[(size_t)n * 64 + c];
    *(float4*)&A_s[n_loc * 72 + c] = v;
  }
  __syncthreads();

  const int c0 = (tid & 15) * 4;
  const int r0 = (tid >> 4) * 4;
  float ad[4][4], as_[4][4];
#pragma unroll
  for (int i = 0; i < 4; ++i)
#pragma unroll
    for (int j = 0; j < 4; ++j) { ad[i][j] = 0.f; as_[i][j] = 0.f; }

  for (int k = 0; k < 64; k += 2) {
    float4 bd0 = *(const float4*)&W[(k + 0) * 64 + c0];
    float4 bd1 = *(const float4*)&W[(k + 1) * 64 + c0];
    float4 bs0 = *(const float4*)&W[(64 + k + 0) * 64 + c0];
    float4 bs1 = *(const float4*)&W[(64 + k + 1) * 64 + c0];
#pragma unroll
    for (int i = 0; i < 4; ++i) {
      float a0 = A_s[(r0 + i) * 72 + k];
      float a1 = A_s[(r0 + i) * 72 + k + 1];
      fma4(ad[i], a0, bd0); fma4(ad[i], a1, bd1);
      fma4(as_[i], a0, bs0); fma4(as_[i], a1, bs1);
    }
  }
#pragma unroll
  for (int i = 0; i < 4; ++i) {
    int r = rbase + r0 + i;
    if (r < NN) {
      ushort4 od, os;
      od.x = f2b(ad[i][0]); od.y = f2b(ad[i][1]);
      od.z = f2b(ad[i][2]); od.w = f2b(ad[i][3]);
      os.x = f2b(as_[i][0]); os.y = f2b(as_[i][1]);
      os.z = f2b(as_[i][2]); os.w = f2b(as_[i][3]);
      *(ushort4*)&Hd[(size_t)r * 64 + c0] = od;
      *(ushort4*)&Hs[(size_t)r * 64 + c0] = os;
    }
  }
}

// ---------------------------------------------------------------------------
// edge_combine: t1[e] = Hd[dst[e]] + Hs[src[e]] + ea[e]@W_bot + b (bf16 out)
// stats (fp32) accumulated pre-rounding.
// ---------------------------------------------------------------------------
__global__ __launch_bounds__(256) void edge_combine(
    const unsigned short* __restrict__ Hd, const unsigned short* __restrict__ Hs,
    const float* __restrict__ ea, const int* __restrict__ srcI,
    const int* __restrict__ dstI, const float* __restrict__ Wb, // 4x64
    const float* __restrict__ bias, unsigned short* __restrict__ t1,
    float* __restrict__ outStats)
{
  __shared__ float red_s[128];
  const int tid = threadIdx.x;
  const int c0 = (tid & 15) * 4;
  const float4 bv = *(const float4*)&bias[c0];
  const float4 w0 = *(const float4*)&Wb[0 * 64 + c0];
  const float4 w1 = *(const float4*)&Wb[1 * 64 + c0];
  const float4 w2 = *(const float4*)&Wb[2 * 64 + c0];
  const float4 w3 = *(const float4*)&Wb[3 * 64 + c0];

  float s[4] = {0.f, 0.f, 0.f, 0.f};
  float s2[4] = {0.f, 0.f, 0.f, 0.f};

  int e0 = (blockIdx.x * 256 + tid) >> 4;
  int estep = (gridDim.x * 256) >> 4;
  for (int e = e0; e < NE; e += estep) {
    int si = srcI[e];
    int di = dstI[e];
    float4 av = *(const float4*)&ea[(size_t)e * 4];
    ushort4 hd4 = *(const ushort4*)&Hd[(size_t)di * 64 + c0];
    ushort4 hs4 = *(const ushort4*)&Hs[(size_t)si * 64 + c0];
    float4 y;
    y.x = b2f(hd4.x) + b2f(hs4.x) + bv.x + av.x * w0.x + av.y * w1.x + av.z * w2.x + av.w * w3.x;
    y.y = b2f(hd4.y) + b2f(hs4.y) + bv.y + av.x * w0.y + av.y * w1.y + av.z * w2.y + av.w * w3.y;
    y.z = b2f(hd4.z) + b2f(hs4.z) + bv.z + av.x * w0.z + av.y * w1.z + av.z * w2.z + av.w * w3.z;
    y.w = b2f(hd4.w) + b2f(hs4.w) + bv.w + av.x * w0.w + av.y * w1.w + av.z * w2.w + av.w * w3.w;
    ushort4 o;
    o.x = f2b(y.x); o.y = f2b(y.y); o.z = f2b(y.z); o.w = f2b(y.w);
    *(ushort4*)&t1[(size_t)e * 64 + c0] = o;
    s[0] += y.x; s2[0] += y.x * y.x;
    s[1] += y.y; s2[1] += y.y * y.y;
    s[2] += y.z; s2[2] += y.z * y.z;
    s[3] += y.w; s2[3] += y.w * y.w;
  }
#pragma unroll
  for (int j = 0; j < 4; ++j) {
    s[j] += __shfl_xor(s[j], 16, 64);
    s[j] += __shfl_xor(s[j], 32, 64);
    s2[j] += __shfl_xor(s2[j], 16, 64);
    s2[j] += __shfl_xor(s2[j], 32, 64);
  }
  if (tid < 128) red_s[tid] = 0.f;
  __syncthreads();
  if ((tid & 63) < 16) {
#pragma unroll
    for (int j = 0; j < 4; ++j) {
      atomicAdd(&red_s[c0 + j], s[j]);
      atomicAdd(&red_s[64 + c0 + j], s2[j]);
    }
  }
  __syncthreads();
  if (tid < 128) atomicAdd(&outStats[tid], red_s[tid]);
}

// ---------------------------------------------------------------------------
// gemm64_bn_mfma: t2 = relu(bn(t1)) @ W(64x64) + b  — bf16 in/out, MFMA.
// Block = 256 thr = 4 waves, each wave: 32 rows x 64 cols.
// A-frags loaded straight from global (16B/lane), BN+ReLU fused in unpack.
// W transposed to LDS as bf16 once per block. Stats epilogue fp32.
// In-place safe (wave reads only its own rows before storing) — no
// __restrict__ on A0/outp since they alias.
// M must be a multiple of 128.
// ---------------------------------------------------------------------------
__global__ __launch_bounds__(256) void gemm64_bn_mfma(
    const unsigned short* A0,         // bf16 M x 64
    const float* __restrict__ W,      // 64 x 64 fp32
    const float* __restrict__ bias,
    const float* __restrict__ inStats,
    const float* __restrict__ inG,
    const float* __restrict__ inBe,
    float invM_in,
    unsigned short* outp,             // bf16 M x 64
    float* __restrict__ outStats,
    int M)
{
  __shared__ unsigned short Wt_s[64 * 72];  // Wt[n][k], pad 72 (2-way free)
  __shared__ float scale_s[64];
  __shared__ float shift_s[64];
  __shared__ float red_s[128];

  const int tid = threadIdx.x;
  const int lane = tid & 63;
  const int wave = tid >> 6;
  const int nn = lane & 15;   // n (or m) within 16-tile
  const int kq = lane >> 4;   // k-octet index (0..3)

  if (tid < 64) {
    float mean = inStats[tid] * invM_in;
    float var = inStats[64 + tid] * invM_in - mean * mean;
    float sc = inG[tid] * rsqrtf(var + EPSV);
    scale_s[tid] = sc;
    shift_s[tid] = inBe[tid] - mean * sc;
  }
#pragma unroll
  for (int i = 0; i < 16; ++i) {       // stage W^T as bf16
    int idx = i * 256 + tid;           // 4096 elements
    int k = idx >> 6, n = idx & 63;
    Wt_s[n * 72 + k] = f2b(W[idx]);
  }
  __syncthreads();

  // B-frags: [n-tile][k-chunk], 8 contiguous bf16 each
  s16x8 bfrag[4][2];
#pragma unroll
  for (int nt = 0; nt < 4; ++nt)
#pragma unroll
    for (int kc = 0; kc < 2; ++kc) {
      const unsigned short* p = &Wt_s[(nt * 16 + nn) * 72 + kc * 32 + kq * 8];
#pragma unroll
      for (int j = 0; j < 8; ++j) bfrag[nt][kc][j] = (short)p[j];
    }

  // per-lane BN scale/shift for its 8 k-values per chunk
  float scf[2][8], shf[2][8];
#pragma unroll
  for (int kc = 0; kc < 2; ++kc)
#pragma unroll
    for (int j = 0; j < 8; ++j) {
      int k = kc * 32 + kq * 8 + j;
      scf[kc][j] = scale_s[k];
      shf[kc][j] = shift_s[k];
    }

  const int rbase = blockIdx.x * 128 + wave * 32;

  f32x4 acc[2][4];
#pragma unroll
  for (int rt = 0; rt < 2; ++rt)
#pragma unroll
    for (int nt = 0; nt < 4; ++nt) acc[rt][nt] = (f32x4){0.f, 0.f, 0.f, 0.f};

#pragma unroll
  for (int rt = 0; rt < 2; ++rt) {
    int row = rbase + rt * 16 + nn;
#pragma unroll
    for (int kc = 0; kc < 2; ++kc) {
      uint4 raw = *(const uint4*)&A0[(size_t)row * 64 + kc * 32 + kq * 8];
      unsigned wbits[4] = {raw.x, raw.y, raw.z, raw.w};
      s16x8 af;
#pragma unroll
      for (int d = 0; d < 4; ++d) {
        union { unsigned u; float f; } lo, hi;
        lo.u = (wbits[d] & 0xffffu) << 16;
        hi.u = wbits[d] & 0xffff0000u;
        int j0 = d * 2, j1 = d * 2 + 1;
        af[j0] = (short)f2b(fmaxf(fmaf(scf[kc][j0], lo.f, shf[kc][j0]), 0.f));
        af[j1] = (short)f2b(fmaxf(fmaf(scf[kc][j1], hi.f, shf[kc][j1]), 0.f));
      }
#pragma unroll
      for (int nt = 0; nt < 4; ++nt)
        acc[rt][nt] = __builtin_amdgcn_mfma_f32_16x16x32_bf16(
            af, bfrag[nt][kc], acc[rt][nt], 0, 0, 0);
    }
  }

  // epilogue: +bias, bf16 store, fp32 stats
  float bcol[4];
#pragma unroll
  for (int nt = 0; nt < 4; ++nt) bcol[nt] = bias[nt * 16 + nn];

  float s[4] = {0.f, 0.f, 0.f, 0.f};
  float s2[4] = {0.f, 0.f, 0.f, 0.f};
#pragma unroll
  for (int rt = 0; rt < 2; ++rt)
#pragma unroll
    for (int nt = 0; nt < 4; ++nt) {
      int col = nt * 16 + nn;
#pragma unroll
      for (int reg = 0; reg < 4; ++reg) {
        float y = acc[rt][nt][reg] + bcol[nt];
        int row = rbase + rt * 16 + kq * 4 + reg;
        outp[(size_t)row * 64 + col] = f2b(y);
        s[nt] += y; s2[nt] += y * y;
      }
    }
#pragma unroll
  for (int nt = 0; nt < 4; ++nt) {
    s[nt] += __shfl_xor(s[nt], 16, 64);
    s[nt] += __shfl_xor(s[nt], 32, 64);
    s2[nt] += __shfl_xor(s2[nt], 16, 64);
    s2[nt] += __shfl_xor(s2[nt], 32, 64);
  }
  if (tid < 128) red_s[tid] = 0.f;
  __syncthreads();
  if (lane < 16) {
#pragma unroll
    for (int nt = 0; nt < 4; ++nt) {
      atomicAdd(&red_s[nt * 16 + nn], s[nt]);
      atomicAdd(&red_s[64 + nt * 16 + nn], s2[nt]);
    }
  }
  __syncthreads();
  if (tid < 128) atomicAdd(&outStats[tid], red_s[tid]);
}

// ---------------------------------------------------------------------------
// gemm64_bn (fp32, node-side): out = relu(bn(A)) @ W + b, W in LDS.
// ---------------------------------------------------------------------------
__global__ __launch_bounds__(256) void gemm64_bn(
    const float* __restrict__ A0,
    const float* __restrict__ W,
    const float* __restrict__ bias,
    const float* __restrict__ inStats,
    const float* __restrict__ inG,
    const float* __restrict__ inBe,
    float invM_in,
    float* __restrict__ outp,
    float* __restrict__ outStats,
    int M)
{
  __shared__ float A_s[64 * 72];
  __shared__ float W_s[64 * 64];
  __shared__ float scale_s[64];
  __shared__ float shift_s[64];
  __shared__ float red_s[128];

  const int tid = threadIdx.x;
  const int rbase = blockIdx.x * 64;

  if (tid < 64) {
    float mean = inStats[tid] * invM_in;
    float var = inStats[64 + tid] * invM_in - mean * mean;
    float sc = inG[tid] * rsqrtf(var + EPSV);
    scale_s[tid] = sc;
    shift_s[tid] = inBe[tid] - mean * sc;
  }
#pragma unroll
  for (int i = 0; i < 4; ++i) {
    int idx = (i * 256 + tid) * 4;
    *(float4*)&W_s[idx] = *(const float4*)&W[idx];
  }
  __syncthreads();

#pragma unroll
  for (int i = 0; i < 4; ++i) {
    int row = (tid >> 4) + i * 16;
    int c = (tid & 15) * 4;
    int r = rbase + row;
    float4 v = make_float4(0.f, 0.f, 0.f, 0.f);
    if (r < M) v = *(const float4*)&A0[(size_t)r * 64 + c];
    v.x = fmaxf(fmaf(scale_s[c + 0], v.x, shift_s[c + 0]), 0.f);
    v.y = fmaxf(fmaf(scale_s[c + 1], v.y, shift_s[c + 1]), 0.f);
    v.z = fmaxf(fmaf(scale_s[c + 2], v.z, shift_s[c + 2]), 0.f);
    v.w = fmaxf(fmaf(scale_s[c + 3], v.w, shift_s[c + 3]), 0.f);
    *(float4*)&A_s[row * 72 + c] = v;
  }
  __syncthreads();

  const int c0 = (tid & 15) * 4;
  const int r0 = (tid >> 4) * 4;

  float acc[4][4];
#pragma unroll
  for (int i = 0; i < 4; ++i)
#pragma unroll
    for (int j = 0; j < 4; ++j) acc[i][j] = 0.f;

  for (int k = 0; k < 64; k += 4) {
    float4 a0 = *(const float4*)&A_s[(r0 + 0) * 72 + k];
    float4 a1 = *(const float4*)&A_s[(r0 + 1) * 72 + k];
    float4 a2 = *(const float4*)&A_s[(r0 + 2) * 72 + k];
    float4 a3 = *(const float4*)&A_s[(r0 + 3) * 72 + k];
    float4 b0 = *(const float4*)&W_s[(k + 0) * 64 + c0];
    float4 b1 = *(const float4*)&W_s[(k + 1) * 64 + c0];
    float4 b2 = *(const float4*)&W_s[(k + 2) * 64 + c0];
    float4 b3 = *(const float4*)&W_s[(k + 3) * 64 + c0];
    fma4(acc[0], a0.x, b0); fma4(acc[0], a0.y, b1); fma4(acc[0], a0.z, b2); fma4(acc[0], a0.w, b3);
    fma4(acc[1], a1.x, b0); fma4(acc[1], a1.y, b1); fma4(acc[1], a1.z, b2); fma4(acc[1], a1.w, b3);
    fma4(acc[2], a2.x, b0); fma4(acc[2], a2.y, b1); fma4(acc[2], a2.z, b2); fma4(acc[2], a2.w, b3);
    fma4(acc[3], a3.x, b0); fma4(acc[3], a3.y, b1); fma4(acc[3], a3.z, b2); fma4(acc[3], a3.w, b3);
  }

  float4 bv = *(const float4*)&bias[c0];
  float s[4] = {0.f, 0.f, 0.f, 0.f};
  float s2[4] = {0.f, 0.f, 0.f, 0.f};
#pragma unroll
  for (int i = 0; i < 4; ++i) {
    int r = rbase + r0 + i;
    if (r < M) {
      float y0 = acc[i][0] + bv.x;
      float y1 = acc[i][1] + bv.y;
      float y2 = acc[i][2] + bv.z;
      float y3 = acc[i][3] + bv.w;
      float4 o;
      o.x = y0; o.y = y1; o.z = y2; o.w = y3;
      *(float4*)&outp[(size_t)r * 64 + c0] = o;
      s[0] += y0; s2[0] += y0 * y0;
      s[1] += y1; s2[1] += y1 * y1;
      s[2] += y2; s2[2] += y2 * y2;
      s[3] += y3; s2[3] += y3 * y3;
    }
  }
#pragma unroll
  for (int j = 0; j < 4; ++j) {
    s[j] += __shfl_xor(s[j], 16, 64);
    s[j] += __shfl_xor(s[j], 32, 64);
    s2[j] += __shfl_xor(s2[j], 16, 64);
    s2[j] += __shfl_xor(s2[j], 32, 64);
  }
  if (tid < 128) red_s[tid] = 0.f;
  __syncthreads();
  if ((tid & 63) < 16) {
#pragma unroll
    for (int j = 0; j < 4; ++j) {
      atomicAdd(&red_s[c0 + j], s[j]);
      atomicAdd(&red_s[64 + c0 + j], s2[j]);
    }
  }
  __syncthreads();
  if (tid < 128) atomicAdd(&outStats[tid], red_s[tid]);
}

// ---------------------------------------------------------------------------
// gemm_concat_bn: u1 = [h|aggr] @ W(128x64) + b ; stats out (fp32)
// ---------------------------------------------------------------------------
__global__ __launch_bounds__(256) void gemm_concat_bn(
    const float* __restrict__ A0,
    const float* __restrict__ A1,
    const float* __restrict__ W,      // 128 x 64
    const float* __restrict__ bias,
    float* __restrict__ outp,
    float* __restrict__ outStats,
    int M)
{
  constexpr int LDA = 136;
  __shared__ float A_s[64 * LDA];
  __shared__ float red_s[128];

  const int tid = threadIdx.x;
  const int rbase = blockIdx.x * 64;

  int n_loc = tid >> 2, quad = tid & 3;
  int n = rbase + n_loc;
  bool ok = n < M;
#pragma unroll
  for (int q = 0; q < 4; ++q) {
    int c = quad * 16 + q * 4;
    float4 va = make_float4(0.f, 0.f, 0.f, 0.f);
    float4 vb = make_float4(0.f, 0.f, 0.f, 0.f);
    if (ok) {
      va = *(const float4*)&A0[(size_t)n * 64 + c];
      vb = *(const float4*)&A1[(size_t)n * 64 + c];
    }
    *(float4*)&A_s[n_loc * LDA + c] = va;
    *(float4*)&A_s[n_loc * LDA + 64 + c] = vb;
  }
  __syncthreads();

  const int c0 = (tid & 15) * 4;
  const int r0 = (tid >> 4) * 4;

  float acc[4][4];
#pragma unroll
  for (int i = 0; i < 4; ++i)
#pragma unroll
    for (int j = 0; j < 4; ++j) acc[i][j] = 0.f;

  for (int k = 0; k < 128; k += 4) {
    float4 a0 = *(const float4*)&A_s[(r0 + 0) * LDA + k];
    float4 a1 = *(const float4*)&A_s[(r0 + 1) * LDA + k];
    float4 a2 = *(const float4*)&A_s[(r0 + 2) * LDA + k];
    float4 a3 = *(const float4*)&A_s[(r0 + 3) * LDA + k];
    float4 b0 = *(const float4*)&W[(k + 0) * 64 + c0];
    float4 b1 = *(const float4*)&W[(k + 1) * 64 + c0];
    float4 b2 = *(const float4*)&W[(k + 2) * 64 + c0];
    float4 b3 = *(const float4*)&W[(k + 3) * 64 + c0];
    fma4(acc[0], a0.x, b0); fma4(acc[0], a0.y, b1); fma4(acc[0], a0.z, b2); fma4(acc[0], a0.w, b3);
    fma4(acc[1], a1.x, b0); fma4(acc[1], a1.y, b1); fma4(acc[1], a1.z, b2); fma4(acc[1], a1.w, b3);
    fma4(acc[2], a2.x, b0); fma4(acc[2], a2.y, b1); fma4(acc[2], a2.z, b2); fma4(acc[2], a2.w, b3);
    fma4(acc[3], a3.x, b0); fma4(acc[3], a3.y, b1); fma4(acc[3], a3.z, b2); fma4(acc[3], a3.w, b3);
  }

  float4 bv = *(const float4*)&bias[c0];
  float s[4] = {0.f, 0.f, 0.f, 0.f};
  float s2[4] = {0.f, 0.f, 0.f, 0.f};
#pragma unroll
  for (int i = 0; i < 4; ++i) {
    int r = rbase + r0 + i;
    if (r < M) {
      float y0 = acc[i][0] + bv.x;
      float y1 = acc[i][1] + bv.y;
      float y2 = acc[i][2] + bv.z;
      float y3 = acc[i][3] + bv.w;
      float4 o;
      o.x = y0; o.y = y1; o.z = y2; o.w = y3;
      *(float4*)&outp[(size_t)r * 64 + c0] = o;
      s[0] += y0; s2[0] += y0 * y0;
      s[1] += y1; s2[1] += y1 * y1;
      s[2] += y2; s2[2] += y2 * y2;
      s[3] += y3; s2[3] += y3 * y3;
    }
  }
#pragma unroll
  for (int j = 0; j < 4; ++j) {
    s[j] += __shfl_xor(s[j], 16, 64);
    s[j] += __shfl_xor(s[j], 32, 64);
    s2[j] += __shfl_xor(s2[j], 16, 64);
    s2[j] += __shfl_xor(s2[j], 32, 64);
  }
  if (tid < 128) red_s[tid] = 0.f;
  __syncthreads();
  if ((tid & 63) < 16) {
#pragma unroll
    for (int j = 0; j < 4; ++j) {
      atomicAdd(&red_s[c0 + j], s[j]);
      atomicAdd(&red_s[64 + c0 + j], s2[j]);
    }
  }
  __syncthreads();
  if (tid < 128) atomicAdd(&outStats[tid], red_s[tid]);
}

// ---------------------------------------------------------------------------
// aggregate: aggr[n] = sum_{e in CSR(n)} relu(bn(t2_bf16[e]))  (fp32 out)
// ---------------------------------------------------------------------------
__global__ __launch_bounds__(256) void aggregate_kernel(
    const unsigned short* __restrict__ t2, const int* __restrict__ rowptr,
    const int* __restrict__ eid, const float* __restrict__ stats,
    const float* __restrict__ g, const float* __restrict__ be,
    float invM, float* __restrict__ aggr)
{
  int node = (blockIdx.x * 256 + threadIdx.x) >> 6;
  int lane = threadIdx.x & 63;
  if (node >= NN) return;
  float mean = stats[lane] * invM;
  float var = stats[64 + lane] * invM - mean * mean;
  float sc = g[lane] * rsqrtf(var + EPSV);
  float sh = be[lane] - mean * sc;
  int lo = rowptr[node], hi = rowptr[node + 1];
  float acc = 0.f;
  for (int i = lo; i < hi; ++i) {
    int e = eid[i];
    acc += fmaxf(fmaf(sc, b2f(t2[(size_t)e * 64 + lane]), sh), 0.f);
  }
  aggr[(size_t)node * 64 + lane] = acc;
}

// ---------------------------------------------------------------------------
// residual: h += relu(bn(u2))
// ---------------------------------------------------------------------------
__global__ __launch_bounds__(256) void residual_kernel(
    const float* __restrict__ u2, const float* __restrict__ stats,
    const float* __restrict__ g, const float* __restrict__ be,
    float invM, float* __restrict__ h)
{
  int gid = blockIdx.x * 256 + threadIdx.x;
  if (gid >= NN * 16) return;
  int c = (gid & 15) * 4;
  float4 v = *(const float4*)&u2[(size_t)gid * 4];
  float4 hv = *(const float4*)&h[(size_t)gid * 4];
  float* vp = (float*)&v;
  float* hp = (float*)&hv;
#pragma unroll
  for (int j = 0; j < 4; ++j) {
    float mean = stats[c + j] * invM;
    float var = stats[64 + c + j] * invM - mean * mean;
    float sc = g[c + j] * rsqrtf(var + EPSV);
    float sh = be[c + j] - mean * sc;
    hp[j] += fmaxf(fmaf(sc, vp[j], sh), 0.f);
  }
  *(float4*)&h[(size_t)gid * 4] = hv;
}

// ---------------------------------------------------------------------------
// pool + prediction head (batch sorted -> binary-search ranges)
// ---------------------------------------------------------------------------
DEV int lower_bound_i(const int* __restrict__ a, int n, int v) {
  int lo = 0, hi = n;
  while (lo < hi) {
    int m = (lo + hi) >> 1;
    if (a[m] < v) lo = m + 1; else hi = m;
  }
  return lo;
}

__global__ __launch_bounds__(256) void pool_pred_kernel(
    const float* __restrict__ h, const int* __restrict__ batch,
    const float* __restrict__ predW, const float* __restrict__ predB,
    float* __restrict__ out)
{
  __shared__ int s_lo, s_hi;
  __shared__ float red[4][64];
  int g = blockIdx.x;
  int tid = threadIdx.x;
  if (tid == 0) {
    s_lo = lower_bound_i(batch, NN, g);
    s_hi = lower_bound_i(batch, NN, g + 1);
  }
  __syncthreads();
  int lo = s_lo, hi = s_hi;
  int c = tid & 63, sl = tid >> 6;
  float acc = 0.f;
  for (int n = lo + sl; n < hi; n += 4) acc += h[(size_t)n * 64 + c];
  red[sl][c] = acc;
  __syncthreads();
  if (tid < 64) {
    float v = red[0][tid] + red[1][tid] + red[2][tid] + red[3][tid];
    float cnt = (float)(hi - lo);
    cnt = fmaxf(cnt, 1.0f);
    float p = (v / cnt) * predW[tid];
#pragma unroll
    for (int off = 32; off > 0; off >>= 1) p += __shfl_down(p, off, 64);
    if (tid == 0) out[g] = p + predB[0];
  }
}

// ---------------------------------------------------------------------------
extern "C" void kernel_launch(void* const* d_in, const int* in_sizes, int n_in,
                              void* d_out, int out_size, void* d_ws, size_t ws_size,
                              hipStream_t stream)
{
  (void)in_sizes; (void)n_in; (void)out_size; (void)ws_size;

  const float* x        = (const float*)d_in[0];
  const float* edge_attr= (const float*)d_in[1];
  const int*   eidx     = (const int*)d_in[2];
  const int*   batch    = (const int*)d_in[3];
  const float* linW     = (const float*)d_in[4];
  const float* linB     = (const float*)d_in[5];
  const float* msgW1    = (const float*)d_in[6];
  const float* msgB1    = (const float*)d_in[7];
  const float* msgG1    = (const float*)d_in[8];
  const float* msgBe1   = (const float*)d_in[9];
  const float* msgW2    = (const float*)d_in[10];
  const float* msgB2    = (const float*)d_in[11];
  const float* msgG2    = (const float*)d_in[12];
  const float* msgBe2   = (const float*)d_in[13];
  const float* updW1    = (const float*)d_in[14];
  const float* updB1    = (const float*)d_in[15];
  const float* updG1    = (const float*)d_in[16];
  const float* updBe1   = (const float*)d_in[17];
  const float* updW2    = (const float*)d_in[18];
  const float* updB2    = (const float*)d_in[19];
  const float* updG2    = (const float*)d_in[20];
  const float* updBe2   = (const float*)d_in[21];
  const float* predW    = (const float*)d_in[22];
  const float* predB    = (const float*)d_in[23];

  const int* srcI = eidx;        // edge_index[0] = source
  const int* dstI = eidx + NE;   // edge_index[1] = target

  char* p = (char*)d_ws;
  float* h  = (float*)p;            p += (size_t)NN * 64 * 4;   // 12.8 MB
  unsigned short* t1 = (unsigned short*)p; p += (size_t)NE * 64 * 2; // 51.2 MB
  float* aggr = (float*)p;          p += (size_t)NN * 64 * 4;   // 12.8 MB
  float* u1 = (float*)p;            p += (size_t)NN * 64 * 4;   // 12.8 MB
  unsigned short* Hd = (unsigned short*)p; p += (size_t)NN * 64 * 2; // 6.4 MB
  unsigned short* Hs = (unsigned short*)p; p += (size_t)NN * 64 * 2; // 6.4 MB
  float* stats = (float*)p;         p += 16 * 128 * 4;
  int* deg = (int*)p;               p += (size_t)NN * 4;
  int* cursor = (int*)p;            p += (size_t)NN * 4;
  int* rowptr = (int*)p;            p += (size_t)(NN + 1) * 4;
  int* eid = (int*)p;               p += (size_t)NE * 4;

  hipMemsetAsync(stats, 0, 16 * 128 * sizeof(float), stream);
  hipMemsetAsync(deg, 0, 2 * NN * sizeof(int), stream);  // deg + cursor

  hist_kernel<<<(NE + 255) / 256, 256, 0, stream>>>(dstI, deg);
  scan_kernel<<<1, 256, 0, stream>>>(deg, rowptr);
  fill_kernel<<<(NE + 255) / 256, 256, 0, stream>>>(dstI, rowptr, cursor, eid);

  lin_in_kernel<<<(NN * 64 + 255) / 256, 256, 0, stream>>>(x, linW, linB, h);

  const float invE = 1.0f / (float)NE;
  const float invN = 1.0f / (float)NN;
  const int nodeBlocks = (NN + 63) / 64;      // 782

  for (int l = 0; l < 4; ++l) {
    float* st0 = stats + (l * 4 + 0) * 128;
    float* st1 = stats + (l * 4 + 1) * 128;
    float* st2 = stats + (l * 4 + 2) * 128;
    float* st3 = stats + (l * 4 + 3) * 128;
    const float* W1 = msgW1 + (size_t)l * 132 * 64;

    // Hd = h @ W1[0:64], Hs = h @ W1[64:128]  (bf16 out)
    gemm_dual<<<nodeBlocks, 256, 0, stream>>>(h, W1, Hd, Hs);

    // t1[e] = Hd[dst] + Hs[src] + ea@W1[128:132] + b1 (bf16) ; stats(st0)
    edge_combine<<<2048, 256, 0, stream>>>(
        Hd, Hs, edge_attr, srcI, dstI, W1 + 128 * 64, msgB1 + l * 64,
        t1, st0);

    // t1 = relu(bn(t1)) @ msgW2 + b2 (bf16, in-place, MFMA) ; stats(st1)
    gemm64_bn_mfma<<<NE / 128, 256, 0, stream>>>(
        t1, msgW2 + (size_t)l * 64 * 64, msgB2 + l * 64,
        st0, msgG1 + l * 64, msgBe1 + l * 64, invE,
        t1, st1, NE);

    // aggr[n] = sum relu(bn(t1)) over incoming edges (CSR gather, fp32)
    aggregate_kernel<<<(NN * 64 + 255) / 256, 256, 0, stream>>>(
        t1, rowptr, eid, st1, msgG2 + l * 64, msgBe2 + l * 64, invE, aggr);

    // u1 = [h|aggr] @ updW1 + b1 ; stats(st2)
    gemm_concat_bn<<<nodeBlocks, 256, 0, stream>>>(
        h, aggr, updW1 + (size_t)l * 128 * 64, updB1 + l * 64,
        u1, st2, NN);

    // u1 = relu(bn(u1)) @ updW2 + b2 (fp32, in-place) ; stats(st3)
    gemm64_bn<<<nodeBlocks, 256, 0, stream>>>(
        u1, updW2 + (size_t)l * 64 * 64, updB2 + l * 64,
        st2, updG1 + l * 64, updBe1 + l * 64, invN,
        u1, st3, NN);

    // h += relu(bn(u1))
    residual_kernel<<<(NN * 16 + 255) / 256, 256, 0, stream>>>(
        u1, st3, updG2 + l * 64, updBe2 + l * 64, invN, h);
  }

  pool_pred_kernel<<<NG, 256, 0, stream>>>(h, batch, predW, predB, (float*)d_out);
}

// Round 5
// 1290.820 us; speedup vs baseline: 2.6811x; 1.2337x over previous
//
#include <hip/hip_runtime.h>

#define DEV __device__ __forceinline__

constexpr int NN = 50000;   // nodes
constexpr int NE = 400000;  // edges
constexpr int NG = 32;      // graphs
constexpr float EPSV = 1e-5f;

typedef __attribute__((ext_vector_type(8))) short s16x8;
typedef __attribute__((ext_vector_type(4))) float f32x4;

DEV unsigned short f2b(float f) {  // fp32 -> bf16 RNE (finite inputs)
  union { float f; unsigned u; } x; x.f = f;
  unsigned r = x.u + 0x7fffu + ((x.u >> 16) & 1u);
  return (unsigned short)(r >> 16);
}
DEV float b2f(unsigned short u) {
  union { unsigned u; float f; } x; x.u = ((unsigned)u) << 16; return x.f;
}

DEV s16x8 frag_from_f32(const float* p) {
  const float4 v0 = *(const float4*)p;
  const float4 v1 = *(const float4*)(p + 4);
  s16x8 af;
  af[0] = (short)f2b(v0.x); af[1] = (short)f2b(v0.y);
  af[2] = (short)f2b(v0.z); af[3] = (short)f2b(v0.w);
  af[4] = (short)f2b(v1.x); af[5] = (short)f2b(v1.y);
  af[6] = (short)f2b(v1.z); af[7] = (short)f2b(v1.w);
  return af;
}

// ---------------------------------------------------------------------------
// lin_in: h = x @ W(11x64) + b
// ---------------------------------------------------------------------------
__global__ __launch_bounds__(256) void lin_in_kernel(
    const float* __restrict__ x, const float* __restrict__ W,
    const float* __restrict__ b, float* __restrict__ h)
{
  int gid = blockIdx.x * 256 + threadIdx.x;
  if (gid >= NN * 64) return;
  int n = gid >> 6, c = gid & 63;
  float acc = b[c];
#pragma unroll
  for (int k = 0; k < 11; ++k)
    acc = fmaf(x[n * 11 + k], W[k * 64 + c], acc);
  h[gid] = acc;
}

// ---------------------------------------------------------------------------
// CSR build: histogram of dst -> exclusive scan -> edge-id fill
// ---------------------------------------------------------------------------
__global__ __launch_bounds__(256) void hist_kernel(
    const int* __restrict__ dstI, int* __restrict__ deg)
{
  int e = blockIdx.x * 256 + threadIdx.x;
  if (e < NE) atomicAdd(&deg[dstI[e]], 1);
}

__global__ __launch_bounds__(256) void scan_kernel(
    const int* __restrict__ deg, int* __restrict__ rowptr)
{
  __shared__ int part[256];
  constexpr int CH = (NN + 255) / 256;  // 196
  int tid = threadIdx.x;
  int base = tid * CH;
  int sum = 0;
  for (int i = 0; i < CH; ++i) {
    int idx = base + i;
    if (idx < NN) sum += deg[idx];
  }
  part[tid] = sum;
  __syncthreads();
  for (int off = 1; off < 256; off <<= 1) {
    int v = 0;
    if (tid >= off) v = part[tid - off];
    __syncthreads();
    if (tid >= off) part[tid] += v;
    __syncthreads();
  }
  int run = (tid == 0) ? 0 : part[tid - 1];
  for (int i = 0; i < CH; ++i) {
    int idx = base + i;
    if (idx < NN) { rowptr[idx] = run; run += deg[idx]; }
  }
  if (tid == 255) rowptr[NN] = run;
}

__global__ __launch_bounds__(256) void fill_kernel(
    const int* __restrict__ dstI, const int* __restrict__ rowptr,
    int* __restrict__ cursor, int* __restrict__ eid)
{
  int e = blockIdx.x * 256 + threadIdx.x;
  if (e < NE) {
    int d = dstI[e];
    int pos = rowptr[d] + atomicAdd(&cursor[d], 1);
    eid[pos] = e;
  }
}

// ---------------------------------------------------------------------------
// gemm_dual_mfma: Hd = h @ W[0:64], Hs = h @ W[64:128] (bf16 out, MFMA)
// 256 thr = 4 waves, wave = 32 rows x 64 cols x 2 outputs.
// ---------------------------------------------------------------------------
__global__ __launch_bounds__(256) void gemm_dual_mfma(
    const float* __restrict__ h, const float* __restrict__ W, // 132x64
    unsigned short* __restrict__ Hd, unsigned short* __restrict__ Hs)
{
  __shared__ unsigned short Wt_s[2 * 64 * 72];  // [half][n][k]

  const int tid = threadIdx.x;
  const int lane = tid & 63;
  const int wave = tid >> 6;
  const int nn = lane & 15;
  const int kq = lane >> 4;

#pragma unroll
  for (int i = 0; i < 32; ++i) {
    int idx = i * 256 + tid;          // 8192 = 2*64*64
    int half = idx >> 12;
    int rem = idx & 4095;
    int k = rem >> 6, n = rem & 63;
    Wt_s[half * 4608 + n * 72 + k] = f2b(W[idx]);
  }
  __syncthreads();

  s16x8 bfrag[2][4][2];  // [out][nt][kc]
#pragma unroll
  for (int o = 0; o < 2; ++o)
#pragma unroll
    for (int nt = 0; nt < 4; ++nt)
#pragma unroll
      for (int kc = 0; kc < 2; ++kc) {
        const unsigned short* p =
            &Wt_s[o * 4608 + (nt * 16 + nn) * 72 + kc * 32 + kq * 8];
#pragma unroll
        for (int j = 0; j < 8; ++j) bfrag[o][nt][kc][j] = (short)p[j];
      }

  const int rbase = blockIdx.x * 128 + wave * 32;

  f32x4 acc[2][2][4];  // [out][rt][nt]
#pragma unroll
  for (int o = 0; o < 2; ++o)
#pragma unroll
    for (int rt = 0; rt < 2; ++rt)
#pragma unroll
      for (int nt = 0; nt < 4; ++nt) acc[o][rt][nt] = (f32x4){0.f, 0.f, 0.f, 0.f};

#pragma unroll
  for (int rt = 0; rt < 2; ++rt) {
    int row = rbase + rt * 16 + nn;
    int rowc = row < NN ? row : NN - 1;
#pragma unroll
    for (int kc = 0; kc < 2; ++kc) {
      s16x8 af = frag_from_f32(&h[(size_t)rowc * 64 + kc * 32 + kq * 8]);
#pragma unroll
      for (int o = 0; o < 2; ++o)
#pragma unroll
        for (int nt = 0; nt < 4; ++nt)
          acc[o][rt][nt] = __builtin_amdgcn_mfma_f32_16x16x32_bf16(
              af, bfrag[o][nt][kc], acc[o][rt][nt], 0, 0, 0);
    }
  }

#pragma unroll
  for (int rt = 0; rt < 2; ++rt)
#pragma unroll
    for (int nt = 0; nt < 4; ++nt) {
      int col = nt * 16 + nn;
#pragma unroll
      for (int reg = 0; reg < 4; ++reg) {
        int row = rbase + rt * 16 + kq * 4 + reg;
        if (row < NN) {
          Hd[(size_t)row * 64 + col] = f2b(acc[0][rt][nt][reg]);
          Hs[(size_t)row * 64 + col] = f2b(acc[1][rt][nt][reg]);
        }
      }
    }
}

// ---------------------------------------------------------------------------
// edge_combine: t1[e] = Hd[dst[e]] + Hs[src[e]] + ea[e]@W_bot + b (bf16 out)
// ---------------------------------------------------------------------------
__global__ __launch_bounds__(256) void edge_combine(
    const unsigned short* __restrict__ Hd, const unsigned short* __restrict__ Hs,
    const float* __restrict__ ea, const int* __restrict__ srcI,
    const int* __restrict__ dstI, const float* __restrict__ Wb, // 4x64
    const float* __restrict__ bias, unsigned short* __restrict__ t1,
    float* __restrict__ outStats)
{
  __shared__ float red_s[128];
  const int tid = threadIdx.x;
  const int c0 = (tid & 15) * 4;
  const float4 bv = *(const float4*)&bias[c0];
  const float4 w0 = *(const float4*)&Wb[0 * 64 + c0];
  const float4 w1 = *(const float4*)&Wb[1 * 64 + c0];
  const float4 w2 = *(const float4*)&Wb[2 * 64 + c0];
  const float4 w3 = *(const float4*)&Wb[3 * 64 + c0];

  float s[4] = {0.f, 0.f, 0.f, 0.f};
  float s2[4] = {0.f, 0.f, 0.f, 0.f};

  int e0 = (blockIdx.x * 256 + tid) >> 4;
  int estep = (gridDim.x * 256) >> 4;
  for (int e = e0; e < NE; e += estep) {
    int si = srcI[e];
    int di = dstI[e];
    float4 av = *(const float4*)&ea[(size_t)e * 4];
    ushort4 hd4 = *(const ushort4*)&Hd[(size_t)di * 64 + c0];
    ushort4 hs4 = *(const ushort4*)&Hs[(size_t)si * 64 + c0];
    float4 y;
    y.x = b2f(hd4.x) + b2f(hs4.x) + bv.x + av.x * w0.x + av.y * w1.x + av.z * w2.x + av.w * w3.x;
    y.y = b2f(hd4.y) + b2f(hs4.y) + bv.y + av.x * w0.y + av.y * w1.y + av.z * w2.y + av.w * w3.y;
    y.z = b2f(hd4.z) + b2f(hs4.z) + bv.z + av.x * w0.z + av.y * w1.z + av.z * w2.z + av.w * w3.z;
    y.w = b2f(hd4.w) + b2f(hs4.w) + bv.w + av.x * w0.w + av.y * w1.w + av.z * w2.w + av.w * w3.w;
    ushort4 o;
    o.x = f2b(y.x); o.y = f2b(y.y); o.z = f2b(y.z); o.w = f2b(y.w);
    *(ushort4*)&t1[(size_t)e * 64 + c0] = o;
    s[0] += y.x; s2[0] += y.x * y.x;
    s[1] += y.y; s2[1] += y.y * y.y;
    s[2] += y.z; s2[2] += y.z * y.z;
    s[3] += y.w; s2[3] += y.w * y.w;
  }
#pragma unroll
  for (int j = 0; j < 4; ++j) {
    s[j] += __shfl_xor(s[j], 16, 64);
    s[j] += __shfl_xor(s[j], 32, 64);
    s2[j] += __shfl_xor(s2[j], 16, 64);
    s2[j] += __shfl_xor(s2[j], 32, 64);
  }
  if (tid < 128) red_s[tid] = 0.f;
  __syncthreads();
  if ((tid & 63) < 16) {
#pragma unroll
    for (int j = 0; j < 4; ++j) {
      atomicAdd(&red_s[c0 + j], s[j]);
      atomicAdd(&red_s[64 + c0 + j], s2[j]);
    }
  }
  __syncthreads();
  if (tid < 128) atomicAdd(&outStats[tid], red_s[tid]);
}

// ---------------------------------------------------------------------------
// gemm64_bn_mfma (edge): t2 = relu(bn(t1)) @ W + b — bf16 in/out, in-place.
// M multiple of 128.
// ---------------------------------------------------------------------------
__global__ __launch_bounds__(256) void gemm64_bn_mfma(
    const unsigned short* A0,         // bf16 M x 64
    const float* __restrict__ W,      // 64 x 64 fp32
    const float* __restrict__ bias,
    const float* __restrict__ inStats,
    const float* __restrict__ inG,
    const float* __restrict__ inBe,
    float invM_in,
    unsigned short* outp,             // bf16 M x 64
    float* __restrict__ outStats,
    int M)
{
  __shared__ unsigned short Wt_s[64 * 72];
  __shared__ float scale_s[64];
  __shared__ float shift_s[64];
  __shared__ float red_s[128];

  const int tid = threadIdx.x;
  const int lane = tid & 63;
  const int wave = tid >> 6;
  const int nn = lane & 15;
  const int kq = lane >> 4;

  if (tid < 64) {
    float mean = inStats[tid] * invM_in;
    float var = inStats[64 + tid] * invM_in - mean * mean;
    float sc = inG[tid] * rsqrtf(var + EPSV);
    scale_s[tid] = sc;
    shift_s[tid] = inBe[tid] - mean * sc;
  }
#pragma unroll
  for (int i = 0; i < 16; ++i) {
    int idx = i * 256 + tid;
    int k = idx >> 6, n = idx & 63;
    Wt_s[n * 72 + k] = f2b(W[idx]);
  }
  __syncthreads();

  s16x8 bfrag[4][2];
#pragma unroll
  for (int nt = 0; nt < 4; ++nt)
#pragma unroll
    for (int kc = 0; kc < 2; ++kc) {
      const unsigned short* p = &Wt_s[(nt * 16 + nn) * 72 + kc * 32 + kq * 8];
#pragma unroll
      for (int j = 0; j < 8; ++j) bfrag[nt][kc][j] = (short)p[j];
    }

  float scf[2][8], shf[2][8];
#pragma unroll
  for (int kc = 0; kc < 2; ++kc)
#pragma unroll
    for (int j = 0; j < 8; ++j) {
      int k = kc * 32 + kq * 8 + j;
      scf[kc][j] = scale_s[k];
      shf[kc][j] = shift_s[k];
    }

  const int rbase = blockIdx.x * 128 + wave * 32;

  f32x4 acc[2][4];
#pragma unroll
  for (int rt = 0; rt < 2; ++rt)
#pragma unroll
    for (int nt = 0; nt < 4; ++nt) acc[rt][nt] = (f32x4){0.f, 0.f, 0.f, 0.f};

#pragma unroll
  for (int rt = 0; rt < 2; ++rt) {
    int row = rbase + rt * 16 + nn;
#pragma unroll
    for (int kc = 0; kc < 2; ++kc) {
      uint4 raw = *(const uint4*)&A0[(size_t)row * 64 + kc * 32 + kq * 8];
      unsigned wbits[4] = {raw.x, raw.y, raw.z, raw.w};
      s16x8 af;
#pragma unroll
      for (int d = 0; d < 4; ++d) {
        union { unsigned u; float f; } lo, hi;
        lo.u = (wbits[d] & 0xffffu) << 16;
        hi.u = wbits[d] & 0xffff0000u;
        int j0 = d * 2, j1 = d * 2 + 1;
        af[j0] = (short)f2b(fmaxf(fmaf(scf[kc][j0], lo.f, shf[kc][j0]), 0.f));
        af[j1] = (short)f2b(fmaxf(fmaf(scf[kc][j1], hi.f, shf[kc][j1]), 0.f));
      }
#pragma unroll
      for (int nt = 0; nt < 4; ++nt)
        acc[rt][nt] = __builtin_amdgcn_mfma_f32_16x16x32_bf16(
            af, bfrag[nt][kc], acc[rt][nt], 0, 0, 0);
    }
  }

  float bcol[4];
#pragma unroll
  for (int nt = 0; nt < 4; ++nt) bcol[nt] = bias[nt * 16 + nn];

  float s[4] = {0.f, 0.f, 0.f, 0.f};
  float s2[4] = {0.f, 0.f, 0.f, 0.f};
#pragma unroll
  for (int rt = 0; rt < 2; ++rt)
#pragma unroll
    for (int nt = 0; nt < 4; ++nt) {
      int col = nt * 16 + nn;
#pragma unroll
      for (int reg = 0; reg < 4; ++reg) {
        float y = acc[rt][nt][reg] + bcol[nt];
        int row = rbase + rt * 16 + kq * 4 + reg;
        outp[(size_t)row * 64 + col] = f2b(y);
        s[nt] += y; s2[nt] += y * y;
      }
    }
#pragma unroll
  for (int nt = 0; nt < 4; ++nt) {
    s[nt] += __shfl_xor(s[nt], 16, 64);
    s[nt] += __shfl_xor(s[nt], 32, 64);
    s2[nt] += __shfl_xor(s2[nt], 16, 64);
    s2[nt] += __shfl_xor(s2[nt], 32, 64);
  }
  if (tid < 128) red_s[tid] = 0.f;
  __syncthreads();
  if (lane < 16) {
#pragma unroll
    for (int nt = 0; nt < 4; ++nt) {
      atomicAdd(&red_s[nt * 16 + nn], s[nt]);
      atomicAdd(&red_s[64 + nt * 16 + nn], s2[nt]);
    }
  }
  __syncthreads();
  if (tid < 128) atomicAdd(&outStats[tid], red_s[tid]);
}

// ---------------------------------------------------------------------------
// gemm_concat_mfma: u1 = [h|aggr] @ W(128x64) + b (fp32 out) ; stats.
// ---------------------------------------------------------------------------
__global__ __launch_bounds__(256) void gemm_concat_mfma(
    const float* __restrict__ A0,     // h
    const float* __restrict__ A1,     // aggr
    const float* __restrict__ W,      // 128 x 64
    const float* __restrict__ bias,
    float* __restrict__ outp,         // u1 fp32
    float* __restrict__ outStats,
    int M)
{
  __shared__ unsigned short Wt_s[64 * 136];
  __shared__ float red_s[128];

  const int tid = threadIdx.x;
  const int lane = tid & 63;
  const int wave = tid >> 6;
  const int nn = lane & 15;
  const int kq = lane >> 4;

#pragma unroll
  for (int i = 0; i < 32; ++i) {
    int idx = i * 256 + tid;          // 8192
    int k = idx >> 6, n = idx & 63;
    Wt_s[n * 136 + k] = f2b(W[idx]);
  }
  __syncthreads();

  s16x8 bfrag[4][4];  // [nt][kc]
#pragma unroll
  for (int nt = 0; nt < 4; ++nt)
#pragma unroll
    for (int kc = 0; kc < 4; ++kc) {
      const unsigned short* p = &Wt_s[(nt * 16 + nn) * 136 + kc * 32 + kq * 8];
#pragma unroll
      for (int j = 0; j < 8; ++j) bfrag[nt][kc][j] = (short)p[j];
    }

  const int rbase = blockIdx.x * 128 + wave * 32;

  f32x4 acc[2][4];
#pragma unroll
  for (int rt = 0; rt < 2; ++rt)
#pragma unroll
    for (int nt = 0; nt < 4; ++nt) acc[rt][nt] = (f32x4){0.f, 0.f, 0.f, 0.f};

#pragma unroll
  for (int rt = 0; rt < 2; ++rt) {
    int row = rbase + rt * 16 + nn;
    int rowc = row < M ? row : M - 1;
#pragma unroll
    for (int kc = 0; kc < 4; ++kc) {
      const float* src = (kc < 2)
          ? &A0[(size_t)rowc * 64 + kc * 32 + kq * 8]
          : &A1[(size_t)rowc * 64 + (kc - 2) * 32 + kq * 8];
      s16x8 af = frag_from_f32(src);
#pragma unroll
      for (int nt = 0; nt < 4; ++nt)
        acc[rt][nt] = __builtin_amdgcn_mfma_f32_16x16x32_bf16(
            af, bfrag[nt][kc], acc[rt][nt], 0, 0, 0);
    }
  }

  float bcol[4];
#pragma unroll
  for (int nt = 0; nt < 4; ++nt) bcol[nt] = bias[nt * 16 + nn];

  float s[4] = {0.f, 0.f, 0.f, 0.f};
  float s2[4] = {0.f, 0.f, 0.f, 0.f};
#pragma unroll
  for (int rt = 0; rt < 2; ++rt)
#pragma unroll
    for (int nt = 0; nt < 4; ++nt) {
      int col = nt * 16 + nn;
#pragma unroll
      for (int reg = 0; reg < 4; ++reg) {
        int row = rbase + rt * 16 + kq * 4 + reg;
        if (row < M) {
          float y = acc[rt][nt][reg] + bcol[nt];
          outp[(size_t)row * 64 + col] = y;
          s[nt] += y; s2[nt] += y * y;
        }
      }
    }
#pragma unroll
  for (int nt = 0; nt < 4; ++nt) {
    s[nt] += __shfl_xor(s[nt], 16, 64);
    s[nt] += __shfl_xor(s[nt], 32, 64);
    s2[nt] += __shfl_xor(s2[nt], 16, 64);
    s2[nt] += __shfl_xor(s2[nt], 32, 64);
  }
  if (tid < 128) red_s[tid] = 0.f;
  __syncthreads();
  if (lane < 16) {
#pragma unroll
    for (int nt = 0; nt < 4; ++nt) {
      atomicAdd(&red_s[nt * 16 + nn], s[nt]);
      atomicAdd(&red_s[64 + nt * 16 + nn], s2[nt]);
    }
  }
  __syncthreads();
  if (tid < 128) atomicAdd(&outStats[tid], red_s[tid]);
}

// ---------------------------------------------------------------------------
// gemm64_node_mfma: u2 = relu(bn(u1)) @ W + b — fp32 in/out, in-place, MFMA.
// ---------------------------------------------------------------------------
__global__ __launch_bounds__(256) void gemm64_node_mfma(
    const float* A0,                  // fp32 M x 64 (aliases outp)
    const float* __restrict__ W,
    const float* __restrict__ bias,
    const float* __restrict__ inStats,
    const float* __restrict__ inG,
    const float* __restrict__ inBe,
    float invM_in,
    float* outp,
    float* __restrict__ outStats,
    int M)
{
  __shared__ unsigned short Wt_s[64 * 72];
  __shared__ float scale_s[64];
  __shared__ float shift_s[64];
  __shared__ float red_s[128];

  const int tid = threadIdx.x;
  const int lane = tid & 63;
  const int wave = tid >> 6;
  const int nn = lane & 15;
  const int kq = lane >> 4;

  if (tid < 64) {
    float mean = inStats[tid] * invM_in;
    float var = inStats[64 + tid] * invM_in - mean * mean;
    float sc = inG[tid] * rsqrtf(var + EPSV);
    scale_s[tid] = sc;
    shift_s[tid] = inBe[tid] - mean * sc;
  }
#pragma unroll
  for (int i = 0; i < 16; ++i) {
    int idx = i * 256 + tid;
    int k = idx >> 6, n = idx & 63;
    Wt_s[n * 72 + k] = f2b(W[idx]);
  }
  __syncthreads();

  s16x8 bfrag[4][2];
#pragma unroll
  for (int nt = 0; nt < 4; ++nt)
#pragma unroll
    for (int kc = 0; kc < 2; ++kc) {
      const unsigned short* p = &Wt_s[(nt * 16 + nn) * 72 + kc * 32 + kq * 8];
#pragma unroll
      for (int j = 0; j < 8; ++j) bfrag[nt][kc][j] = (short)p[j];
    }

  float scf[2][8], shf[2][8];
#pragma unroll
  for (int kc = 0; kc < 2; ++kc)
#pragma unroll
    for (int j = 0; j < 8; ++j) {
      int k = kc * 32 + kq * 8 + j;
      scf[kc][j] = scale_s[k];
      shf[kc][j] = shift_s[k];
    }

  const int rbase = blockIdx.x * 128 + wave * 32;

  f32x4 acc[2][4];
#pragma unroll
  for (int rt = 0; rt < 2; ++rt)
#pragma unroll
    for (int nt = 0; nt < 4; ++nt) acc[rt][nt] = (f32x4){0.f, 0.f, 0.f, 0.f};

#pragma unroll
  for (int rt = 0; rt < 2; ++rt) {
    int row = rbase + rt * 16 + nn;
    int rowc = row < M ? row : M - 1;
#pragma unroll
    for (int kc = 0; kc < 2; ++kc) {
      const float* src = &A0[(size_t)rowc * 64 + kc * 32 + kq * 8];
      float4 v0 = *(const float4*)src;
      float4 v1 = *(const float4*)(src + 4);
      float v[8] = {v0.x, v0.y, v0.z, v0.w, v1.x, v1.y, v1.z, v1.w};
      s16x8 af;
#pragma unroll
      for (int j = 0; j < 8; ++j)
        af[j] = (short)f2b(fmaxf(fmaf(scf[kc][j], v[j], shf[kc][j]), 0.f));
#pragma unroll
      for (int nt = 0; nt < 4; ++nt)
        acc[rt][nt] = __builtin_amdgcn_mfma_f32_16x16x32_bf16(
            af, bfrag[nt][kc], acc[rt][nt], 0, 0, 0);
    }
  }

  float bcol[4];
#pragma unroll
  for (int nt = 0; nt < 4; ++nt) bcol[nt] = bias[nt * 16 + nn];

  float s[4] = {0.f, 0.f, 0.f, 0.f};
  float s2[4] = {0.f, 0.f, 0.f, 0.f};
#pragma unroll
  for (int rt = 0; rt < 2; ++rt)
#pragma unroll
    for (int nt = 0; nt < 4; ++nt) {
      int col = nt * 16 + nn;
#pragma unroll
      for (int reg = 0; reg < 4; ++reg) {
        int row = rbase + rt * 16 + kq * 4 + reg;
        if (row < M) {
          float y = acc[rt][nt][reg] + bcol[nt];
          outp[(size_t)row * 64 + col] = y;
          s[nt] += y; s2[nt] += y * y;
        }
      }
    }
#pragma unroll
  for (int nt = 0; nt < 4; ++nt) {
    s[nt] += __shfl_xor(s[nt], 16, 64);
    s[nt] += __shfl_xor(s[nt], 32, 64);
    s2[nt] += __shfl_xor(s2[nt], 16, 64);
    s2[nt] += __shfl_xor(s2[nt], 32, 64);
  }
  if (tid < 128) red_s[tid] = 0.f;
  __syncthreads();
  if (lane < 16) {
#pragma unroll
    for (int nt = 0; nt < 4; ++nt) {
      atomicAdd(&red_s[nt * 16 + nn], s[nt]);
      atomicAdd(&red_s[64 + nt * 16 + nn], s2[nt]);
    }
  }
  __syncthreads();
  if (tid < 128) atomicAdd(&outStats[tid], red_s[tid]);
}

// ---------------------------------------------------------------------------
// aggregate: aggr[n] = sum_{e in CSR(n)} relu(bn(t2_bf16[e]))  (fp32 out)
// ---------------------------------------------------------------------------
__global__ __launch_bounds__(256) void aggregate_kernel(
    const unsigned short* __restrict__ t2, const int* __restrict__ rowptr,
    const int* __restrict__ eid, const float* __restrict__ stats,
    const float* __restrict__ g, const float* __restrict__ be,
    float invM, float* __restrict__ aggr)
{
  int node = (blockIdx.x * 256 + threadIdx.x) >> 6;
  int lane = threadIdx.x & 63;
  if (node >= NN) return;
  float mean = stats[lane] * invM;
  float var = stats[64 + lane] * invM - mean * mean;
  float sc = g[lane] * rsqrtf(var + EPSV);
  float sh = be[lane] - mean * sc;
  int lo = rowptr[node], hi = rowptr[node + 1];
  float acc = 0.f;
  for (int i = lo; i < hi; ++i) {
    int e = eid[i];
    acc += fmaxf(fmaf(sc, b2f(t2[(size_t)e * 64 + lane]), sh), 0.f);
  }
  aggr[(size_t)node * 64 + lane] = acc;
}

// ---------------------------------------------------------------------------
// residual: h += relu(bn(u2))
// ---------------------------------------------------------------------------
__global__ __launch_bounds__(256) void residual_kernel(
    const float* __restrict__ u2, const float* __restrict__ stats,
    const float* __restrict__ g, const float* __restrict__ be,
    float invM, float* __restrict__ h)
{
  int gid = blockIdx.x * 256 + threadIdx.x;
  if (gid >= NN * 16) return;
  int c = (gid & 15) * 4;
  float4 v = *(const float4*)&u2[(size_t)gid * 4];
  float4 hv = *(const float4*)&h[(size_t)gid * 4];
  float* vp = (float*)&v;
  float* hp = (float*)&hv;
#pragma unroll
  for (int j = 0; j < 4; ++j) {
    float mean = stats[c + j] * invM;
    float var = stats[64 + c + j] * invM - mean * mean;
    float sc = g[c + j] * rsqrtf(var + EPSV);
    float sh = be[c + j] - mean * sc;
    hp[j] += fmaxf(fmaf(sc, vp[j], sh), 0.f);
  }
  *(float4*)&h[(size_t)gid * 4] = hv;
}

// ---------------------------------------------------------------------------
// pool: partial per-graph column sums (batch sorted -> register run-length),
// then tiny final kernel with prediction head.
// ---------------------------------------------------------------------------
constexpr int POOL_NPB = 128;  // nodes per block

__global__ __launch_bounds__(256) void pool_partial(
    const float* __restrict__ h, const int* __restrict__ batch,
    float* __restrict__ sums)  // NG x 64
{
  int lane = threadIdx.x & 63;
  int wave = threadIdx.x >> 6;
  int base = blockIdx.x * POOL_NPB;
  float acc = 0.f;
  int gcur = -1;
  for (int i = wave; i < POOL_NPB; i += 4) {
    int n = base + i;
    if (n >= NN) break;
    int g = batch[n];
    if (g != gcur) {
      if (gcur >= 0) atomicAdd(&sums[gcur * 64 + lane], acc);
      gcur = g;
      acc = 0.f;
    }
    acc += h[(size_t)n * 64 + lane];
  }
  if (gcur >= 0) atomicAdd(&sums[gcur * 64 + lane], acc);
}

DEV int lower_bound_i(const int* __restrict__ a, int n, int v) {
  int lo = 0, hi = n;
  while (lo < hi) {
    int m = (lo + hi) >> 1;
    if (a[m] < v) lo = m + 1; else hi = m;
  }
  return lo;
}

__global__ __launch_bounds__(64) void pool_final(
    const float* __restrict__ sums, const int* __restrict__ batch,
    const float* __restrict__ predW, const float* __restrict__ predB,
    float* __restrict__ out)
{
  int g = blockIdx.x;
  int lane = threadIdx.x;
  int lo = lower_bound_i(batch, NN, g);
  int hi = lower_bound_i(batch, NN, g + 1);
  float cnt = fmaxf((float)(hi - lo), 1.0f);
  float p = sums[g * 64 + lane] / cnt * predW[lane];
#pragma unroll
  for (int off = 32; off > 0; off >>= 1) p += __shfl_down(p, off, 64);
  if (lane == 0) out[g] = p + predB[0];
}

// ---------------------------------------------------------------------------
extern "C" void kernel_launch(void* const* d_in, const int* in_sizes, int n_in,
                              void* d_out, int out_size, void* d_ws, size_t ws_size,
                              hipStream_t stream)
{
  (void)in_sizes; (void)n_in; (void)out_size; (void)ws_size;

  const float* x        = (const float*)d_in[0];
  const float* edge_attr= (const float*)d_in[1];
  const int*   eidx     = (const int*)d_in[2];
  const int*   batch    = (const int*)d_in[3];
  const float* linW     = (const float*)d_in[4];
  const float* linB     = (const float*)d_in[5];
  const float* msgW1    = (const float*)d_in[6];
  const float* msgB1    = (const float*)d_in[7];
  const float* msgG1    = (const float*)d_in[8];
  const float* msgBe1   = (const float*)d_in[9];
  const float* msgW2    = (const float*)d_in[10];
  const float* msgB2    = (const float*)d_in[11];
  const float* msgG2    = (const float*)d_in[12];
  const float* msgBe2   = (const float*)d_in[13];
  const float* updW1    = (const float*)d_in[14];
  const float* updB1    = (const float*)d_in[15];
  const float* updG1    = (const float*)d_in[16];
  const float* updBe1   = (const float*)d_in[17];
  const float* updW2    = (const float*)d_in[18];
  const float* updB2    = (const float*)d_in[19];
  const float* updG2    = (const float*)d_in[20];
  const float* updBe2   = (const float*)d_in[21];
  const float* predW    = (const float*)d_in[22];
  const float* predB    = (const float*)d_in[23];

  const int* srcI = eidx;        // edge_index[0] = source
  const int* dstI = eidx + NE;   // edge_index[1] = target

  char* p = (char*)d_ws;
  float* h  = (float*)p;            p += (size_t)NN * 64 * 4;
  unsigned short* t1 = (unsigned short*)p; p += (size_t)NE * 64 * 2;
  float* aggr = (float*)p;          p += (size_t)NN * 64 * 4;
  float* u1 = (float*)p;            p += (size_t)NN * 64 * 4;
  unsigned short* Hd = (unsigned short*)p; p += (size_t)NN * 64 * 2;
  unsigned short* Hs = (unsigned short*)p; p += (size_t)NN * 64 * 2;
  float* stats = (float*)p;         p += 16 * 128 * 4;
  float* sums = (float*)p;          p += NG * 64 * 4;
  int* deg = (int*)p;               p += (size_t)NN * 4;
  int* cursor = (int*)p;            p += (size_t)NN * 4;
  int* rowptr = (int*)p;            p += (size_t)(NN + 1) * 4;
  int* eid = (int*)p;               p += (size_t)NE * 4;

  // stats + sums are contiguous: one memset
  hipMemsetAsync(stats, 0, (16 * 128 + NG * 64) * sizeof(float), stream);
  hipMemsetAsync(deg, 0, 2 * NN * sizeof(int), stream);  // deg + cursor

  hist_kernel<<<(NE + 255) / 256, 256, 0, stream>>>(dstI, deg);
  scan_kernel<<<1, 256, 0, stream>>>(deg, rowptr);
  fill_kernel<<<(NE + 255) / 256, 256, 0, stream>>>(dstI, rowptr, cursor, eid);

  lin_in_kernel<<<(NN * 64 + 255) / 256, 256, 0, stream>>>(x, linW, linB, h);

  const float invE = 1.0f / (float)NE;
  const float invN = 1.0f / (float)NN;
  const int NB128 = (NN + 127) / 128;         // 391

  for (int l = 0; l < 4; ++l) {
    float* st0 = stats + (l * 4 + 0) * 128;
    float* st1 = stats + (l * 4 + 1) * 128;
    float* st2 = stats + (l * 4 + 2) * 128;
    float* st3 = stats + (l * 4 + 3) * 128;
    const float* W1 = msgW1 + (size_t)l * 132 * 64;

    // Hd = h @ W1[0:64], Hs = h @ W1[64:128]  (bf16 out, MFMA)
    gemm_dual_mfma<<<NB128, 256, 0, stream>>>(h, W1, Hd, Hs);

    // t1[e] = Hd[dst] + Hs[src] + ea@W1[128:132] + b1 (bf16) ; stats(st0)
    edge_combine<<<2048, 256, 0, stream>>>(
        Hd, Hs, edge_attr, srcI, dstI, W1 + 128 * 64, msgB1 + l * 64,
        t1, st0);

    // t1 = relu(bn(t1)) @ msgW2 + b2 (bf16, in-place, MFMA) ; stats(st1)
    gemm64_bn_mfma<<<NE / 128, 256, 0, stream>>>(
        t1, msgW2 + (size_t)l * 64 * 64, msgB2 + l * 64,
        st0, msgG1 + l * 64, msgBe1 + l * 64, invE,
        t1, st1, NE);

    // aggr[n] = sum relu(bn(t1)) over incoming edges (CSR gather, fp32)
    aggregate_kernel<<<(NN * 64 + 255) / 256, 256, 0, stream>>>(
        t1, rowptr, eid, st1, msgG2 + l * 64, msgBe2 + l * 64, invE, aggr);

    // u1 = [h|aggr] @ updW1 + b1 (MFMA) ; stats(st2)
    gemm_concat_mfma<<<NB128, 256, 0, stream>>>(
        h, aggr, updW1 + (size_t)l * 128 * 64, updB1 + l * 64,
        u1, st2, NN);

    // u1 = relu(bn(u1)) @ updW2 + b2 (fp32 in/out, in-place, MFMA) ; stats(st3)
    gemm64_node_mfma<<<NB128, 256, 0, stream>>>(
        u1, updW2 + (size_t)l * 64 * 64, updB2 + l * 64,
        st2, updG1 + l * 64, updBe1 + l * 64, invN,
        u1, st3, NN);

    // h += relu(bn(u1))
    residual_kernel<<<(NN * 16 + 255) / 256, 256, 0, stream>>>(
        u1, st3, updG2 + l * 64, updBe2 + l * 64, invN, h);
  }

  pool_partial<<<(NN + POOL_NPB - 1) / POOL_NPB, 256, 0, stream>>>(h, batch, sums);
  pool_final<<<NG, 64, 0, stream>>>(sums, batch, predW, predB, (float*)d_out);
}

// Round 6
// 1125.480 us; speedup vs baseline: 3.0749x; 1.1469x over previous
//
#include <hip/hip_runtime.h>

#define DEV __device__ __forceinline__

constexpr int NN = 50000;   // nodes
constexpr int NE = 400000;  // edges
constexpr int NG = 32;      // graphs
constexpr float EPSV = 1e-5f;
constexpr int SCAN_BLOCKS = 196;  // 196*256 = 50176 >= NN

typedef __attribute__((ext_vector_type(8))) short s16x8;
typedef __attribute__((ext_vector_type(4))) float f32x4;

DEV unsigned short f2b(float f) {  // fp32 -> bf16 RNE (finite inputs)
  union { float f; unsigned u; } x; x.f = f;
  unsigned r = x.u + 0x7fffu + ((x.u >> 16) & 1u);
  return (unsigned short)(r >> 16);
}
DEV float b2f(unsigned short u) {
  union { unsigned u; float f; } x; x.u = ((unsigned)u) << 16; return x.f;
}

DEV s16x8 frag_from_f32(const float* p) {
  const float4 v0 = *(const float4*)p;
  const float4 v1 = *(const float4*)(p + 4);
  s16x8 af;
  af[0] = (short)f2b(v0.x); af[1] = (short)f2b(v0.y);
  af[2] = (short)f2b(v0.z); af[3] = (short)f2b(v0.w);
  af[4] = (short)f2b(v1.x); af[5] = (short)f2b(v1.y);
  af[6] = (short)f2b(v1.z); af[7] = (short)f2b(v1.w);
  return af;
}

// ---------------------------------------------------------------------------
// lin_in: h = x @ W(11x64) + b
// ---------------------------------------------------------------------------
__global__ __launch_bounds__(256) void lin_in_kernel(
    const float* __restrict__ x, const float* __restrict__ W,
    const float* __restrict__ b, float* __restrict__ h)
{
  int gid = blockIdx.x * 256 + threadIdx.x;
  if (gid >= NN * 64) return;
  int n = gid >> 6, c = gid & 63;
  float acc = b[c];
#pragma unroll
  for (int k = 0; k < 11; ++k)
    acc = fmaf(x[n * 11 + k], W[k * 64 + c], acc);
  h[gid] = acc;
}

// ---------------------------------------------------------------------------
// CSR build: histogram -> hierarchical exclusive scan (3 passes) -> fill
// ---------------------------------------------------------------------------
__global__ __launch_bounds__(256) void hist_kernel(
    const int* __restrict__ dstI, int* __restrict__ deg)
{
  int e = blockIdx.x * 256 + threadIdx.x;
  if (e < NE) atomicAdd(&deg[dstI[e]], 1);
}

__global__ __launch_bounds__(256) void scan_pass1(
    const int* __restrict__ deg, int* __restrict__ blockSums)
{
  __shared__ int red[4];
  int tid = threadIdx.x;
  int idx = blockIdx.x * 256 + tid;
  int v = (idx < NN) ? deg[idx] : 0;
#pragma unroll
  for (int off = 32; off > 0; off >>= 1) v += __shfl_down(v, off, 64);
  if ((tid & 63) == 0) red[tid >> 6] = v;
  __syncthreads();
  if (tid == 0) blockSums[blockIdx.x] = red[0] + red[1] + red[2] + red[3];
}

__global__ __launch_bounds__(256) void scan_pass2(
    const int* __restrict__ blockSums, int* __restrict__ blockOffs)
{
  __shared__ int part[256];
  int tid = threadIdx.x;
  int v = (tid < SCAN_BLOCKS) ? blockSums[tid] : 0;
  part[tid] = v;
  __syncthreads();
  for (int off = 1; off < 256; off <<= 1) {
    int t = 0;
    if (tid >= off) t = part[tid - off];
    __syncthreads();
    if (tid >= off) part[tid] += t;
    __syncthreads();
  }
  blockOffs[tid] = (tid == 0) ? 0 : part[tid - 1];
}

__global__ __launch_bounds__(256) void scan_pass3(
    const int* __restrict__ deg, const int* __restrict__ blockOffs,
    int* __restrict__ rowptr, int* __restrict__ cursor)
{
  __shared__ int part[256];
  int tid = threadIdx.x;
  int idx = blockIdx.x * 256 + tid;
  int v = (idx < NN) ? deg[idx] : 0;
  part[tid] = v;
  __syncthreads();
  for (int off = 1; off < 256; off <<= 1) {
    int t = 0;
    if (tid >= off) t = part[tid - off];
    __syncthreads();
    if (tid >= off) part[tid] += t;
    __syncthreads();
  }
  int excl = (tid == 0) ? 0 : part[tid - 1];
  int val = blockOffs[blockIdx.x] + excl;
  if (idx < NN) { rowptr[idx] = val; cursor[idx] = val; }
  if (idx == 0) rowptr[NN] = NE;  // total is a compile-time constant
}

__global__ __launch_bounds__(256) void fill_kernel(
    const int* __restrict__ dstI, int* __restrict__ cursor,
    int* __restrict__ eid)
{
  int e = blockIdx.x * 256 + threadIdx.x;
  if (e < NE) {
    int pos = atomicAdd(&cursor[dstI[e]], 1);
    eid[pos] = e;
  }
}

// ---------------------------------------------------------------------------
// gemm_dual_mfma: Hd = h @ W[0:64], Hs = h @ W[64:128] (bf16 out, MFMA)
// ---------------------------------------------------------------------------
__global__ __launch_bounds__(256) void gemm_dual_mfma(
    const float* __restrict__ h, const float* __restrict__ W, // 132x64
    unsigned short* __restrict__ Hd, unsigned short* __restrict__ Hs)
{
  __shared__ unsigned short Wt_s[2 * 64 * 72];  // [half][n][k]

  const int tid = threadIdx.x;
  const int lane = tid & 63;
  const int wave = tid >> 6;
  const int nn = lane & 15;
  const int kq = lane >> 4;

#pragma unroll
  for (int i = 0; i < 32; ++i) {
    int idx = i * 256 + tid;          // 8192 = 2*64*64
    int half = idx >> 12;
    int rem = idx & 4095;
    int k = rem >> 6, n = rem & 63;
    Wt_s[half * 4608 + n * 72 + k] = f2b(W[idx]);
  }
  __syncthreads();

  s16x8 bfrag[2][4][2];  // [out][nt][kc]
#pragma unroll
  for (int o = 0; o < 2; ++o)
#pragma unroll
    for (int nt = 0; nt < 4; ++nt)
#pragma unroll
      for (int kc = 0; kc < 2; ++kc) {
        const unsigned short* p =
            &Wt_s[o * 4608 + (nt * 16 + nn) * 72 + kc * 32 + kq * 8];
#pragma unroll
        for (int j = 0; j < 8; ++j) bfrag[o][nt][kc][j] = (short)p[j];
      }

  const int rbase = blockIdx.x * 128 + wave * 32;

  f32x4 acc[2][2][4];  // [out][rt][nt]
#pragma unroll
  for (int o = 0; o < 2; ++o)
#pragma unroll
    for (int rt = 0; rt < 2; ++rt)
#pragma unroll
      for (int nt = 0; nt < 4; ++nt) acc[o][rt][nt] = (f32x4){0.f, 0.f, 0.f, 0.f};

#pragma unroll
  for (int rt = 0; rt < 2; ++rt) {
    int row = rbase + rt * 16 + nn;
    int rowc = row < NN ? row : NN - 1;
#pragma unroll
    for (int kc = 0; kc < 2; ++kc) {
      s16x8 af = frag_from_f32(&h[(size_t)rowc * 64 + kc * 32 + kq * 8]);
#pragma unroll
      for (int o = 0; o < 2; ++o)
#pragma unroll
        for (int nt = 0; nt < 4; ++nt)
          acc[o][rt][nt] = __builtin_amdgcn_mfma_f32_16x16x32_bf16(
              af, bfrag[o][nt][kc], acc[o][rt][nt], 0, 0, 0);
    }
  }

#pragma unroll
  for (int rt = 0; rt < 2; ++rt)
#pragma unroll
    for (int nt = 0; nt < 4; ++nt) {
      int col = nt * 16 + nn;
#pragma unroll
      for (int reg = 0; reg < 4; ++reg) {
        int row = rbase + rt * 16 + kq * 4 + reg;
        if (row < NN) {
          Hd[(size_t)row * 64 + col] = f2b(acc[0][rt][nt][reg]);
          Hs[(size_t)row * 64 + col] = f2b(acc[1][rt][nt][reg]);
        }
      }
    }
}

// ---------------------------------------------------------------------------
// edge_combine: t1[e] = Hd[dst[e]] + Hs[src[e]] + ea[e]@W_bot + b (bf16 out)
// 8 lanes/edge, 16B row loads/stores; fp32 stats pre-rounding.
// ---------------------------------------------------------------------------
__global__ __launch_bounds__(256) void edge_combine(
    const unsigned short* __restrict__ Hd, const unsigned short* __restrict__ Hs,
    const float* __restrict__ ea, const int* __restrict__ srcI,
    const int* __restrict__ dstI, const float* __restrict__ Wb, // 4x64
    const float* __restrict__ bias, unsigned short* __restrict__ t1,
    float* __restrict__ outStats)
{
  __shared__ float red_s[128];
  const int tid = threadIdx.x;
  const int c0 = (tid & 7) * 8;
  float bv[8], w0[8], w1[8], w2[8], w3[8];
#pragma unroll
  for (int j = 0; j < 8; ++j) {
    bv[j] = bias[c0 + j];
    w0[j] = Wb[0 * 64 + c0 + j];
    w1[j] = Wb[1 * 64 + c0 + j];
    w2[j] = Wb[2 * 64 + c0 + j];
    w3[j] = Wb[3 * 64 + c0 + j];
  }

  float s[8], s2[8];
#pragma unroll
  for (int j = 0; j < 8; ++j) { s[j] = 0.f; s2[j] = 0.f; }

  int e0 = (blockIdx.x * 256 + tid) >> 3;
  int estep = (gridDim.x * 256) >> 3;
  for (int e = e0; e < NE; e += estep) {
    int si = srcI[e];
    int di = dstI[e];
    float4 av = *(const float4*)&ea[(size_t)e * 4];
    uint4 hd = *(const uint4*)&Hd[(size_t)di * 64 + c0];
    uint4 hs = *(const uint4*)&Hs[(size_t)si * 64 + c0];
    const unsigned hdw[4] = {hd.x, hd.y, hd.z, hd.w};
    const unsigned hsw[4] = {hs.x, hs.y, hs.z, hs.w};
    unsigned short ob[8];
#pragma unroll
    for (int d = 0; d < 4; ++d) {
      union { unsigned u; float f; } a0, a1, b0, b1;
      a0.u = (hdw[d] & 0xffffu) << 16; a1.u = hdw[d] & 0xffff0000u;
      b0.u = (hsw[d] & 0xffffu) << 16; b1.u = hsw[d] & 0xffff0000u;
      int j0 = d * 2, j1 = d * 2 + 1;
      float y0 = a0.f + b0.f + bv[j0] + av.x * w0[j0] + av.y * w1[j0] + av.z * w2[j0] + av.w * w3[j0];
      float y1 = a1.f + b1.f + bv[j1] + av.x * w0[j1] + av.y * w1[j1] + av.z * w2[j1] + av.w * w3[j1];
      ob[j0] = f2b(y0); ob[j1] = f2b(y1);
      s[j0] += y0; s2[j0] += y0 * y0;
      s[j1] += y1; s2[j1] += y1 * y1;
    }
    *(uint4*)&t1[(size_t)e * 64 + c0] = *(const uint4*)ob;
  }
#pragma unroll
  for (int j = 0; j < 8; ++j) {
    s[j] += __shfl_xor(s[j], 8, 64);
    s[j] += __shfl_xor(s[j], 16, 64);
    s[j] += __shfl_xor(s[j], 32, 64);
    s2[j] += __shfl_xor(s2[j], 8, 64);
    s2[j] += __shfl_xor(s2[j], 16, 64);
    s2[j] += __shfl_xor(s2[j], 32, 64);
  }
  if (tid < 128) red_s[tid] = 0.f;
  __syncthreads();
  if ((tid & 63) < 8) {
#pragma unroll
    for (int j = 0; j < 8; ++j) {
      atomicAdd(&red_s[c0 + j], s[j]);
      atomicAdd(&red_s[64 + c0 + j], s2[j]);
    }
  }
  __syncthreads();
  if (tid < 128) atomicAdd(&outStats[tid], red_s[tid]);
}

// ---------------------------------------------------------------------------
// gemm64_bn_mfma: out = relu(bn(A)) @ W + b — bf16 in/out, MFMA, in-place ok.
// Row-clamped loads stay inside the block's own 128-row range; OOB rows'
// stores and stats are guarded, so M need not divide 128.
// ---------------------------------------------------------------------------
__global__ __launch_bounds__(256) void gemm64_bn_mfma(
    const unsigned short* A0,         // bf16 M x 64 (may alias outp)
    const float* __restrict__ W,      // 64 x 64 fp32
    const float* __restrict__ bias,
    const float* __restrict__ inStats,
    const float* __restrict__ inG,
    const float* __restrict__ inBe,
    float invM_in,
    unsigned short* outp,             // bf16 M x 64
    float* __restrict__ outStats,
    int M)
{
  __shared__ unsigned short Wt_s[64 * 72];
  __shared__ float scale_s[64];
  __shared__ float shift_s[64];
  __shared__ float red_s[128];

  const int tid = threadIdx.x;
  const int lane = tid & 63;
  const int wave = tid >> 6;
  const int nn = lane & 15;
  const int kq = lane >> 4;

  if (tid < 64) {
    float mean = inStats[tid] * invM_in;
    float var = inStats[64 + tid] * invM_in - mean * mean;
    float sc = inG[tid] * rsqrtf(var + EPSV);
    scale_s[tid] = sc;
    shift_s[tid] = inBe[tid] - mean * sc;
  }
#pragma unroll
  for (int i = 0; i < 16; ++i) {
    int idx = i * 256 + tid;
    int k = idx >> 6, n = idx & 63;
    Wt_s[n * 72 + k] = f2b(W[idx]);
  }
  __syncthreads();

  s16x8 bfrag[4][2];
#pragma unroll
  for (int nt = 0; nt < 4; ++nt)
#pragma unroll
    for (int kc = 0; kc < 2; ++kc) {
      const unsigned short* p = &Wt_s[(nt * 16 + nn) * 72 + kc * 32 + kq * 8];
#pragma unroll
      for (int j = 0; j < 8; ++j) bfrag[nt][kc][j] = (short)p[j];
    }

  float scf[2][8], shf[2][8];
#pragma unroll
  for (int kc = 0; kc < 2; ++kc)
#pragma unroll
    for (int j = 0; j < 8; ++j) {
      int k = kc * 32 + kq * 8 + j;
      scf[kc][j] = scale_s[k];
      shf[kc][j] = shift_s[k];
    }

  const int rbase = blockIdx.x * 128 + wave * 32;

  f32x4 acc[2][4];
#pragma unroll
  for (int rt = 0; rt < 2; ++rt)
#pragma unroll
    for (int nt = 0; nt < 4; ++nt) acc[rt][nt] = (f32x4){0.f, 0.f, 0.f, 0.f};

#pragma unroll
  for (int rt = 0; rt < 2; ++rt) {
    int row = rbase + rt * 16 + nn;
    int rowc = row < M ? row : M - 1;
#pragma unroll
    for (int kc = 0; kc < 2; ++kc) {
      uint4 raw = *(const uint4*)&A0[(size_t)rowc * 64 + kc * 32 + kq * 8];
      unsigned wbits[4] = {raw.x, raw.y, raw.z, raw.w};
      s16x8 af;
#pragma unroll
      for (int d = 0; d < 4; ++d) {
        union { unsigned u; float f; } lo, hi;
        lo.u = (wbits[d] & 0xffffu) << 16;
        hi.u = wbits[d] & 0xffff0000u;
        int j0 = d * 2, j1 = d * 2 + 1;
        af[j0] = (short)f2b(fmaxf(fmaf(scf[kc][j0], lo.f, shf[kc][j0]), 0.f));
        af[j1] = (short)f2b(fmaxf(fmaf(scf[kc][j1], hi.f, shf[kc][j1]), 0.f));
      }
#pragma unroll
      for (int nt = 0; nt < 4; ++nt)
        acc[rt][nt] = __builtin_amdgcn_mfma_f32_16x16x32_bf16(
            af, bfrag[nt][kc], acc[rt][nt], 0, 0, 0);
    }
  }

  float bcol[4];
#pragma unroll
  for (int nt = 0; nt < 4; ++nt) bcol[nt] = bias[nt * 16 + nn];

  float s[4] = {0.f, 0.f, 0.f, 0.f};
  float s2[4] = {0.f, 0.f, 0.f, 0.f};
#pragma unroll
  for (int rt = 0; rt < 2; ++rt)
#pragma unroll
    for (int nt = 0; nt < 4; ++nt) {
      int col = nt * 16 + nn;
#pragma unroll
      for (int reg = 0; reg < 4; ++reg) {
        int row = rbase + rt * 16 + kq * 4 + reg;
        if (row < M) {
          float y = acc[rt][nt][reg] + bcol[nt];
          outp[(size_t)row * 64 + col] = f2b(y);
          s[nt] += y; s2[nt] += y * y;
        }
      }
    }
#pragma unroll
  for (int nt = 0; nt < 4; ++nt) {
    s[nt] += __shfl_xor(s[nt], 16, 64);
    s[nt] += __shfl_xor(s[nt], 32, 64);
    s2[nt] += __shfl_xor(s2[nt], 16, 64);
    s2[nt] += __shfl_xor(s2[nt], 32, 64);
  }
  if (tid < 128) red_s[tid] = 0.f;
  __syncthreads();
  if (lane < 16) {
#pragma unroll
    for (int nt = 0; nt < 4; ++nt) {
      atomicAdd(&red_s[nt * 16 + nn], s[nt]);
      atomicAdd(&red_s[64 + nt * 16 + nn], s2[nt]);
    }
  }
  __syncthreads();
  if (tid < 128) atomicAdd(&outStats[tid], red_s[tid]);
}

// ---------------------------------------------------------------------------
// gemm_concat_mfma: u1 = [h(fp32)|aggr(bf16)] @ W(128x64) + b (bf16 out)
// ---------------------------------------------------------------------------
__global__ __launch_bounds__(256) void gemm_concat_mfma(
    const float* __restrict__ A0,            // h fp32
    const unsigned short* __restrict__ A1b,  // aggr bf16
    const float* __restrict__ W,             // 128 x 64
    const float* __restrict__ bias,
    unsigned short* __restrict__ outp,       // u1 bf16
    float* __restrict__ outStats,
    int M)
{
  __shared__ unsigned short Wt_s[64 * 136];
  __shared__ float red_s[128];

  const int tid = threadIdx.x;
  const int lane = tid & 63;
  const int wave = tid >> 6;
  const int nn = lane & 15;
  const int kq = lane >> 4;

#pragma unroll
  for (int i = 0; i < 32; ++i) {
    int idx = i * 256 + tid;          // 8192
    int k = idx >> 6, n = idx & 63;
    Wt_s[n * 136 + k] = f2b(W[idx]);
  }
  __syncthreads();

  s16x8 bfrag[4][4];  // [nt][kc]
#pragma unroll
  for (int nt = 0; nt < 4; ++nt)
#pragma unroll
    for (int kc = 0; kc < 4; ++kc) {
      const unsigned short* p = &Wt_s[(nt * 16 + nn) * 136 + kc * 32 + kq * 8];
#pragma unroll
      for (int j = 0; j < 8; ++j) bfrag[nt][kc][j] = (short)p[j];
    }

  const int rbase = blockIdx.x * 128 + wave * 32;

  f32x4 acc[2][4];
#pragma unroll
  for (int rt = 0; rt < 2; ++rt)
#pragma unroll
    for (int nt = 0; nt < 4; ++nt) acc[rt][nt] = (f32x4){0.f, 0.f, 0.f, 0.f};

#pragma unroll
  for (int rt = 0; rt < 2; ++rt) {
    int row = rbase + rt * 16 + nn;
    int rowc = row < M ? row : M - 1;
#pragma unroll
    for (int kc = 0; kc < 4; ++kc) {
      s16x8 af;
      if (kc < 2) {
        af = frag_from_f32(&A0[(size_t)rowc * 64 + kc * 32 + kq * 8]);
      } else {
        af = *(const s16x8*)&A1b[(size_t)rowc * 64 + (kc - 2) * 32 + kq * 8];
      }
#pragma unroll
      for (int nt = 0; nt < 4; ++nt)
        acc[rt][nt] = __builtin_amdgcn_mfma_f32_16x16x32_bf16(
            af, bfrag[nt][kc], acc[rt][nt], 0, 0, 0);
    }
  }

  float bcol[4];
#pragma unroll
  for (int nt = 0; nt < 4; ++nt) bcol[nt] = bias[nt * 16 + nn];

  float s[4] = {0.f, 0.f, 0.f, 0.f};
  float s2[4] = {0.f, 0.f, 0.f, 0.f};
#pragma unroll
  for (int rt = 0; rt < 2; ++rt)
#pragma unroll
    for (int nt = 0; nt < 4; ++nt) {
      int col = nt * 16 + nn;
#pragma unroll
      for (int reg = 0; reg < 4; ++reg) {
        int row = rbase + rt * 16 + kq * 4 + reg;
        if (row < M) {
          float y = acc[rt][nt][reg] + bcol[nt];
          outp[(size_t)row * 64 + col] = f2b(y);
          s[nt] += y; s2[nt] += y * y;
        }
      }
    }
#pragma unroll
  for (int nt = 0; nt < 4; ++nt) {
    s[nt] += __shfl_xor(s[nt], 16, 64);
    s[nt] += __shfl_xor(s[nt], 32, 64);
    s2[nt] += __shfl_xor(s2[nt], 16, 64);
    s2[nt] += __shfl_xor(s2[nt], 32, 64);
  }
  if (tid < 128) red_s[tid] = 0.f;
  __syncthreads();
  if (lane < 16) {
#pragma unroll
    for (int nt = 0; nt < 4; ++nt) {
      atomicAdd(&red_s[nt * 16 + nn], s[nt]);
      atomicAdd(&red_s[64 + nt * 16 + nn], s2[nt]);
    }
  }
  __syncthreads();
  if (tid < 128) atomicAdd(&outStats[tid], red_s[tid]);
}

// ---------------------------------------------------------------------------
// aggregate: aggr[n] = sum_{e in CSR(n)} relu(bn(t2_bf16[e]))  (bf16 out)
// 2-edge unroll for memory-level parallelism.
// ---------------------------------------------------------------------------
__global__ __launch_bounds__(256) void aggregate_kernel(
    const unsigned short* __restrict__ t2, const int* __restrict__ rowptr,
    const int* __restrict__ eid, const float* __restrict__ stats,
    const float* __restrict__ g, const float* __restrict__ be,
    float invM, unsigned short* __restrict__ aggr)
{
  int node = (blockIdx.x * 256 + threadIdx.x) >> 6;
  int lane = threadIdx.x & 63;
  if (node >= NN) return;
  float mean = stats[lane] * invM;
  float var = stats[64 + lane] * invM - mean * mean;
  float sc = g[lane] * rsqrtf(var + EPSV);
  float sh = be[lane] - mean * sc;
  int lo = rowptr[node], hi = rowptr[node + 1];
  float acc = 0.f;
  int i = lo;
  for (; i + 1 < hi; i += 2) {
    int e1 = eid[i], e2 = eid[i + 1];
    float v1 = b2f(t2[(size_t)e1 * 64 + lane]);
    float v2 = b2f(t2[(size_t)e2 * 64 + lane]);
    acc += fmaxf(fmaf(sc, v1, sh), 0.f) + fmaxf(fmaf(sc, v2, sh), 0.f);
  }
  if (i < hi) {
    int e = eid[i];
    acc += fmaxf(fmaf(sc, b2f(t2[(size_t)e * 64 + lane]), sh), 0.f);
  }
  aggr[(size_t)node * 64 + lane] = f2b(acc);
}

// ---------------------------------------------------------------------------
// residual: h += relu(bn(u2_bf16))
// ---------------------------------------------------------------------------
__global__ __launch_bounds__(256) void residual_kernel(
    const unsigned short* __restrict__ u2, const float* __restrict__ stats,
    const float* __restrict__ g, const float* __restrict__ be,
    float invM, float* __restrict__ h)
{
  int gid = blockIdx.x * 256 + threadIdx.x;
  if (gid >= NN * 16) return;
  int c = (gid & 15) * 4;
  ushort4 v4 = *(const ushort4*)&u2[(size_t)gid * 4];
  float4 hv = *(const float4*)&h[(size_t)gid * 4];
  const unsigned short vu[4] = {v4.x, v4.y, v4.z, v4.w};
  float* hp = (float*)&hv;
#pragma unroll
  for (int j = 0; j < 4; ++j) {
    float mean = stats[c + j] * invM;
    float var = stats[64 + c + j] * invM - mean * mean;
    float sc = g[c + j] * rsqrtf(var + EPSV);
    float sh = be[c + j] - mean * sc;
    hp[j] += fmaxf(fmaf(sc, b2f(vu[j]), sh), 0.f);
  }
  *(float4*)&h[(size_t)gid * 4] = hv;
}

// ---------------------------------------------------------------------------
// pool: partial per-graph column sums, then tiny final with prediction head
// ---------------------------------------------------------------------------
constexpr int POOL_NPB = 128;  // nodes per block

__global__ __launch_bounds__(256) void pool_partial(
    const float* __restrict__ h, const int* __restrict__ batch,
    float* __restrict__ sums)  // NG x 64
{
  int lane = threadIdx.x & 63;
  int wave = threadIdx.x >> 6;
  int base = blockIdx.x * POOL_NPB;
  float acc = 0.f;
  int gcur = -1;
  for (int i = wave; i < POOL_NPB; i += 4) {
    int n = base + i;
    if (n >= NN) break;
    int g = batch[n];
    if (g != gcur) {
      if (gcur >= 0) atomicAdd(&sums[gcur * 64 + lane], acc);
      gcur = g;
      acc = 0.f;
    }
    acc += h[(size_t)n * 64 + lane];
  }
  if (gcur >= 0) atomicAdd(&sums[gcur * 64 + lane], acc);
}

DEV int lower_bound_i(const int* __restrict__ a, int n, int v) {
  int lo = 0, hi = n;
  while (lo < hi) {
    int m = (lo + hi) >> 1;
    if (a[m] < v) lo = m + 1; else hi = m;
  }
  return lo;
}

__global__ __launch_bounds__(64) void pool_final(
    const float* __restrict__ sums, const int* __restrict__ batch,
    const float* __restrict__ predW, const float* __restrict__ predB,
    float* __restrict__ out)
{
  int g = blockIdx.x;
  int lane = threadIdx.x;
  int lo = lower_bound_i(batch, NN, g);
  int hi = lower_bound_i(batch, NN, g + 1);
  float cnt = fmaxf((float)(hi - lo), 1.0f);
  float p = sums[g * 64 + lane] / cnt * predW[lane];
#pragma unroll
  for (int off = 32; off > 0; off >>= 1) p += __shfl_down(p, off, 64);
  if (lane == 0) out[g] = p + predB[0];
}

// ---------------------------------------------------------------------------
extern "C" void kernel_launch(void* const* d_in, const int* in_sizes, int n_in,
                              void* d_out, int out_size, void* d_ws, size_t ws_size,
                              hipStream_t stream)
{
  (void)in_sizes; (void)n_in; (void)out_size; (void)ws_size;

  const float* x        = (const float*)d_in[0];
  const float* edge_attr= (const float*)d_in[1];
  const int*   eidx     = (const int*)d_in[2];
  const int*   batch    = (const int*)d_in[3];
  const float* linW     = (const float*)d_in[4];
  const float* linB     = (const float*)d_in[5];
  const float* msgW1    = (const float*)d_in[6];
  const float* msgB1    = (const float*)d_in[7];
  const float* msgG1    = (const float*)d_in[8];
  const float* msgBe1   = (const float*)d_in[9];
  const float* msgW2    = (const float*)d_in[10];
  const float* msgB2    = (const float*)d_in[11];
  const float* msgG2    = (const float*)d_in[12];
  const float* msgBe2   = (const float*)d_in[13];
  const float* updW1    = (const float*)d_in[14];
  const float* updB1    = (const float*)d_in[15];
  const float* updG1    = (const float*)d_in[16];
  const float* updBe1   = (const float*)d_in[17];
  const float* updW2    = (const float*)d_in[18];
  const float* updB2    = (const float*)d_in[19];
  const float* updG2    = (const float*)d_in[20];
  const float* updBe2   = (const float*)d_in[21];
  const float* predW    = (const float*)d_in[22];
  const float* predB    = (const float*)d_in[23];

  const int* srcI = eidx;        // edge_index[0] = source
  const int* dstI = eidx + NE;   // edge_index[1] = target

  char* p = (char*)d_ws;
  float* h  = (float*)p;            p += (size_t)NN * 64 * 4;
  unsigned short* t1 = (unsigned short*)p; p += (size_t)NE * 64 * 2;
  unsigned short* aggr = (unsigned short*)p; p += (size_t)NN * 64 * 2;
  unsigned short* u1 = (unsigned short*)p;   p += (size_t)NN * 64 * 2;
  unsigned short* Hd = (unsigned short*)p;   p += (size_t)NN * 64 * 2;
  unsigned short* Hs = (unsigned short*)p;   p += (size_t)NN * 64 * 2;
  float* stats = (float*)p;         p += 16 * 128 * 4;
  float* sums = (float*)p;          p += NG * 64 * 4;
  int* deg = (int*)p;               p += (size_t)NN * 4;
  int* cursor = (int*)p;            p += (size_t)NN * 4;
  int* rowptr = (int*)p;            p += (size_t)(NN + 1) * 4;
  int* eid = (int*)p;               p += (size_t)NE * 4;
  int* blockSums = (int*)p;         p += 256 * 4;
  int* blockOffs = (int*)p;         p += 256 * 4;

  hipMemsetAsync(stats, 0, (16 * 128 + NG * 64) * sizeof(float), stream);
  hipMemsetAsync(deg, 0, NN * sizeof(int), stream);

  hist_kernel<<<(NE + 255) / 256, 256, 0, stream>>>(dstI, deg);
  scan_pass1<<<SCAN_BLOCKS, 256, 0, stream>>>(deg, blockSums);
  scan_pass2<<<1, 256, 0, stream>>>(blockSums, blockOffs);
  scan_pass3<<<SCAN_BLOCKS, 256, 0, stream>>>(deg, blockOffs, rowptr, cursor);
  fill_kernel<<<(NE + 255) / 256, 256, 0, stream>>>(dstI, cursor, eid);

  lin_in_kernel<<<(NN * 64 + 255) / 256, 256, 0, stream>>>(x, linW, linB, h);

  const float invE = 1.0f / (float)NE;
  const float invN = 1.0f / (float)NN;
  const int NB128 = (NN + 127) / 128;         // 391

  for (int l = 0; l < 4; ++l) {
    float* st0 = stats + (l * 4 + 0) * 128;
    float* st1 = stats + (l * 4 + 1) * 128;
    float* st2 = stats + (l * 4 + 2) * 128;
    float* st3 = stats + (l * 4 + 3) * 128;
    const float* W1 = msgW1 + (size_t)l * 132 * 64;

    // Hd = h @ W1[0:64], Hs = h @ W1[64:128]  (bf16 out, MFMA)
    gemm_dual_mfma<<<NB128, 256, 0, stream>>>(h, W1, Hd, Hs);

    // t1[e] = Hd[dst] + Hs[src] + ea@W1[128:132] + b1 (bf16) ; stats(st0)
    edge_combine<<<2048, 256, 0, stream>>>(
        Hd, Hs, edge_attr, srcI, dstI, W1 + 128 * 64, msgB1 + l * 64,
        t1, st0);

    // t1 = relu(bn(t1)) @ msgW2 + b2 (bf16, in-place, MFMA) ; stats(st1)
    gemm64_bn_mfma<<<NE / 128, 256, 0, stream>>>(
        t1, msgW2 + (size_t)l * 64 * 64, msgB2 + l * 64,
        st0, msgG1 + l * 64, msgBe1 + l * 64, invE,
        t1, st1, NE);

    // aggr[n] = sum relu(bn(t1)) over incoming edges (CSR gather, bf16 out)
    aggregate_kernel<<<(NN * 64 + 255) / 256, 256, 0, stream>>>(
        t1, rowptr, eid, st1, msgG2 + l * 64, msgBe2 + l * 64, invE, aggr);

    // u1 = [h|aggr] @ updW1 + b1 (MFMA, bf16 out) ; stats(st2)
    gemm_concat_mfma<<<NB128, 256, 0, stream>>>(
        h, aggr, updW1 + (size_t)l * 128 * 64, updB1 + l * 64,
        u1, st2, NN);

    // u1 = relu(bn(u1)) @ updW2 + b2 (bf16, in-place, MFMA) ; stats(st3)
    gemm64_bn_mfma<<<NB128, 256, 0, stream>>>(
        u1, updW2 + (size_t)l * 64 * 64, updB2 + l * 64,
        st2, updG1 + l * 64, updBe1 + l * 64, invN,
        u1, st3, NN);

    // h += relu(bn(u1))
    residual_kernel<<<(NN * 16 + 255) / 256, 256, 0, stream>>>(
        u1, st3, updG2 + l * 64, updBe2 + l * 64, invN, h);
  }

  pool_partial<<<(NN + POOL_NPB - 1) / POOL_NPB, 256, 0, stream>>>(h, batch, sums);
  pool_final<<<NG, 64, 0, stream>>>(sums, batch, predW, predB, (float*)d_out);
}

// Round 7
// 980.276 us; speedup vs baseline: 3.5304x; 1.1481x over previous
//
#include <hip/hip_runtime.h>

#define DEV __device__ __forceinline__

constexpr int NN = 50000;   // nodes
constexpr int NE = 400000;  // edges
constexpr int NG = 32;      // graphs
constexpr float EPSV = 1e-5f;
constexpr int SCAN_BLOCKS = 196;  // 196*256 = 50176 >= NN

typedef __attribute__((ext_vector_type(8))) short s16x8;
typedef __attribute__((ext_vector_type(4))) float f32x4;

DEV unsigned short f2b(float f) {  // fp32 -> bf16 RNE (finite inputs)
  union { float f; unsigned u; } x; x.f = f;
  unsigned r = x.u + 0x7fffu + ((x.u >> 16) & 1u);
  return (unsigned short)(r >> 16);
}
DEV float b2f(unsigned short u) {
  union { unsigned u; float f; } x; x.u = ((unsigned)u) << 16; return x.f;
}

DEV s16x8 frag_from_f32(const float* p) {
  const float4 v0 = *(const float4*)p;
  const float4 v1 = *(const float4*)(p + 4);
  s16x8 af;
  af[0] = (short)f2b(v0.x); af[1] = (short)f2b(v0.y);
  af[2] = (short)f2b(v0.z); af[3] = (short)f2b(v0.w);
  af[4] = (short)f2b(v1.x); af[5] = (short)f2b(v1.y);
  af[6] = (short)f2b(v1.z); af[7] = (short)f2b(v1.w);
  return af;
}

// ---------------------------------------------------------------------------
// lin_in: h = x @ W(11x64) + b
// ---------------------------------------------------------------------------
__global__ __launch_bounds__(256) void lin_in_kernel(
    const float* __restrict__ x, const float* __restrict__ W,
    const float* __restrict__ b, float* __restrict__ h)
{
  int gid = blockIdx.x * 256 + threadIdx.x;
  if (gid >= NN * 64) return;
  int n = gid >> 6, c = gid & 63;
  float acc = b[c];
#pragma unroll
  for (int k = 0; k < 11; ++k)
    acc = fmaf(x[n * 11 + k], W[k * 64 + c], acc);
  h[gid] = acc;
}

// ---------------------------------------------------------------------------
// CSR build: histogram -> hierarchical exclusive scan (3 passes) -> fill
// ---------------------------------------------------------------------------
__global__ __launch_bounds__(256) void hist_kernel(
    const int* __restrict__ dstI, int* __restrict__ deg)
{
  int e = blockIdx.x * 256 + threadIdx.x;
  if (e < NE) atomicAdd(&deg[dstI[e]], 1);
}

__global__ __launch_bounds__(256) void scan_pass1(
    const int* __restrict__ deg, int* __restrict__ blockSums)
{
  __shared__ int red[4];
  int tid = threadIdx.x;
  int idx = blockIdx.x * 256 + tid;
  int v = (idx < NN) ? deg[idx] : 0;
#pragma unroll
  for (int off = 32; off > 0; off >>= 1) v += __shfl_down(v, off, 64);
  if ((tid & 63) == 0) red[tid >> 6] = v;
  __syncthreads();
  if (tid == 0) blockSums[blockIdx.x] = red[0] + red[1] + red[2] + red[3];
}

__global__ __launch_bounds__(256) void scan_pass2(
    const int* __restrict__ blockSums, int* __restrict__ blockOffs)
{
  __shared__ int part[256];
  int tid = threadIdx.x;
  int v = (tid < SCAN_BLOCKS) ? blockSums[tid] : 0;
  part[tid] = v;
  __syncthreads();
  for (int off = 1; off < 256; off <<= 1) {
    int t = 0;
    if (tid >= off) t = part[tid - off];
    __syncthreads();
    if (tid >= off) part[tid] += t;
    __syncthreads();
  }
  blockOffs[tid] = (tid == 0) ? 0 : part[tid - 1];
}

__global__ __launch_bounds__(256) void scan_pass3(
    const int* __restrict__ deg, const int* __restrict__ blockOffs,
    int* __restrict__ rowptr, int* __restrict__ cursor)
{
  __shared__ int part[256];
  int tid = threadIdx.x;
  int idx = blockIdx.x * 256 + tid;
  int v = (idx < NN) ? deg[idx] : 0;
  part[tid] = v;
  __syncthreads();
  for (int off = 1; off < 256; off <<= 1) {
    int t = 0;
    if (tid >= off) t = part[tid - off];
    __syncthreads();
    if (tid >= off) part[tid] += t;
    __syncthreads();
  }
  int excl = (tid == 0) ? 0 : part[tid - 1];
  int val = blockOffs[blockIdx.x] + excl;
  if (idx < NN) { rowptr[idx] = val; cursor[idx] = val; }
  if (idx == 0) rowptr[NN] = NE;
}

__global__ __launch_bounds__(256) void fill_kernel(
    const int* __restrict__ dstI, int* __restrict__ cursor,
    int* __restrict__ eid)
{
  int e = blockIdx.x * 256 + threadIdx.x;
  if (e < NE) {
    int pos = atomicAdd(&cursor[dstI[e]], 1);
    eid[pos] = e;
  }
}

// ---------------------------------------------------------------------------
// gemm_dual_mfma: Hd = h @ W[0:64], Hs = h @ W[64:128] (bf16 out, MFMA)
// ---------------------------------------------------------------------------
__global__ __launch_bounds__(256) void gemm_dual_mfma(
    const float* __restrict__ h, const float* __restrict__ W, // 132x64
    unsigned short* __restrict__ Hd, unsigned short* __restrict__ Hs)
{
  __shared__ unsigned short Wt_s[2 * 64 * 72];  // [half][n][k]

  const int tid = threadIdx.x;
  const int lane = tid & 63;
  const int wave = tid >> 6;
  const int nn = lane & 15;
  const int kq = lane >> 4;

#pragma unroll
  for (int i = 0; i < 32; ++i) {
    int idx = i * 256 + tid;          // 8192 = 2*64*64
    int half = idx >> 12;
    int rem = idx & 4095;
    int k = rem >> 6, n = rem & 63;
    Wt_s[half * 4608 + n * 72 + k] = f2b(W[idx]);
  }
  __syncthreads();

  s16x8 bfrag[2][4][2];  // [out][nt][kc]
#pragma unroll
  for (int o = 0; o < 2; ++o)
#pragma unroll
    for (int nt = 0; nt < 4; ++nt)
#pragma unroll
      for (int kc = 0; kc < 2; ++kc) {
        const unsigned short* p =
            &Wt_s[o * 4608 + (nt * 16 + nn) * 72 + kc * 32 + kq * 8];
#pragma unroll
        for (int j = 0; j < 8; ++j) bfrag[o][nt][kc][j] = (short)p[j];
      }

  const int rbase = blockIdx.x * 128 + wave * 32;

  f32x4 acc[2][2][4];  // [out][rt][nt]
#pragma unroll
  for (int o = 0; o < 2; ++o)
#pragma unroll
    for (int rt = 0; rt < 2; ++rt)
#pragma unroll
      for (int nt = 0; nt < 4; ++nt) acc[o][rt][nt] = (f32x4){0.f, 0.f, 0.f, 0.f};

#pragma unroll
  for (int rt = 0; rt < 2; ++rt) {
    int row = rbase + rt * 16 + nn;
    int rowc = row < NN ? row : NN - 1;
#pragma unroll
    for (int kc = 0; kc < 2; ++kc) {
      s16x8 af = frag_from_f32(&h[(size_t)rowc * 64 + kc * 32 + kq * 8]);
#pragma unroll
      for (int o = 0; o < 2; ++o)
#pragma unroll
        for (int nt = 0; nt < 4; ++nt)
          acc[o][rt][nt] = __builtin_amdgcn_mfma_f32_16x16x32_bf16(
              af, bfrag[o][nt][kc], acc[o][rt][nt], 0, 0, 0);
    }
  }

#pragma unroll
  for (int rt = 0; rt < 2; ++rt)
#pragma unroll
    for (int nt = 0; nt < 4; ++nt) {
      int col = nt * 16 + nn;
#pragma unroll
      for (int reg = 0; reg < 4; ++reg) {
        int row = rbase + rt * 16 + kq * 4 + reg;
        if (row < NN) {
          Hd[(size_t)row * 64 + col] = f2b(acc[0][rt][nt][reg]);
          Hs[(size_t)row * 64 + col] = f2b(acc[1][rt][nt][reg]);
        }
      }
    }
}

// ---------------------------------------------------------------------------
// edge_combine: t1[e] = Hd[dst[e]] + Hs[src[e]] + ea[e]@W_bot + b (bf16 out)
// 8 lanes/edge, 16B loads/stores, 2x grid-stride unroll for ILP.
// ---------------------------------------------------------------------------
__global__ __launch_bounds__(256) void edge_combine(
    const unsigned short* __restrict__ Hd, const unsigned short* __restrict__ Hs,
    const float* __restrict__ ea, const int* __restrict__ srcI,
    const int* __restrict__ dstI, const float* __restrict__ Wb, // 4x64
    const float* __restrict__ bias, unsigned short* __restrict__ t1,
    float* __restrict__ outStats)
{
  __shared__ float red_s[128];
  const int tid = threadIdx.x;
  const int c0 = (tid & 7) * 8;
  float bv[8], w0[8], w1[8], w2[8], w3[8];
#pragma unroll
  for (int j = 0; j < 8; ++j) {
    bv[j] = bias[c0 + j];
    w0[j] = Wb[0 * 64 + c0 + j];
    w1[j] = Wb[1 * 64 + c0 + j];
    w2[j] = Wb[2 * 64 + c0 + j];
    w3[j] = Wb[3 * 64 + c0 + j];
  }

  float s[8], s2[8];
#pragma unroll
  for (int j = 0; j < 8; ++j) { s[j] = 0.f; s2[j] = 0.f; }

  const int e0 = (blockIdx.x * 256 + tid) >> 3;
  const int estep = (gridDim.x * 256) >> 3;

  for (int e = e0; e < NE; e += 2 * estep) {
    int eb = e + estep;
    bool hasB = eb < NE;
    // issue all loads for both edges first
    int siA = srcI[e], diA = dstI[e];
    float4 avA = *(const float4*)&ea[(size_t)e * 4];
    uint4 hdA = *(const uint4*)&Hd[(size_t)diA * 64 + c0];
    uint4 hsA = *(const uint4*)&Hs[(size_t)siA * 64 + c0];
    int ebc = hasB ? eb : e;
    int siB = srcI[ebc], diB = dstI[ebc];
    float4 avB = *(const float4*)&ea[(size_t)ebc * 4];
    uint4 hdB = *(const uint4*)&Hd[(size_t)diB * 64 + c0];
    uint4 hsB = *(const uint4*)&Hs[(size_t)siB * 64 + c0];

    {
      const unsigned hdw[4] = {hdA.x, hdA.y, hdA.z, hdA.w};
      const unsigned hsw[4] = {hsA.x, hsA.y, hsA.z, hsA.w};
      unsigned short ob[8];
#pragma unroll
      for (int d = 0; d < 4; ++d) {
        union { unsigned u; float f; } a0, a1, b0, b1;
        a0.u = (hdw[d] & 0xffffu) << 16; a1.u = hdw[d] & 0xffff0000u;
        b0.u = (hsw[d] & 0xffffu) << 16; b1.u = hsw[d] & 0xffff0000u;
        int j0 = d * 2, j1 = d * 2 + 1;
        float y0 = a0.f + b0.f + bv[j0] + avA.x * w0[j0] + avA.y * w1[j0] + avA.z * w2[j0] + avA.w * w3[j0];
        float y1 = a1.f + b1.f + bv[j1] + avA.x * w0[j1] + avA.y * w1[j1] + avA.z * w2[j1] + avA.w * w3[j1];
        ob[j0] = f2b(y0); ob[j1] = f2b(y1);
        s[j0] += y0; s2[j0] += y0 * y0;
        s[j1] += y1; s2[j1] += y1 * y1;
      }
      *(uint4*)&t1[(size_t)e * 64 + c0] = *(const uint4*)ob;
    }
    if (hasB) {
      const unsigned hdw[4] = {hdB.x, hdB.y, hdB.z, hdB.w};
      const unsigned hsw[4] = {hsB.x, hsB.y, hsB.z, hsB.w};
      unsigned short ob[8];
#pragma unroll
      for (int d = 0; d < 4; ++d) {
        union { unsigned u; float f; } a0, a1, b0, b1;
        a0.u = (hdw[d] & 0xffffu) << 16; a1.u = hdw[d] & 0xffff0000u;
        b0.u = (hsw[d] & 0xffffu) << 16; b1.u = hsw[d] & 0xffff0000u;
        int j0 = d * 2, j1 = d * 2 + 1;
        float y0 = a0.f + b0.f + bv[j0] + avB.x * w0[j0] + avB.y * w1[j0] + avB.z * w2[j0] + avB.w * w3[j0];
        float y1 = a1.f + b1.f + bv[j1] + avB.x * w0[j1] + avB.y * w1[j1] + avB.z * w2[j1] + avB.w * w3[j1];
        ob[j0] = f2b(y0); ob[j1] = f2b(y1);
        s[j0] += y0; s2[j0] += y0 * y0;
        s[j1] += y1; s2[j1] += y1 * y1;
      }
      *(uint4*)&t1[(size_t)eb * 64 + c0] = *(const uint4*)ob;
    }
  }
#pragma unroll
  for (int j = 0; j < 8; ++j) {
    s[j] += __shfl_xor(s[j], 8, 64);
    s[j] += __shfl_xor(s[j], 16, 64);
    s[j] += __shfl_xor(s[j], 32, 64);
    s2[j] += __shfl_xor(s2[j], 8, 64);
    s2[j] += __shfl_xor(s2[j], 16, 64);
    s2[j] += __shfl_xor(s2[j], 32, 64);
  }
  if (tid < 128) red_s[tid] = 0.f;
  __syncthreads();
  if ((tid & 63) < 8) {
#pragma unroll
    for (int j = 0; j < 8; ++j) {
      atomicAdd(&red_s[c0 + j], s[j]);
      atomicAdd(&red_s[64 + c0 + j], s2[j]);
    }
  }
  __syncthreads();
  if (tid < 128) atomicAdd(&outStats[tid], red_s[tid]);
}

// ---------------------------------------------------------------------------
// gemm64_bn_mfma: out = relu(bn(A)) @ W + b — bf16 in/out, MFMA, in-place ok.
// 64 rows per wave (256-row block) -> 8 independent A-loads in flight/lane.
// Row-clamped loads stay within the wave's own 64 rows (or read another
// wave's possibly-updated row whose result is then discarded by guards).
// ---------------------------------------------------------------------------
__global__ __launch_bounds__(256) void gemm64_bn_mfma(
    const unsigned short* A0,         // bf16 M x 64 (may alias outp)
    const float* __restrict__ W,      // 64 x 64 fp32
    const float* __restrict__ bias,
    const float* __restrict__ inStats,
    const float* __restrict__ inG,
    const float* __restrict__ inBe,
    float invM_in,
    unsigned short* outp,             // bf16 M x 64
    float* __restrict__ outStats,
    int M)
{
  __shared__ unsigned short Wt_s[64 * 72];
  __shared__ float scale_s[64];
  __shared__ float shift_s[64];
  __shared__ float red_s[128];

  const int tid = threadIdx.x;
  const int lane = tid & 63;
  const int wave = tid >> 6;
  const int nn = lane & 15;
  const int kq = lane >> 4;

  if (tid < 64) {
    float mean = inStats[tid] * invM_in;
    float var = inStats[64 + tid] * invM_in - mean * mean;
    float sc = inG[tid] * rsqrtf(var + EPSV);
    scale_s[tid] = sc;
    shift_s[tid] = inBe[tid] - mean * sc;
  }
#pragma unroll
  for (int i = 0; i < 16; ++i) {
    int idx = i * 256 + tid;
    int k = idx >> 6, n = idx & 63;
    Wt_s[n * 72 + k] = f2b(W[idx]);
  }
  __syncthreads();

  s16x8 bfrag[4][2];
#pragma unroll
  for (int nt = 0; nt < 4; ++nt)
#pragma unroll
    for (int kc = 0; kc < 2; ++kc) {
      const unsigned short* p = &Wt_s[(nt * 16 + nn) * 72 + kc * 32 + kq * 8];
#pragma unroll
      for (int j = 0; j < 8; ++j) bfrag[nt][kc][j] = (short)p[j];
    }

  // vectorized scale/shift loads: 8 consecutive floats per (kc)
  float scf[2][8], shf[2][8];
#pragma unroll
  for (int kc = 0; kc < 2; ++kc) {
    int k0 = kc * 32 + kq * 8;
    float4 a = *(const float4*)&scale_s[k0];
    float4 b = *(const float4*)&scale_s[k0 + 4];
    float4 c = *(const float4*)&shift_s[k0];
    float4 d = *(const float4*)&shift_s[k0 + 4];
    scf[kc][0] = a.x; scf[kc][1] = a.y; scf[kc][2] = a.z; scf[kc][3] = a.w;
    scf[kc][4] = b.x; scf[kc][5] = b.y; scf[kc][6] = b.z; scf[kc][7] = b.w;
    shf[kc][0] = c.x; shf[kc][1] = c.y; shf[kc][2] = c.z; shf[kc][3] = c.w;
    shf[kc][4] = d.x; shf[kc][5] = d.y; shf[kc][6] = d.z; shf[kc][7] = d.w;
  }

  const int rbase = blockIdx.x * 256 + wave * 64;

  f32x4 acc[4][4];
#pragma unroll
  for (int rt = 0; rt < 4; ++rt)
#pragma unroll
    for (int nt = 0; nt < 4; ++nt) acc[rt][nt] = (f32x4){0.f, 0.f, 0.f, 0.f};

  // issue all 8 A-loads first
  uint4 raw[4][2];
#pragma unroll
  for (int rt = 0; rt < 4; ++rt) {
    int row = rbase + rt * 16 + nn;
    int rowc = row < M ? row : M - 1;
#pragma unroll
    for (int kc = 0; kc < 2; ++kc)
      raw[rt][kc] = *(const uint4*)&A0[(size_t)rowc * 64 + kc * 32 + kq * 8];
  }

#pragma unroll
  for (int rt = 0; rt < 4; ++rt) {
#pragma unroll
    for (int kc = 0; kc < 2; ++kc) {
      unsigned wbits[4] = {raw[rt][kc].x, raw[rt][kc].y, raw[rt][kc].z, raw[rt][kc].w};
      s16x8 af;
#pragma unroll
      for (int d = 0; d < 4; ++d) {
        union { unsigned u; float f; } lo, hi;
        lo.u = (wbits[d] & 0xffffu) << 16;
        hi.u = wbits[d] & 0xffff0000u;
        int j0 = d * 2, j1 = d * 2 + 1;
        af[j0] = (short)f2b(fmaxf(fmaf(scf[kc][j0], lo.f, shf[kc][j0]), 0.f));
        af[j1] = (short)f2b(fmaxf(fmaf(scf[kc][j1], hi.f, shf[kc][j1]), 0.f));
      }
#pragma unroll
      for (int nt = 0; nt < 4; ++nt)
        acc[rt][nt] = __builtin_amdgcn_mfma_f32_16x16x32_bf16(
            af, bfrag[nt][kc], acc[rt][nt], 0, 0, 0);
    }
  }

  float bcol[4];
#pragma unroll
  for (int nt = 0; nt < 4; ++nt) bcol[nt] = bias[nt * 16 + nn];

  float s[4] = {0.f, 0.f, 0.f, 0.f};
  float s2[4] = {0.f, 0.f, 0.f, 0.f};
#pragma unroll
  for (int rt = 0; rt < 4; ++rt)
#pragma unroll
    for (int nt = 0; nt < 4; ++nt) {
      int col = nt * 16 + nn;
#pragma unroll
      for (int reg = 0; reg < 4; ++reg) {
        int row = rbase + rt * 16 + kq * 4 + reg;
        if (row < M) {
          float y = acc[rt][nt][reg] + bcol[nt];
          outp[(size_t)row * 64 + col] = f2b(y);
          s[nt] += y; s2[nt] += y * y;
        }
      }
    }
#pragma unroll
  for (int nt = 0; nt < 4; ++nt) {
    s[nt] += __shfl_xor(s[nt], 16, 64);
    s[nt] += __shfl_xor(s[nt], 32, 64);
    s2[nt] += __shfl_xor(s2[nt], 16, 64);
    s2[nt] += __shfl_xor(s2[nt], 32, 64);
  }
  if (tid < 128) red_s[tid] = 0.f;
  __syncthreads();
  if (lane < 16) {
#pragma unroll
    for (int nt = 0; nt < 4; ++nt) {
      atomicAdd(&red_s[nt * 16 + nn], s[nt]);
      atomicAdd(&red_s[64 + nt * 16 + nn], s2[nt]);
    }
  }
  __syncthreads();
  if (tid < 128) atomicAdd(&outStats[tid], red_s[tid]);
}

// ---------------------------------------------------------------------------
// gemm_concat_mfma: u1 = [h(fp32)|aggr(bf16)] @ W(128x64) + b (bf16 out)
// ---------------------------------------------------------------------------
__global__ __launch_bounds__(256) void gemm_concat_mfma(
    const float* __restrict__ A0,            // h fp32
    const unsigned short* __restrict__ A1b,  // aggr bf16
    const float* __restrict__ W,             // 128 x 64
    const float* __restrict__ bias,
    unsigned short* __restrict__ outp,       // u1 bf16
    float* __restrict__ outStats,
    int M)
{
  __shared__ unsigned short Wt_s[64 * 136];
  __shared__ float red_s[128];

  const int tid = threadIdx.x;
  const int lane = tid & 63;
  const int wave = tid >> 6;
  const int nn = lane & 15;
  const int kq = lane >> 4;

#pragma unroll
  for (int i = 0; i < 32; ++i) {
    int idx = i * 256 + tid;          // 8192
    int k = idx >> 6, n = idx & 63;
    Wt_s[n * 136 + k] = f2b(W[idx]);
  }
  __syncthreads();

  s16x8 bfrag[4][4];  // [nt][kc]
#pragma unroll
  for (int nt = 0; nt < 4; ++nt)
#pragma unroll
    for (int kc = 0; kc < 4; ++kc) {
      const unsigned short* p = &Wt_s[(nt * 16 + nn) * 136 + kc * 32 + kq * 8];
#pragma unroll
      for (int j = 0; j < 8; ++j) bfrag[nt][kc][j] = (short)p[j];
    }

  const int rbase = blockIdx.x * 128 + wave * 32;

  f32x4 acc[2][4];
#pragma unroll
  for (int rt = 0; rt < 2; ++rt)
#pragma unroll
    for (int nt = 0; nt < 4; ++nt) acc[rt][nt] = (f32x4){0.f, 0.f, 0.f, 0.f};

#pragma unroll
  for (int rt = 0; rt < 2; ++rt) {
    int row = rbase + rt * 16 + nn;
    int rowc = row < M ? row : M - 1;
#pragma unroll
    for (int kc = 0; kc < 4; ++kc) {
      s16x8 af;
      if (kc < 2) {
        af = frag_from_f32(&A0[(size_t)rowc * 64 + kc * 32 + kq * 8]);
      } else {
        af = *(const s16x8*)&A1b[(size_t)rowc * 64 + (kc - 2) * 32 + kq * 8];
      }
#pragma unroll
      for (int nt = 0; nt < 4; ++nt)
        acc[rt][nt] = __builtin_amdgcn_mfma_f32_16x16x32_bf16(
            af, bfrag[nt][kc], acc[rt][nt], 0, 0, 0);
    }
  }

  float bcol[4];
#pragma unroll
  for (int nt = 0; nt < 4; ++nt) bcol[nt] = bias[nt * 16 + nn];

  float s[4] = {0.f, 0.f, 0.f, 0.f};
  float s2[4] = {0.f, 0.f, 0.f, 0.f};
#pragma unroll
  for (int rt = 0; rt < 2; ++rt)
#pragma unroll
    for (int nt = 0; nt < 4; ++nt) {
      int col = nt * 16 + nn;
#pragma unroll
      for (int reg = 0; reg < 4; ++reg) {
        int row = rbase + rt * 16 + kq * 4 + reg;
        if (row < M) {
          float y = acc[rt][nt][reg] + bcol[nt];
          outp[(size_t)row * 64 + col] = f2b(y);
          s[nt] += y; s2[nt] += y * y;
        }
      }
    }
#pragma unroll
  for (int nt = 0; nt < 4; ++nt) {
    s[nt] += __shfl_xor(s[nt], 16, 64);
    s[nt] += __shfl_xor(s[nt], 32, 64);
    s2[nt] += __shfl_xor(s2[nt], 16, 64);
    s2[nt] += __shfl_xor(s2[nt], 32, 64);
  }
  if (tid < 128) red_s[tid] = 0.f;
  __syncthreads();
  if (lane < 16) {
#pragma unroll
    for (int nt = 0; nt < 4; ++nt) {
      atomicAdd(&red_s[nt * 16 + nn], s[nt]);
      atomicAdd(&red_s[64 + nt * 16 + nn], s2[nt]);
    }
  }
  __syncthreads();
  if (tid < 128) atomicAdd(&outStats[tid], red_s[tid]);
}

// ---------------------------------------------------------------------------
// aggregate: aggr[n] = sum_{e in CSR(n)} relu(bn(t2_bf16[e]))  (bf16 out)
// 4-edge unroll for memory-level parallelism.
// ---------------------------------------------------------------------------
__global__ __launch_bounds__(256) void aggregate_kernel(
    const unsigned short* __restrict__ t2, const int* __restrict__ rowptr,
    const int* __restrict__ eid, const float* __restrict__ stats,
    const float* __restrict__ g, const float* __restrict__ be,
    float invM, unsigned short* __restrict__ aggr)
{
  int node = (blockIdx.x * 256 + threadIdx.x) >> 6;
  int lane = threadIdx.x & 63;
  if (node >= NN) return;
  float mean = stats[lane] * invM;
  float var = stats[64 + lane] * invM - mean * mean;
  float sc = g[lane] * rsqrtf(var + EPSV);
  float sh = be[lane] - mean * sc;
  int lo = rowptr[node], hi = rowptr[node + 1];
  float acc = 0.f;
  int i = lo;
  for (; i + 3 < hi; i += 4) {
    int e1 = eid[i], e2 = eid[i + 1], e3 = eid[i + 2], e4 = eid[i + 3];
    float v1 = b2f(t2[(size_t)e1 * 64 + lane]);
    float v2 = b2f(t2[(size_t)e2 * 64 + lane]);
    float v3 = b2f(t2[(size_t)e3 * 64 + lane]);
    float v4 = b2f(t2[(size_t)e4 * 64 + lane]);
    acc += fmaxf(fmaf(sc, v1, sh), 0.f) + fmaxf(fmaf(sc, v2, sh), 0.f) +
           fmaxf(fmaf(sc, v3, sh), 0.f) + fmaxf(fmaf(sc, v4, sh), 0.f);
  }
  for (; i < hi; ++i) {
    int e = eid[i];
    acc += fmaxf(fmaf(sc, b2f(t2[(size_t)e * 64 + lane]), sh), 0.f);
  }
  aggr[(size_t)node * 64 + lane] = f2b(acc);
}

// ---------------------------------------------------------------------------
// residual: h += relu(bn(u2_bf16))
// ---------------------------------------------------------------------------
__global__ __launch_bounds__(256) void residual_kernel(
    const unsigned short* __restrict__ u2, const float* __restrict__ stats,
    const float* __restrict__ g, const float* __restrict__ be,
    float invM, float* __restrict__ h)
{
  int gid = blockIdx.x * 256 + threadIdx.x;
  if (gid >= NN * 16) return;
  int c = (gid & 15) * 4;
  ushort4 v4 = *(const ushort4*)&u2[(size_t)gid * 4];
  float4 hv = *(const float4*)&h[(size_t)gid * 4];
  const unsigned short vu[4] = {v4.x, v4.y, v4.z, v4.w};
  float* hp = (float*)&hv;
#pragma unroll
  for (int j = 0; j < 4; ++j) {
    float mean = stats[c + j] * invM;
    float var = stats[64 + c + j] * invM - mean * mean;
    float sc = g[c + j] * rsqrtf(var + EPSV);
    float sh = be[c + j] - mean * sc;
    hp[j] += fmaxf(fmaf(sc, b2f(vu[j]), sh), 0.f);
  }
  *(float4*)&h[(size_t)gid * 4] = hv;
}

// ---------------------------------------------------------------------------
// pool: partial per-graph column sums, then tiny final with prediction head
// ---------------------------------------------------------------------------
constexpr int POOL_NPB = 128;  // nodes per block

__global__ __launch_bounds__(256) void pool_partial(
    const float* __restrict__ h, const int* __restrict__ batch,
    float* __restrict__ sums)  // NG x 64
{
  int lane = threadIdx.x & 63;
  int wave = threadIdx.x >> 6;
  int base = blockIdx.x * POOL_NPB;
  float acc = 0.f;
  int gcur = -1;
  for (int i = wave; i < POOL_NPB; i += 4) {
    int n = base + i;
    if (n >= NN) break;
    int g = batch[n];
    if (g != gcur) {
      if (gcur >= 0) atomicAdd(&sums[gcur * 64 + lane], acc);
      gcur = g;
      acc = 0.f;
    }
    acc += h[(size_t)n * 64 + lane];
  }
  if (gcur >= 0) atomicAdd(&sums[gcur * 64 + lane], acc);
}

DEV int lower_bound_i(const int* __restrict__ a, int n, int v) {
  int lo = 0, hi = n;
  while (lo < hi) {
    int m = (lo + hi) >> 1;
    if (a[m] < v) lo = m + 1; else hi = m;
  }
  return lo;
}

__global__ __launch_bounds__(64) void pool_final(
    const float* __restrict__ sums, const int* __restrict__ batch,
    const float* __restrict__ predW, const float* __restrict__ predB,
    float* __restrict__ out)
{
  int g = blockIdx.x;
  int lane = threadIdx.x;
  int lo = lower_bound_i(batch, NN, g);
  int hi = lower_bound_i(batch, NN, g + 1);
  float cnt = fmaxf((float)(hi - lo), 1.0f);
  float p = sums[g * 64 + lane] / cnt * predW[lane];
#pragma unroll
  for (int off = 32; off > 0; off >>= 1) p += __shfl_down(p, off, 64);
  if (lane == 0) out[g] = p + predB[0];
}

// ---------------------------------------------------------------------------
extern "C" void kernel_launch(void* const* d_in, const int* in_sizes, int n_in,
                              void* d_out, int out_size, void* d_ws, size_t ws_size,
                              hipStream_t stream)
{
  (void)in_sizes; (void)n_in; (void)out_size; (void)ws_size;

  const float* x        = (const float*)d_in[0];
  const float* edge_attr= (const float*)d_in[1];
  const int*   eidx     = (const int*)d_in[2];
  const int*   batch    = (const int*)d_in[3];
  const float* linW     = (const float*)d_in[4];
  const float* linB     = (const float*)d_in[5];
  const float* msgW1    = (const float*)d_in[6];
  const float* msgB1    = (const float*)d_in[7];
  const float* msgG1    = (const float*)d_in[8];
  const float* msgBe1   = (const float*)d_in[9];
  const float* msgW2    = (const float*)d_in[10];
  const float* msgB2    = (const float*)d_in[11];
  const float* msgG2    = (const float*)d_in[12];
  const float* msgBe2   = (const float*)d_in[13];
  const float* updW1    = (const float*)d_in[14];
  const float* updB1    = (const float*)d_in[15];
  const float* updG1    = (const float*)d_in[16];
  const float* updBe1   = (const float*)d_in[17];
  const float* updW2    = (const float*)d_in[18];
  const float* updB2    = (const float*)d_in[19];
  const float* updG2    = (const float*)d_in[20];
  const float* updBe2   = (const float*)d_in[21];
  const float* predW    = (const float*)d_in[22];
  const float* predB    = (const float*)d_in[23];

  const int* srcI = eidx;        // edge_index[0] = source
  const int* dstI = eidx + NE;   // edge_index[1] = target

  char* p = (char*)d_ws;
  float* h  = (float*)p;            p += (size_t)NN * 64 * 4;
  unsigned short* t1 = (unsigned short*)p; p += (size_t)NE * 64 * 2;
  unsigned short* aggr = (unsigned short*)p; p += (size_t)NN * 64 * 2;
  unsigned short* u1 = (unsigned short*)p;   p += (size_t)NN * 64 * 2;
  unsigned short* Hd = (unsigned short*)p;   p += (size_t)NN * 64 * 2;
  unsigned short* Hs = (unsigned short*)p;   p += (size_t)NN * 64 * 2;
  float* stats = (float*)p;         p += 16 * 128 * 4;
  float* sums = (float*)p;          p += NG * 64 * 4;
  int* deg = (int*)p;               p += (size_t)NN * 4;
  int* cursor = (int*)p;            p += (size_t)NN * 4;
  int* rowptr = (int*)p;            p += (size_t)(NN + 1) * 4;
  int* eid = (int*)p;               p += (size_t)NE * 4;
  int* blockSums = (int*)p;         p += 256 * 4;
  int* blockOffs = (int*)p;         p += 256 * 4;

  hipMemsetAsync(stats, 0, (16 * 128 + NG * 64) * sizeof(float), stream);
  hipMemsetAsync(deg, 0, NN * sizeof(int), stream);

  hist_kernel<<<(NE + 255) / 256, 256, 0, stream>>>(dstI, deg);
  scan_pass1<<<SCAN_BLOCKS, 256, 0, stream>>>(deg, blockSums);
  scan_pass2<<<1, 256, 0, stream>>>(blockSums, blockOffs);
  scan_pass3<<<SCAN_BLOCKS, 256, 0, stream>>>(deg, blockOffs, rowptr, cursor);
  fill_kernel<<<(NE + 255) / 256, 256, 0, stream>>>(dstI, cursor, eid);

  lin_in_kernel<<<(NN * 64 + 255) / 256, 256, 0, stream>>>(x, linW, linB, h);

  const float invE = 1.0f / (float)NE;
  const float invN = 1.0f / (float)NN;
  const int NB128 = (NN + 127) / 128;         // 391
  const int NB256 = (NN + 255) / 256;         // 196
  const int EB256 = (NE + 255) / 256;         // 1563

  for (int l = 0; l < 4; ++l) {
    float* st0 = stats + (l * 4 + 0) * 128;
    float* st1 = stats + (l * 4 + 1) * 128;
    float* st2 = stats + (l * 4 + 2) * 128;
    float* st3 = stats + (l * 4 + 3) * 128;
    const float* W1 = msgW1 + (size_t)l * 132 * 64;

    // Hd = h @ W1[0:64], Hs = h @ W1[64:128]  (bf16 out, MFMA)
    gemm_dual_mfma<<<NB128, 256, 0, stream>>>(h, W1, Hd, Hs);

    // t1[e] = Hd[dst] + Hs[src] + ea@W1[128:132] + b1 (bf16) ; stats(st0)
    edge_combine<<<2048, 256, 0, stream>>>(
        Hd, Hs, edge_attr, srcI, dstI, W1 + 128 * 64, msgB1 + l * 64,
        t1, st0);

    // t1 = relu(bn(t1)) @ msgW2 + b2 (bf16, in-place, MFMA) ; stats(st1)
    gemm64_bn_mfma<<<EB256, 256, 0, stream>>>(
        t1, msgW2 + (size_t)l * 64 * 64, msgB2 + l * 64,
        st0, msgG1 + l * 64, msgBe1 + l * 64, invE,
        t1, st1, NE);

    // aggr[n] = sum relu(bn(t1)) over incoming edges (CSR gather, bf16 out)
    aggregate_kernel<<<(NN * 64 + 255) / 256, 256, 0, stream>>>(
        t1, rowptr, eid, st1, msgG2 + l * 64, msgBe2 + l * 64, invE, aggr);

    // u1 = [h|aggr] @ updW1 + b1 (MFMA, bf16 out) ; stats(st2)
    gemm_concat_mfma<<<NB128, 256, 0, stream>>>(
        h, aggr, updW1 + (size_t)l * 128 * 64, updB1 + l * 64,
        u1, st2, NN);

    // u1 = relu(bn(u1)) @ updW2 + b2 (bf16, in-place, MFMA) ; stats(st3)
    gemm64_bn_mfma<<<NB256, 256, 0, stream>>>(
        u1, updW2 + (size_t)l * 64 * 64, updB2 + l * 64,
        st2, updG1 + l * 64, updBe1 + l * 64, invN,
        u1, st3, NN);

    // h += relu(bn(u1))
    residual_kernel<<<(NN * 16 + 255) / 256, 256, 0, stream>>>(
        u1, st3, updG2 + l * 64, updBe2 + l * 64, invN, h);
  }

  pool_partial<<<(NN + POOL_NPB - 1) / POOL_NPB, 256, 0, stream>>>(h, batch, sums);
  pool_final<<<NG, 64, 0, stream>>>(sums, batch, predW, predB, (float*)d_out);
}

// Round 8
// 962.261 us; speedup vs baseline: 3.5965x; 1.0187x over previous
//
#include <hip/hip_runtime.h>

#define DEV __device__ __forceinline__

constexpr int NN = 50000;   // nodes
constexpr int NE = 400000;  // edges
constexpr int NG = 32;      // graphs
constexpr float EPSV = 1e-5f;
constexpr int SCAN_BLOCKS = 196;  // 196*256 = 50176 >= NN

typedef __attribute__((ext_vector_type(8))) short s16x8;
typedef __attribute__((ext_vector_type(4))) float f32x4;

DEV unsigned short f2b(float f) {  // fp32 -> bf16 RNE (finite inputs)
  union { float f; unsigned u; } x; x.f = f;
  unsigned r = x.u + 0x7fffu + ((x.u >> 16) & 1u);
  return (unsigned short)(r >> 16);
}
DEV float b2f(unsigned short u) {
  union { unsigned u; float f; } x; x.u = ((unsigned)u) << 16; return x.f;
}

DEV s16x8 frag_from_f32(const float* p) {
  const float4 v0 = *(const float4*)p;
  const float4 v1 = *(const float4*)(p + 4);
  s16x8 af;
  af[0] = (short)f2b(v0.x); af[1] = (short)f2b(v0.y);
  af[2] = (short)f2b(v0.z); af[3] = (short)f2b(v0.w);
  af[4] = (short)f2b(v1.x); af[5] = (short)f2b(v1.y);
  af[6] = (short)f2b(v1.z); af[7] = (short)f2b(v1.w);
  return af;
}

// ---------------------------------------------------------------------------
// lin_in: h = x @ W(11x64) + b
// ---------------------------------------------------------------------------
__global__ __launch_bounds__(256) void lin_in_kernel(
    const float* __restrict__ x, const float* __restrict__ W,
    const float* __restrict__ b, float* __restrict__ h)
{
  int gid = blockIdx.x * 256 + threadIdx.x;
  if (gid >= NN * 64) return;
  int n = gid >> 6, c = gid & 63;
  float acc = b[c];
#pragma unroll
  for (int k = 0; k < 11; ++k)
    acc = fmaf(x[n * 11 + k], W[k * 64 + c], acc);
  h[gid] = acc;
}

// ---------------------------------------------------------------------------
// CSR build: histogram -> hierarchical exclusive scan -> permuting fill.
// Edge data is stored in CSR (dst-sorted) order from here on:
//   srcP[p] = src[eid[p]], dstP[p] = dst[eid[p]] (sorted), eaP[p] = ea[eid[p]]
// ---------------------------------------------------------------------------
__global__ __launch_bounds__(256) void hist_kernel(
    const int* __restrict__ dstI, int* __restrict__ deg)
{
  int e = blockIdx.x * 256 + threadIdx.x;
  if (e < NE) atomicAdd(&deg[dstI[e]], 1);
}

__global__ __launch_bounds__(256) void scan_pass1(
    const int* __restrict__ deg, int* __restrict__ blockSums)
{
  __shared__ int red[4];
  int tid = threadIdx.x;
  int idx = blockIdx.x * 256 + tid;
  int v = (idx < NN) ? deg[idx] : 0;
#pragma unroll
  for (int off = 32; off > 0; off >>= 1) v += __shfl_down(v, off, 64);
  if ((tid & 63) == 0) red[tid >> 6] = v;
  __syncthreads();
  if (tid == 0) blockSums[blockIdx.x] = red[0] + red[1] + red[2] + red[3];
}

__global__ __launch_bounds__(256) void scan_pass2(
    const int* __restrict__ blockSums, int* __restrict__ blockOffs)
{
  __shared__ int part[256];
  int tid = threadIdx.x;
  int v = (tid < SCAN_BLOCKS) ? blockSums[tid] : 0;
  part[tid] = v;
  __syncthreads();
  for (int off = 1; off < 256; off <<= 1) {
    int t = 0;
    if (tid >= off) t = part[tid - off];
    __syncthreads();
    if (tid >= off) part[tid] += t;
    __syncthreads();
  }
  blockOffs[tid] = (tid == 0) ? 0 : part[tid - 1];
}

__global__ __launch_bounds__(256) void scan_pass3(
    const int* __restrict__ deg, const int* __restrict__ blockOffs,
    int* __restrict__ rowptr, int* __restrict__ cursor)
{
  __shared__ int part[256];
  int tid = threadIdx.x;
  int idx = blockIdx.x * 256 + tid;
  int v = (idx < NN) ? deg[idx] : 0;
  part[tid] = v;
  __syncthreads();
  for (int off = 1; off < 256; off <<= 1) {
    int t = 0;
    if (tid >= off) t = part[tid - off];
    __syncthreads();
    if (tid >= off) part[tid] += t;
    __syncthreads();
  }
  int excl = (tid == 0) ? 0 : part[tid - 1];
  int val = blockOffs[blockIdx.x] + excl;
  if (idx < NN) { rowptr[idx] = val; cursor[idx] = val; }
  if (idx == 0) rowptr[NN] = NE;
}

__global__ __launch_bounds__(256) void fill_permute_kernel(
    const int* __restrict__ srcI, const int* __restrict__ dstI,
    const float* __restrict__ ea, int* __restrict__ cursor,
    int* __restrict__ srcP, int* __restrict__ dstP,
    float* __restrict__ eaP)
{
  int e = blockIdx.x * 256 + threadIdx.x;
  if (e < NE) {
    int d = dstI[e];
    int pos = atomicAdd(&cursor[d], 1);
    srcP[pos] = srcI[e];
    dstP[pos] = d;
    *(float4*)&eaP[(size_t)pos * 4] = *(const float4*)&ea[(size_t)e * 4];
  }
}

// ---------------------------------------------------------------------------
// gemm_dual_mfma: Hd = h @ W[0:64], Hs = h @ W[64:128] (bf16 out, MFMA)
// ---------------------------------------------------------------------------
__global__ __launch_bounds__(256) void gemm_dual_mfma(
    const float* __restrict__ h, const float* __restrict__ W, // 132x64
    unsigned short* __restrict__ Hd, unsigned short* __restrict__ Hs)
{
  __shared__ unsigned short Wt_s[2 * 64 * 72];  // [half][n][k]

  const int tid = threadIdx.x;
  const int lane = tid & 63;
  const int wave = tid >> 6;
  const int nn = lane & 15;
  const int kq = lane >> 4;

#pragma unroll
  for (int i = 0; i < 32; ++i) {
    int idx = i * 256 + tid;          // 8192 = 2*64*64
    int half = idx >> 12;
    int rem = idx & 4095;
    int k = rem >> 6, n = rem & 63;
    Wt_s[half * 4608 + n * 72 + k] = f2b(W[idx]);
  }
  __syncthreads();

  s16x8 bfrag[2][4][2];  // [out][nt][kc]
#pragma unroll
  for (int o = 0; o < 2; ++o)
#pragma unroll
    for (int nt = 0; nt < 4; ++nt)
#pragma unroll
      for (int kc = 0; kc < 2; ++kc) {
        const unsigned short* p =
            &Wt_s[o * 4608 + (nt * 16 + nn) * 72 + kc * 32 + kq * 8];
#pragma unroll
        for (int j = 0; j < 8; ++j) bfrag[o][nt][kc][j] = (short)p[j];
      }

  const int rbase = blockIdx.x * 128 + wave * 32;

  f32x4 acc[2][2][4];  // [out][rt][nt]
#pragma unroll
  for (int o = 0; o < 2; ++o)
#pragma unroll
    for (int rt = 0; rt < 2; ++rt)
#pragma unroll
      for (int nt = 0; nt < 4; ++nt) acc[o][rt][nt] = (f32x4){0.f, 0.f, 0.f, 0.f};

#pragma unroll
  for (int rt = 0; rt < 2; ++rt) {
    int row = rbase + rt * 16 + nn;
    int rowc = row < NN ? row : NN - 1;
#pragma unroll
    for (int kc = 0; kc < 2; ++kc) {
      s16x8 af = frag_from_f32(&h[(size_t)rowc * 64 + kc * 32 + kq * 8]);
#pragma unroll
      for (int o = 0; o < 2; ++o)
#pragma unroll
        for (int nt = 0; nt < 4; ++nt)
          acc[o][rt][nt] = __builtin_amdgcn_mfma_f32_16x16x32_bf16(
              af, bfrag[o][nt][kc], acc[o][rt][nt], 0, 0, 0);
    }
  }

#pragma unroll
  for (int rt = 0; rt < 2; ++rt)
#pragma unroll
    for (int nt = 0; nt < 4; ++nt) {
      int col = nt * 16 + nn;
#pragma unroll
      for (int reg = 0; reg < 4; ++reg) {
        int row = rbase + rt * 16 + kq * 4 + reg;
        if (row < NN) {
          Hd[(size_t)row * 64 + col] = f2b(acc[0][rt][nt][reg]);
          Hs[(size_t)row * 64 + col] = f2b(acc[1][rt][nt][reg]);
        }
      }
    }
}

// ---------------------------------------------------------------------------
// edge_combine (permuted): t1[p] = Hd[dstP[p]] + Hs[srcP[p]] + eaP[p]@Wb + b
// dstP is sorted -> the Hd gather is near-sequential. 8 lanes/edge, 16B ops,
// 2x grid-stride unroll for ILP.
// ---------------------------------------------------------------------------
__global__ __launch_bounds__(256) void edge_combine(
    const unsigned short* __restrict__ Hd, const unsigned short* __restrict__ Hs,
    const float* __restrict__ eaP, const int* __restrict__ srcP,
    const int* __restrict__ dstP, const float* __restrict__ Wb, // 4x64
    const float* __restrict__ bias, unsigned short* __restrict__ t1,
    float* __restrict__ outStats)
{
  __shared__ float red_s[128];
  const int tid = threadIdx.x;
  const int c0 = (tid & 7) * 8;
  float bv[8], w0[8], w1[8], w2[8], w3[8];
#pragma unroll
  for (int j = 0; j < 8; ++j) {
    bv[j] = bias[c0 + j];
    w0[j] = Wb[0 * 64 + c0 + j];
    w1[j] = Wb[1 * 64 + c0 + j];
    w2[j] = Wb[2 * 64 + c0 + j];
    w3[j] = Wb[3 * 64 + c0 + j];
  }

  float s[8], s2[8];
#pragma unroll
  for (int j = 0; j < 8; ++j) { s[j] = 0.f; s2[j] = 0.f; }

  const int e0 = (blockIdx.x * 256 + tid) >> 3;
  const int estep = (gridDim.x * 256) >> 3;

  for (int e = e0; e < NE; e += 2 * estep) {
    int eb = e + estep;
    bool hasB = eb < NE;
    int siA = srcP[e], diA = dstP[e];
    float4 avA = *(const float4*)&eaP[(size_t)e * 4];
    uint4 hdA = *(const uint4*)&Hd[(size_t)diA * 64 + c0];
    uint4 hsA = *(const uint4*)&Hs[(size_t)siA * 64 + c0];
    int ebc = hasB ? eb : e;
    int siB = srcP[ebc], diB = dstP[ebc];
    float4 avB = *(const float4*)&eaP[(size_t)ebc * 4];
    uint4 hdB = *(const uint4*)&Hd[(size_t)diB * 64 + c0];
    uint4 hsB = *(const uint4*)&Hs[(size_t)siB * 64 + c0];

    {
      const unsigned hdw[4] = {hdA.x, hdA.y, hdA.z, hdA.w};
      const unsigned hsw[4] = {hsA.x, hsA.y, hsA.z, hsA.w};
      unsigned short ob[8];
#pragma unroll
      for (int d = 0; d < 4; ++d) {
        union { unsigned u; float f; } a0, a1, b0, b1;
        a0.u = (hdw[d] & 0xffffu) << 16; a1.u = hdw[d] & 0xffff0000u;
        b0.u = (hsw[d] & 0xffffu) << 16; b1.u = hsw[d] & 0xffff0000u;
        int j0 = d * 2, j1 = d * 2 + 1;
        float y0 = a0.f + b0.f + bv[j0] + avA.x * w0[j0] + avA.y * w1[j0] + avA.z * w2[j0] + avA.w * w3[j0];
        float y1 = a1.f + b1.f + bv[j1] + avA.x * w0[j1] + avA.y * w1[j1] + avA.z * w2[j1] + avA.w * w3[j1];
        ob[j0] = f2b(y0); ob[j1] = f2b(y1);
        s[j0] += y0; s2[j0] += y0 * y0;
        s[j1] += y1; s2[j1] += y1 * y1;
      }
      *(uint4*)&t1[(size_t)e * 64 + c0] = *(const uint4*)ob;
    }
    if (hasB) {
      const unsigned hdw[4] = {hdB.x, hdB.y, hdB.z, hdB.w};
      const unsigned hsw[4] = {hsB.x, hsB.y, hsB.z, hsB.w};
      unsigned short ob[8];
#pragma unroll
      for (int d = 0; d < 4; ++d) {
        union { unsigned u; float f; } a0, a1, b0, b1;
        a0.u = (hdw[d] & 0xffffu) << 16; a1.u = hdw[d] & 0xffff0000u;
        b0.u = (hsw[d] & 0xffffu) << 16; b1.u = hsw[d] & 0xffff0000u;
        int j0 = d * 2, j1 = d * 2 + 1;
        float y0 = a0.f + b0.f + bv[j0] + avB.x * w0[j0] + avB.y * w1[j0] + avB.z * w2[j0] + avB.w * w3[j0];
        float y1 = a1.f + b1.f + bv[j1] + avB.x * w0[j1] + avB.y * w1[j1] + avB.z * w2[j1] + avB.w * w3[j1];
        ob[j0] = f2b(y0); ob[j1] = f2b(y1);
        s[j0] += y0; s2[j0] += y0 * y0;
        s[j1] += y1; s2[j1] += y1 * y1;
      }
      *(uint4*)&t1[(size_t)eb * 64 + c0] = *(const uint4*)ob;
    }
  }
#pragma unroll
  for (int j = 0; j < 8; ++j) {
    s[j] += __shfl_xor(s[j], 8, 64);
    s[j] += __shfl_xor(s[j], 16, 64);
    s[j] += __shfl_xor(s[j], 32, 64);
    s2[j] += __shfl_xor(s2[j], 8, 64);
    s2[j] += __shfl_xor(s2[j], 16, 64);
    s2[j] += __shfl_xor(s2[j], 32, 64);
  }
  if (tid < 128) red_s[tid] = 0.f;
  __syncthreads();
  if ((tid & 63) < 8) {
#pragma unroll
    for (int j = 0; j < 8; ++j) {
      atomicAdd(&red_s[c0 + j], s[j]);
      atomicAdd(&red_s[64 + c0 + j], s2[j]);
    }
  }
  __syncthreads();
  if (tid < 128) atomicAdd(&outStats[tid], red_s[tid]);
}

// ---------------------------------------------------------------------------
// gemm64_bn_mfma: out = relu(bn(A)) @ W + b — bf16 in/out, MFMA, in-place ok.
// 64 rows per wave (256-row block) -> 8 independent A-loads in flight/lane.
// ---------------------------------------------------------------------------
__global__ __launch_bounds__(256) void gemm64_bn_mfma(
    const unsigned short* A0,         // bf16 M x 64 (may alias outp)
    const float* __restrict__ W,      // 64 x 64 fp32
    const float* __restrict__ bias,
    const float* __restrict__ inStats,
    const float* __restrict__ inG,
    const float* __restrict__ inBe,
    float invM_in,
    unsigned short* outp,             // bf16 M x 64
    float* __restrict__ outStats,
    int M)
{
  __shared__ unsigned short Wt_s[64 * 72];
  __shared__ float scale_s[64];
  __shared__ float shift_s[64];
  __shared__ float red_s[128];

  const int tid = threadIdx.x;
  const int lane = tid & 63;
  const int wave = tid >> 6;
  const int nn = lane & 15;
  const int kq = lane >> 4;

  if (tid < 64) {
    float mean = inStats[tid] * invM_in;
    float var = inStats[64 + tid] * invM_in - mean * mean;
    float sc = inG[tid] * rsqrtf(var + EPSV);
    scale_s[tid] = sc;
    shift_s[tid] = inBe[tid] - mean * sc;
  }
#pragma unroll
  for (int i = 0; i < 16; ++i) {
    int idx = i * 256 + tid;
    int k = idx >> 6, n = idx & 63;
    Wt_s[n * 72 + k] = f2b(W[idx]);
  }
  __syncthreads();

  s16x8 bfrag[4][2];
#pragma unroll
  for (int nt = 0; nt < 4; ++nt)
#pragma unroll
    for (int kc = 0; kc < 2; ++kc) {
      const unsigned short* p = &Wt_s[(nt * 16 + nn) * 72 + kc * 32 + kq * 8];
#pragma unroll
      for (int j = 0; j < 8; ++j) bfrag[nt][kc][j] = (short)p[j];
    }

  float scf[2][8], shf[2][8];
#pragma unroll
  for (int kc = 0; kc < 2; ++kc) {
    int k0 = kc * 32 + kq * 8;
    float4 a = *(const float4*)&scale_s[k0];
    float4 b = *(const float4*)&scale_s[k0 + 4];
    float4 c = *(const float4*)&shift_s[k0];
    float4 d = *(const float4*)&shift_s[k0 + 4];
    scf[kc][0] = a.x; scf[kc][1] = a.y; scf[kc][2] = a.z; scf[kc][3] = a.w;
    scf[kc][4] = b.x; scf[kc][5] = b.y; scf[kc][6] = b.z; scf[kc][7] = b.w;
    shf[kc][0] = c.x; shf[kc][1] = c.y; shf[kc][2] = c.z; shf[kc][3] = c.w;
    shf[kc][4] = d.x; shf[kc][5] = d.y; shf[kc][6] = d.z; shf[kc][7] = d.w;
  }

  const int rbase = blockIdx.x * 256 + wave * 64;

  f32x4 acc[4][4];
#pragma unroll
  for (int rt = 0; rt < 4; ++rt)
#pragma unroll
    for (int nt = 0; nt < 4; ++nt) acc[rt][nt] = (f32x4){0.f, 0.f, 0.f, 0.f};

  uint4 raw[4][2];
#pragma unroll
  for (int rt = 0; rt < 4; ++rt) {
    int row = rbase + rt * 16 + nn;
    int rowc = row < M ? row : M - 1;
#pragma unroll
    for (int kc = 0; kc < 2; ++kc)
      raw[rt][kc] = *(const uint4*)&A0[(size_t)rowc * 64 + kc * 32 + kq * 8];
  }

#pragma unroll
  for (int rt = 0; rt < 4; ++rt) {
#pragma unroll
    for (int kc = 0; kc < 2; ++kc) {
      unsigned wbits[4] = {raw[rt][kc].x, raw[rt][kc].y, raw[rt][kc].z, raw[rt][kc].w};
      s16x8 af;
#pragma unroll
      for (int d = 0; d < 4; ++d) {
        union { unsigned u; float f; } lo, hi;
        lo.u = (wbits[d] & 0xffffu) << 16;
        hi.u = wbits[d] & 0xffff0000u;
        int j0 = d * 2, j1 = d * 2 + 1;
        af[j0] = (short)f2b(fmaxf(fmaf(scf[kc][j0], lo.f, shf[kc][j0]), 0.f));
        af[j1] = (short)f2b(fmaxf(fmaf(scf[kc][j1], hi.f, shf[kc][j1]), 0.f));
      }
#pragma unroll
      for (int nt = 0; nt < 4; ++nt)
        acc[rt][nt] = __builtin_amdgcn_mfma_f32_16x16x32_bf16(
            af, bfrag[nt][kc], acc[rt][nt], 0, 0, 0);
    }
  }

  float bcol[4];
#pragma unroll
  for (int nt = 0; nt < 4; ++nt) bcol[nt] = bias[nt * 16 + nn];

  float s[4] = {0.f, 0.f, 0.f, 0.f};
  float s2[4] = {0.f, 0.f, 0.f, 0.f};
#pragma unroll
  for (int rt = 0; rt < 4; ++rt)
#pragma unroll
    for (int nt = 0; nt < 4; ++nt) {
      int col = nt * 16 + nn;
#pragma unroll
      for (int reg = 0; reg < 4; ++reg) {
        int row = rbase + rt * 16 + kq * 4 + reg;
        if (row < M) {
          float y = acc[rt][nt][reg] + bcol[nt];
          outp[(size_t)row * 64 + col] = f2b(y);
          s[nt] += y; s2[nt] += y * y;
        }
      }
    }
#pragma unroll
  for (int nt = 0; nt < 4; ++nt) {
    s[nt] += __shfl_xor(s[nt], 16, 64);
    s[nt] += __shfl_xor(s[nt], 32, 64);
    s2[nt] += __shfl_xor(s2[nt], 16, 64);
    s2[nt] += __shfl_xor(s2[nt], 32, 64);
  }
  if (tid < 128) red_s[tid] = 0.f;
  __syncthreads();
  if (lane < 16) {
#pragma unroll
    for (int nt = 0; nt < 4; ++nt) {
      atomicAdd(&red_s[nt * 16 + nn], s[nt]);
      atomicAdd(&red_s[64 + nt * 16 + nn], s2[nt]);
    }
  }
  __syncthreads();
  if (tid < 128) atomicAdd(&outStats[tid], red_s[tid]);
}

// ---------------------------------------------------------------------------
// gemm_concat_mfma: u1 = [h(fp32)|aggr(bf16)] @ W(128x64) + b (bf16 out)
// ---------------------------------------------------------------------------
__global__ __launch_bounds__(256) void gemm_concat_mfma(
    const float* __restrict__ A0,            // h fp32
    const unsigned short* __restrict__ A1b,  // aggr bf16
    const float* __restrict__ W,             // 128 x 64
    const float* __restrict__ bias,
    unsigned short* __restrict__ outp,       // u1 bf16
    float* __restrict__ outStats,
    int M)
{
  __shared__ unsigned short Wt_s[64 * 136];
  __shared__ float red_s[128];

  const int tid = threadIdx.x;
  const int lane = tid & 63;
  const int wave = tid >> 6;
  const int nn = lane & 15;
  const int kq = lane >> 4;

#pragma unroll
  for (int i = 0; i < 32; ++i) {
    int idx = i * 256 + tid;          // 8192
    int k = idx >> 6, n = idx & 63;
    Wt_s[n * 136 + k] = f2b(W[idx]);
  }
  __syncthreads();

  s16x8 bfrag[4][4];  // [nt][kc]
#pragma unroll
  for (int nt = 0; nt < 4; ++nt)
#pragma unroll
    for (int kc = 0; kc < 4; ++kc) {
      const unsigned short* p = &Wt_s[(nt * 16 + nn) * 136 + kc * 32 + kq * 8];
#pragma unroll
      for (int j = 0; j < 8; ++j) bfrag[nt][kc][j] = (short)p[j];
    }

  const int rbase = blockIdx.x * 128 + wave * 32;

  f32x4 acc[2][4];
#pragma unroll
  for (int rt = 0; rt < 2; ++rt)
#pragma unroll
    for (int nt = 0; nt < 4; ++nt) acc[rt][nt] = (f32x4){0.f, 0.f, 0.f, 0.f};

#pragma unroll
  for (int rt = 0; rt < 2; ++rt) {
    int row = rbase + rt * 16 + nn;
    int rowc = row < M ? row : M - 1;
#pragma unroll
    for (int kc = 0; kc < 4; ++kc) {
      s16x8 af;
      if (kc < 2) {
        af = frag_from_f32(&A0[(size_t)rowc * 64 + kc * 32 + kq * 8]);
      } else {
        af = *(const s16x8*)&A1b[(size_t)rowc * 64 + (kc - 2) * 32 + kq * 8];
      }
#pragma unroll
      for (int nt = 0; nt < 4; ++nt)
        acc[rt][nt] = __builtin_amdgcn_mfma_f32_16x16x32_bf16(
            af, bfrag[nt][kc], acc[rt][nt], 0, 0, 0);
    }
  }

  float bcol[4];
#pragma unroll
  for (int nt = 0; nt < 4; ++nt) bcol[nt] = bias[nt * 16 + nn];

  float s[4] = {0.f, 0.f, 0.f, 0.f};
  float s2[4] = {0.f, 0.f, 0.f, 0.f};
#pragma unroll
  for (int rt = 0; rt < 2; ++rt)
#pragma unroll
    for (int nt = 0; nt < 4; ++nt) {
      int col = nt * 16 + nn;
#pragma unroll
      for (int reg = 0; reg < 4; ++reg) {
        int row = rbase + rt * 16 + kq * 4 + reg;
        if (row < M) {
          float y = acc[rt][nt][reg] + bcol[nt];
          outp[(size_t)row * 64 + col] = f2b(y);
          s[nt] += y; s2[nt] += y * y;
        }
      }
    }
#pragma unroll
  for (int nt = 0; nt < 4; ++nt) {
    s[nt] += __shfl_xor(s[nt], 16, 64);
    s[nt] += __shfl_xor(s[nt], 32, 64);
    s2[nt] += __shfl_xor(s2[nt], 16, 64);
    s2[nt] += __shfl_xor(s2[nt], 32, 64);
  }
  if (tid < 128) red_s[tid] = 0.f;
  __syncthreads();
  if (lane < 16) {
#pragma unroll
    for (int nt = 0; nt < 4; ++nt) {
      atomicAdd(&red_s[nt * 16 + nn], s[nt]);
      atomicAdd(&red_s[64 + nt * 16 + nn], s2[nt]);
    }
  }
  __syncthreads();
  if (tid < 128) atomicAdd(&outStats[tid], red_s[tid]);
}

// ---------------------------------------------------------------------------
// aggregate (sequential): aggr[n] = sum_{p in [rowptr[n],rowptr[n+1])}
//   relu(bn(t2[p]))  — t2 stored in CSR order, so reads stream. 4-row unroll.
// ---------------------------------------------------------------------------
__global__ __launch_bounds__(256) void aggregate_kernel(
    const unsigned short* __restrict__ t2, const int* __restrict__ rowptr,
    const float* __restrict__ stats, const float* __restrict__ g,
    const float* __restrict__ be, float invM,
    unsigned short* __restrict__ aggr)
{
  int node = (blockIdx.x * 256 + threadIdx.x) >> 6;
  int lane = threadIdx.x & 63;
  if (node >= NN) return;
  float mean = stats[lane] * invM;
  float var = stats[64 + lane] * invM - mean * mean;
  float sc = g[lane] * rsqrtf(var + EPSV);
  float sh = be[lane] - mean * sc;
  int lo = rowptr[node], hi = rowptr[node + 1];
  float acc = 0.f;
  int i = lo;
  for (; i + 3 < hi; i += 4) {
    float v1 = b2f(t2[(size_t)(i + 0) * 64 + lane]);
    float v2 = b2f(t2[(size_t)(i + 1) * 64 + lane]);
    float v3 = b2f(t2[(size_t)(i + 2) * 64 + lane]);
    float v4 = b2f(t2[(size_t)(i + 3) * 64 + lane]);
    acc += fmaxf(fmaf(sc, v1, sh), 0.f) + fmaxf(fmaf(sc, v2, sh), 0.f) +
           fmaxf(fmaf(sc, v3, sh), 0.f) + fmaxf(fmaf(sc, v4, sh), 0.f);
  }
  for (; i < hi; ++i)
    acc += fmaxf(fmaf(sc, b2f(t2[(size_t)i * 64 + lane]), sh), 0.f);
  aggr[(size_t)node * 64 + lane] = f2b(acc);
}

// ---------------------------------------------------------------------------
// residual: h += relu(bn(u2_bf16))
// ---------------------------------------------------------------------------
__global__ __launch_bounds__(256) void residual_kernel(
    const unsigned short* __restrict__ u2, const float* __restrict__ stats,
    const float* __restrict__ g, const float* __restrict__ be,
    float invM, float* __restrict__ h)
{
  int gid = blockIdx.x * 256 + threadIdx.x;
  if (gid >= NN * 16) return;
  int c = (gid & 15) * 4;
  ushort4 v4 = *(const ushort4*)&u2[(size_t)gid * 4];
  float4 hv = *(const float4*)&h[(size_t)gid * 4];
  const unsigned short vu[4] = {v4.x, v4.y, v4.z, v4.w};
  float* hp = (float*)&hv;
#pragma unroll
  for (int j = 0; j < 4; ++j) {
    float mean = stats[c + j] * invM;
    float var = stats[64 + c + j] * invM - mean * mean;
    float sc = g[c + j] * rsqrtf(var + EPSV);
    float sh = be[c + j] - mean * sc;
    hp[j] += fmaxf(fmaf(sc, b2f(vu[j]), sh), 0.f);
  }
  *(float4*)&h[(size_t)gid * 4] = hv;
}

// ---------------------------------------------------------------------------
// pool: partial per-graph column sums, then tiny final with prediction head
// ---------------------------------------------------------------------------
constexpr int POOL_NPB = 128;  // nodes per block

__global__ __launch_bounds__(256) void pool_partial(
    const float* __restrict__ h, const int* __restrict__ batch,
    float* __restrict__ sums)  // NG x 64
{
  int lane = threadIdx.x & 63;
  int wave = threadIdx.x >> 6;
  int base = blockIdx.x * POOL_NPB;
  float acc = 0.f;
  int gcur = -1;
  for (int i = wave; i < POOL_NPB; i += 4) {
    int n = base + i;
    if (n >= NN) break;
    int g = batch[n];
    if (g != gcur) {
      if (gcur >= 0) atomicAdd(&sums[gcur * 64 + lane], acc);
      gcur = g;
      acc = 0.f;
    }
    acc += h[(size_t)n * 64 + lane];
  }
  if (gcur >= 0) atomicAdd(&sums[gcur * 64 + lane], acc);
}

DEV int lower_bound_i(const int* __restrict__ a, int n, int v) {
  int lo = 0, hi = n;
  while (lo < hi) {
    int m = (lo + hi) >> 1;
    if (a[m] < v) lo = m + 1; else hi = m;
  }
  return lo;
}

__global__ __launch_bounds__(64) void pool_final(
    const float* __restrict__ sums, const int* __restrict__ batch,
    const float* __restrict__ predW, const float* __restrict__ predB,
    float* __restrict__ out)
{
  int g = blockIdx.x;
  int lane = threadIdx.x;
  int lo = lower_bound_i(batch, NN, g);
  int hi = lower_bound_i(batch, NN, g + 1);
  float cnt = fmaxf((float)(hi - lo), 1.0f);
  float p = sums[g * 64 + lane] / cnt * predW[lane];
#pragma unroll
  for (int off = 32; off > 0; off >>= 1) p += __shfl_down(p, off, 64);
  if (lane == 0) out[g] = p + predB[0];
}

// ---------------------------------------------------------------------------
extern "C" void kernel_launch(void* const* d_in, const int* in_sizes, int n_in,
                              void* d_out, int out_size, void* d_ws, size_t ws_size,
                              hipStream_t stream)
{
  (void)in_sizes; (void)n_in; (void)out_size; (void)ws_size;

  const float* x        = (const float*)d_in[0];
  const float* edge_attr= (const float*)d_in[1];
  const int*   eidx     = (const int*)d_in[2];
  const int*   batch    = (const int*)d_in[3];
  const float* linW     = (const float*)d_in[4];
  const float* linB     = (const float*)d_in[5];
  const float* msgW1    = (const float*)d_in[6];
  const float* msgB1    = (const float*)d_in[7];
  const float* msgG1    = (const float*)d_in[8];
  const float* msgBe1   = (const float*)d_in[9];
  const float* msgW2    = (const float*)d_in[10];
  const float* msgB2    = (const float*)d_in[11];
  const float* msgG2    = (const float*)d_in[12];
  const float* msgBe2   = (const float*)d_in[13];
  const float* updW1    = (const float*)d_in[14];
  const float* updB1    = (const float*)d_in[15];
  const float* updG1    = (const float*)d_in[16];
  const float* updBe1   = (const float*)d_in[17];
  const float* updW2    = (const float*)d_in[18];
  const float* updB2    = (const float*)d_in[19];
  const float* updG2    = (const float*)d_in[20];
  const float* updBe2   = (const float*)d_in[21];
  const float* predW    = (const float*)d_in[22];
  const float* predB    = (const float*)d_in[23];

  const int* srcI = eidx;        // edge_index[0] = source
  const int* dstI = eidx + NE;   // edge_index[1] = target

  char* p = (char*)d_ws;
  float* h  = (float*)p;            p += (size_t)NN * 64 * 4;
  unsigned short* t1 = (unsigned short*)p; p += (size_t)NE * 64 * 2;
  unsigned short* aggr = (unsigned short*)p; p += (size_t)NN * 64 * 2;
  unsigned short* u1 = (unsigned short*)p;   p += (size_t)NN * 64 * 2;
  unsigned short* Hd = (unsigned short*)p;   p += (size_t)NN * 64 * 2;
  unsigned short* Hs = (unsigned short*)p;   p += (size_t)NN * 64 * 2;
  float* stats = (float*)p;         p += 16 * 128 * 4;
  float* sums = (float*)p;          p += NG * 64 * 4;
  int* deg = (int*)p;               p += (size_t)NN * 4;
  int* cursor = (int*)p;            p += (size_t)NN * 4;
  int* rowptr = (int*)p;            p += (size_t)(NN + 1) * 4;
  int* srcP = (int*)p;              p += (size_t)NE * 4;
  int* dstP = (int*)p;              p += (size_t)NE * 4;
  float* eaP = (float*)p;           p += (size_t)NE * 4 * 4;
  int* blockSums = (int*)p;         p += 256 * 4;
  int* blockOffs = (int*)p;         p += 256 * 4;

  hipMemsetAsync(stats, 0, (16 * 128 + NG * 64) * sizeof(float), stream);
  hipMemsetAsync(deg, 0, NN * sizeof(int), stream);

  hist_kernel<<<(NE + 255) / 256, 256, 0, stream>>>(dstI, deg);
  scan_pass1<<<SCAN_BLOCKS, 256, 0, stream>>>(deg, blockSums);
  scan_pass2<<<1, 256, 0, stream>>>(blockSums, blockOffs);
  scan_pass3<<<SCAN_BLOCKS, 256, 0, stream>>>(deg, blockOffs, rowptr, cursor);
  fill_permute_kernel<<<(NE + 255) / 256, 256, 0, stream>>>(
      srcI, dstI, edge_attr, cursor, srcP, dstP, eaP);

  lin_in_kernel<<<(NN * 64 + 255) / 256, 256, 0, stream>>>(x, linW, linB, h);

  const float invE = 1.0f / (float)NE;
  const float invN = 1.0f / (float)NN;
  const int NB128 = (NN + 127) / 128;         // 391
  const int NB256 = (NN + 255) / 256;         // 196
  const int EB256 = (NE + 255) / 256;         // 1563

  for (int l = 0; l < 4; ++l) {
    float* st0 = stats + (l * 4 + 0) * 128;
    float* st1 = stats + (l * 4 + 1) * 128;
    float* st2 = stats + (l * 4 + 2) * 128;
    float* st3 = stats + (l * 4 + 3) * 128;
    const float* W1 = msgW1 + (size_t)l * 132 * 64;

    // Hd = h @ W1[0:64], Hs = h @ W1[64:128]  (bf16 out, MFMA)
    gemm_dual_mfma<<<NB128, 256, 0, stream>>>(h, W1, Hd, Hs);

    // t1[p] = Hd[dstP] + Hs[srcP] + eaP@W1[128:132] + b1 (bf16) ; stats(st0)
    edge_combine<<<2048, 256, 0, stream>>>(
        Hd, Hs, eaP, srcP, dstP, W1 + 128 * 64, msgB1 + l * 64,
        t1, st0);

    // t1 = relu(bn(t1)) @ msgW2 + b2 (bf16, in-place, MFMA) ; stats(st1)
    gemm64_bn_mfma<<<EB256, 256, 0, stream>>>(
        t1, msgW2 + (size_t)l * 64 * 64, msgB2 + l * 64,
        st0, msgG1 + l * 64, msgBe1 + l * 64, invE,
        t1, st1, NE);

    // aggr[n] = sum relu(bn(t1)) over CSR rows (sequential stream, bf16 out)
    aggregate_kernel<<<(NN * 64 + 255) / 256, 256, 0, stream>>>(
        t1, rowptr, st1, msgG2 + l * 64, msgBe2 + l * 64, invE, aggr);

    // u1 = [h|aggr] @ updW1 + b1 (MFMA, bf16 out) ; stats(st2)
    gemm_concat_mfma<<<NB128, 256, 0, stream>>>(
        h, aggr, updW1 + (size_t)l * 128 * 64, updB1 + l * 64,
        u1, st2, NN);

    // u1 = relu(bn(u1)) @ updW2 + b2 (bf16, in-place, MFMA) ; stats(st3)
    gemm64_bn_mfma<<<NB256, 256, 0, stream>>>(
        u1, updW2 + (size_t)l * 64 * 64, updB2 + l * 64,
        st2, updG1 + l * 64, updBe1 + l * 64, invN,
        u1, st3, NN);

    // h += relu(bn(u1))
    residual_kernel<<<(NN * 16 + 255) / 256, 256, 0, stream>>>(
        u1, st3, updG2 + l * 64, updBe2 + l * 64, invN, h);
  }

  pool_partial<<<(NN + POOL_NPB - 1) / POOL_NPB, 256, 0, stream>>>(h, batch, sums);
  pool_final<<<NG, 64, 0, stream>>>(sums, batch, predW, predB, (float*)d_out);
}